// Round 4
// baseline (1106.843 us; speedup 1.0000x reference)
//
#include <hip/hip_runtime.h>
#include <math.h>

// Problem constants
#define T_TOK 8192   // B*S tokens
#define DIM   1024   // D
#define HID   2816   // H
#define NE    8      // experts
// K (top-k) = 2

typedef __attribute__((ext_vector_type(4))) float  f32x4;
typedef __attribute__((ext_vector_type(8))) __bf16 bf16x8;

__device__ __forceinline__ unsigned short f2bf(float f) {
  unsigned int u = __builtin_bit_cast(unsigned int, f);
  unsigned int r = (u + 0x7FFFu + ((u >> 16) & 1u)) >> 16;   // RTNE
  return (unsigned short)r;
}
__device__ __forceinline__ int imin(int a, int b) { return a < b ? a : b; }

// global -> LDS direct DMA, 16B per lane. LDS dest = wave-uniform base + lane*16.
typedef const __attribute__((address_space(1))) void gvoid_t;
typedef __attribute__((address_space(3))) void svoid_t;
__device__ __forceinline__ void g2l16(const void* g, void* l) {
  __builtin_amdgcn_global_load_lds((gvoid_t*)g, (svoid_t*)l, 16, 0, 0);
}

// ---------------- x -> bf16 cast ----------------
__global__ __launch_bounds__(256) void cast_x_kernel(const float* __restrict__ x,
                                                     unsigned short* __restrict__ xb) {
  size_t i = ((size_t)blockIdx.x * 256 + threadIdx.x) * 8;
  float4 a = *(const float4*)(x + i);
  float4 b = *(const float4*)(x + i + 4);
  typedef __attribute__((ext_vector_type(8))) unsigned short u16x8;
  u16x8 v;
  v[0] = f2bf(a.x); v[1] = f2bf(a.y); v[2] = f2bf(a.z); v[3] = f2bf(a.w);
  v[4] = f2bf(b.x); v[5] = f2bf(b.y); v[6] = f2bf(b.z); v[7] = f2bf(b.w);
  *(u16x8*)(xb + i) = v;
}

// ------------- fp32 [E][R][C] -> bf16 [E][C][R] transpose-cast -------------
__global__ __launch_bounds__(256) void transpose_cast_kernel(const float* __restrict__ src,
                                                             unsigned short* __restrict__ dst,
                                                             int R, int C) {
  __shared__ float tile[32][33];
  int e = blockIdx.z;
  const float* s = src + (size_t)e * R * C;
  unsigned short* d = dst + (size_t)e * R * C;
  int tx = threadIdx.x & 31, ty = threadIdx.x >> 5;
  int r0 = blockIdx.y * 32, c0 = blockIdx.x * 32;
#pragma unroll
  for (int j = 0; j < 4; ++j)
    tile[ty + 8 * j][tx] = s[(size_t)(r0 + ty + 8 * j) * C + c0 + tx];
  __syncthreads();
#pragma unroll
  for (int j = 0; j < 4; ++j)
    d[(size_t)(c0 + ty + 8 * j) * R + r0 + tx] = f2bf(tile[tx][ty + 8 * j]);
}

// ---------------- router: scores (fp64), top-2, softmax, compact ----------------
__global__ __launch_bounds__(256) void router_kernel(const float* __restrict__ x,
                                                     const float* __restrict__ gw,
                                                     int* __restrict__ cnt,
                                                     int* __restrict__ idx,
                                                     float* __restrict__ wgt) {
  int wid = threadIdx.x >> 6;
  int lane = threadIdx.x & 63;
  int t = blockIdx.x * 4 + wid;
  double acc[NE];
#pragma unroll
  for (int e = 0; e < NE; ++e) acc[e] = 0.0;
  const float* xr = x + (size_t)t * DIM;
#pragma unroll 4
  for (int i = 0; i < DIM / 64; ++i) {
    int d = i * 64 + lane;
    double xv = (double)xr[d];
#pragma unroll
    for (int e = 0; e < NE; ++e) acc[e] += xv * (double)gw[e * DIM + d];
  }
#pragma unroll
  for (int e = 0; e < NE; ++e) {
#pragma unroll
    for (int off = 32; off >= 1; off >>= 1) acc[e] += __shfl_xor(acc[e], off);
  }
  if (lane == 0) {
    int e0 = 0; double s0 = acc[0];
#pragma unroll
    for (int e = 1; e < NE; ++e) if (acc[e] > s0) { s0 = acc[e]; e0 = e; }
    int e1 = -1; double s1 = -1.0e300;
#pragma unroll
    for (int e = 0; e < NE; ++e) if (e != e0 && acc[e] > s1) { s1 = acc[e]; e1 = e; }
    double w0 = 1.0 / (1.0 + exp(s1 - s0));   // softmax over {s0,s1}, s0 >= s1
    int p0 = atomicAdd(&cnt[e0], 1);
    idx[e0 * T_TOK + p0] = t; wgt[e0 * T_TOK + p0] = (float)w0;
    int p1 = atomicAdd(&cnt[e1], 1);
    idx[e1 * T_TOK + p1] = t; wgt[e1 * T_TOK + p1] = (float)(1.0 - w0);
  }
}

__global__ void offsets_kernel(const int* __restrict__ cnt, int* __restrict__ offs) {
  if (threadIdx.x == 0) {
    int s = 0;
    for (int e = 0; e < NE; ++e) { offs[e] = s; s += cnt[e]; }
  }
}

// LDS source/read swizzle (rule #21: linear gload_lds dest + inverse-swz source + swz read):
//   staging lane loads global chunk (lane&3)^(row&3); reader fetches chunk cc^(row&3).
//   Both XORs are lane-constant -> zero extra VALU. 8-way -> 4-way bank conflict.

// ---------------- GEMM1: h = silu(Xg @ w1) * (Xg @ w3), bf16 out ----------------
__global__ __launch_bounds__(256) void gemm1_kernel(const unsigned short* __restrict__ xb,
                                                    const unsigned short* __restrict__ w1t,
                                                    const unsigned short* __restrict__ w3t,
                                                    const int* __restrict__ cnt,
                                                    const int* __restrict__ offs,
                                                    const int* __restrict__ idx,
                                                    unsigned short* __restrict__ hbuf) {
  int bid = blockIdx.x;
  int e = bid & 7;
  int g = bid >> 3;
  int n0 = (g >> 6) * 128;        // 22 n-tiles, slow
  int m0 = (g & 63) * 128;        // 64 m-slots, fast (early exit past c)
  int c = cnt[e];
  if (m0 >= c) return;

  __shared__ __align__(16) unsigned short As[2 * 4096];
  __shared__ __align__(16) unsigned short B1s[2 * 4096];
  __shared__ __align__(16) unsigned short B3s[2 * 4096];

  int t = threadIdx.x;
  int wid = t >> 6, lane = t & 63;
  int wr = (wid >> 1) * 64, wc = (wid & 1) * 64;
  int lr = lane & 15;
  int lks = (((lane >> 4) ^ (lane & 3))) * 8;   // swizzled read chunk

  // staging: wave `wid` owns rows [wid*32, wid*32+32), 2 DMA instrs of 16 rows
  int sr0 = wid * 32 + (lane >> 2);
  int sr1 = sr0 + 16;
  int swz = (((lane & 3) ^ ((lane >> 2) & 3))) * 8;  // swizzled source chunk
  const int* idx_e = idx + e * T_TOK;
  int tokA0 = (m0 + sr0 < c) ? idx_e[m0 + sr0] : 0;
  int tokA1 = (m0 + sr1 < c) ? idx_e[m0 + sr1] : 0;
  const unsigned short* aG0 = xb + (size_t)tokA0 * DIM + swz;
  const unsigned short* aG1 = xb + (size_t)tokA1 * DIM + swz;
  const unsigned short* w1e = w1t + ((size_t)e * HID + n0) * DIM;
  const unsigned short* w3e = w3t + ((size_t)e * HID + n0) * DIM;
  const unsigned short* b1G0 = w1e + (size_t)sr0 * DIM + swz;
  const unsigned short* b1G1 = w1e + (size_t)sr1 * DIM + swz;
  const unsigned short* b3G0 = w3e + (size_t)sr0 * DIM + swz;
  const unsigned short* b3G1 = w3e + (size_t)sr1 * DIM + swz;
  int lofs0 = wid * 1024;          // elems within a 4096-elem buffer
  int lofs1 = wid * 1024 + 512;

  f32x4 acc1[4][4], acc3[4][4];
#pragma unroll
  for (int i = 0; i < 4; ++i)
#pragma unroll
    for (int j = 0; j < 4; ++j) {
      acc1[i][j] = f32x4{0.f, 0.f, 0.f, 0.f};
      acc3[i][j] = f32x4{0.f, 0.f, 0.f, 0.f};
    }

#define STAGE1(K0, BUF)                                   \
  do {                                                    \
    const int bo = (BUF) * 4096;                          \
    g2l16(aG0 + (K0), As + bo + lofs0);                   \
    g2l16(aG1 + (K0), As + bo + lofs1);                   \
    g2l16(b1G0 + (K0), B1s + bo + lofs0);                 \
    g2l16(b1G1 + (K0), B1s + bo + lofs1);                 \
    g2l16(b3G0 + (K0), B3s + bo + lofs0);                 \
    g2l16(b3G1 + (K0), B3s + bo + lofs1);                 \
  } while (0)

#define COMPUTE1(BUF)                                                        \
  do {                                                                       \
    const int bo = (BUF) * 4096;                                             \
    bf16x8 a[4], b1[4], b3[4];                                               \
    _Pragma("unroll") for (int f = 0; f < 4; ++f) {                          \
      a[f]  = *(const bf16x8*)(As  + bo + (wr + f * 16 + lr) * 32 + lks);    \
      b1[f] = *(const bf16x8*)(B1s + bo + (wc + f * 16 + lr) * 32 + lks);    \
      b3[f] = *(const bf16x8*)(B3s + bo + (wc + f * 16 + lr) * 32 + lks);    \
    }                                                                        \
    _Pragma("unroll") for (int i = 0; i < 4; ++i)                            \
      _Pragma("unroll") for (int j = 0; j < 4; ++j) {                        \
        acc1[i][j] = __builtin_amdgcn_mfma_f32_16x16x32_bf16(a[i], b1[j], acc1[i][j], 0, 0, 0); \
        acc3[i][j] = __builtin_amdgcn_mfma_f32_16x16x32_bf16(a[i], b3[j], acc3[i][j], 0, 0, 0); \
      }                                                                      \
  } while (0)

  const int NK = DIM / 32;   // 32, even
  STAGE1(0, 0);
  __syncthreads();
  int ks;
  for (ks = 0; ks + 2 < NK; ks += 2) {
    STAGE1((ks + 1) * 32, 1);
    COMPUTE1(0);
    __syncthreads();
    STAGE1((ks + 2) * 32, 0);
    COMPUTE1(1);
    __syncthreads();
  }
  STAGE1((NK - 1) * 32, 1);
  COMPUTE1(0);
  __syncthreads();
  COMPUTE1(1);

  int base = offs[e];
#pragma unroll
  for (int i = 0; i < 4; ++i)
#pragma unroll
    for (int q = 0; q < 4; ++q) {
      int pl = m0 + wr + i * 16 + (lane >> 4) * 4 + q;
      if (pl >= c) continue;
      unsigned short* hrow = hbuf + (size_t)(base + pl) * HID + n0 + wc + (lane & 15);
#pragma unroll
      for (int j = 0; j < 4; ++j) {
        float v1 = acc1[i][j][q];
        float v3 = acc3[i][j][q];
        float hv = v1 / (1.0f + __expf(-v1)) * v3;   // silu(v1) * v3
        hrow[j * 16] = f2bf(hv);
      }
    }
}

// ---------------- GEMM2: out[tok] += w * (h @ w2) ----------------
__global__ __launch_bounds__(256) void gemm2_kernel(const unsigned short* __restrict__ hbuf,
                                                    const unsigned short* __restrict__ w2t,
                                                    const int* __restrict__ cnt,
                                                    const int* __restrict__ offs,
                                                    const int* __restrict__ idx,
                                                    const float* __restrict__ wgt,
                                                    float* __restrict__ out) {
  int bid = blockIdx.x;
  int e = bid & 7;
  int g = bid >> 3;
  int n0 = (g >> 6) * 128;        // 8 n-tiles, slow
  int m0 = (g & 63) * 128;        // 64 m-slots, fast
  int c = cnt[e];
  if (m0 >= c) return;

  __shared__ __align__(16) unsigned short As[2 * 4096];
  __shared__ __align__(16) unsigned short Bs[2 * 4096];

  int t = threadIdx.x;
  int wid = t >> 6, lane = t & 63;
  int wr = (wid >> 1) * 64, wc = (wid & 1) * 64;
  int lr = lane & 15;
  int lks = (((lane >> 4) ^ (lane & 3))) * 8;
  int base = offs[e];

  int sr0 = wid * 32 + (lane >> 2);
  int sr1 = sr0 + 16;
  int swz = (((lane & 3) ^ ((lane >> 2) & 3))) * 8;
  size_t ha0 = (size_t)imin(base + m0 + sr0, 2 * T_TOK - 1) * HID;
  size_t ha1 = (size_t)imin(base + m0 + sr1, 2 * T_TOK - 1) * HID;
  const unsigned short* aG0 = hbuf + ha0 + swz;
  const unsigned short* aG1 = hbuf + ha1 + swz;
  const unsigned short* w2e = w2t + ((size_t)e * DIM + n0) * HID;
  const unsigned short* bG0 = w2e + (size_t)sr0 * HID + swz;
  const unsigned short* bG1 = w2e + (size_t)sr1 * HID + swz;
  int lofs0 = wid * 1024;
  int lofs1 = wid * 1024 + 512;

  f32x4 acc[4][4];
#pragma unroll
  for (int i = 0; i < 4; ++i)
#pragma unroll
    for (int j = 0; j < 4; ++j) acc[i][j] = f32x4{0.f, 0.f, 0.f, 0.f};

#define STAGE2(K0, BUF)                                   \
  do {                                                    \
    const int bo = (BUF) * 4096;                          \
    g2l16(aG0 + (K0), As + bo + lofs0);                   \
    g2l16(aG1 + (K0), As + bo + lofs1);                   \
    g2l16(bG0 + (K0), Bs + bo + lofs0);                   \
    g2l16(bG1 + (K0), Bs + bo + lofs1);                   \
  } while (0)

#define COMPUTE2(BUF)                                                        \
  do {                                                                       \
    const int bo = (BUF) * 4096;                                             \
    bf16x8 a[4], b[4];                                                       \
    _Pragma("unroll") for (int f = 0; f < 4; ++f) {                          \
      a[f] = *(const bf16x8*)(As + bo + (wr + f * 16 + lr) * 32 + lks);      \
      b[f] = *(const bf16x8*)(Bs + bo + (wc + f * 16 + lr) * 32 + lks);      \
    }                                                                        \
    _Pragma("unroll") for (int i = 0; i < 4; ++i)                            \
      _Pragma("unroll") for (int j = 0; j < 4; ++j)                          \
        acc[i][j] = __builtin_amdgcn_mfma_f32_16x16x32_bf16(a[i], b[j], acc[i][j], 0, 0, 0); \
  } while (0)

  const int NK = HID / 32;   // 88, even
  STAGE2(0, 0);
  __syncthreads();
  int ks;
  for (ks = 0; ks + 2 < NK; ks += 2) {
    STAGE2((ks + 1) * 32, 1);
    COMPUTE2(0);
    __syncthreads();
    STAGE2((ks + 2) * 32, 0);
    COMPUTE2(1);
    __syncthreads();
  }
  STAGE2((NK - 1) * 32, 1);
  COMPUTE2(0);
  __syncthreads();
  COMPUTE2(1);

  const int* idx_e = idx + e * T_TOK;
  const float* wgt_e = wgt + e * T_TOK;
#pragma unroll
  for (int i = 0; i < 4; ++i)
#pragma unroll
    for (int q = 0; q < 4; ++q) {
      int pl = m0 + wr + i * 16 + (lane >> 4) * 4 + q;
      if (pl >= c) continue;
      int tok = idx_e[pl];
      float w = wgt_e[pl];
      float* orow = out + (size_t)tok * DIM + n0 + wc + (lane & 15);
#pragma unroll
      for (int j = 0; j < 4; ++j)
        atomicAdd(orow + j * 16, w * acc[i][j][q]);
    }
}

extern "C" void kernel_launch(void* const* d_in, const int* in_sizes, int n_in,
                              void* d_out, int out_size, void* d_ws, size_t ws_size,
                              hipStream_t stream) {
  const float* x  = (const float*)d_in[0];
  const float* gw = (const float*)d_in[1];
  const float* w1 = (const float*)d_in[2];
  const float* w2 = (const float*)d_in[3];
  const float* w3 = (const float*)d_in[4];
  float* out = (float*)d_out;

  // Workspace layout (~248 MB total)
  char* ws = (char*)d_ws;
  size_t off = 0;
  auto alloc = [&](size_t bytes) {
    char* p = ws + off;
    off += (bytes + 255) & ~(size_t)255;
    return p;
  };
  unsigned short* xb  = (unsigned short*)alloc((size_t)T_TOK * DIM * 2);       // 16.8 MB
  unsigned short* w1t = (unsigned short*)alloc((size_t)NE * DIM * HID * 2);    // 46.1 MB  [E][H][D]
  unsigned short* w3t = (unsigned short*)alloc((size_t)NE * DIM * HID * 2);    // 46.1 MB  [E][H][D]
  unsigned short* w2t = (unsigned short*)alloc((size_t)NE * DIM * HID * 2);    // 46.1 MB  [E][D][H]
  unsigned short* hb  = (unsigned short*)alloc((size_t)2 * T_TOK * HID * 2);   // 92.3 MB
  int*   cnt  = (int*)alloc(NE * sizeof(int));
  int*   offs = (int*)alloc(NE * sizeof(int));
  int*   idx  = (int*)alloc((size_t)NE * T_TOK * sizeof(int));
  float* wgt  = (float*)alloc((size_t)NE * T_TOK * sizeof(float));

  hipMemsetAsync(d_out, 0, (size_t)out_size * sizeof(float), stream);
  hipMemsetAsync(cnt, 0, NE * sizeof(int), stream);

  cast_x_kernel<<<(T_TOK * DIM) / (256 * 8), 256, 0, stream>>>(x, xb);
  transpose_cast_kernel<<<dim3(HID / 32, DIM / 32, NE), 256, 0, stream>>>(w1, w1t, DIM, HID);
  transpose_cast_kernel<<<dim3(HID / 32, DIM / 32, NE), 256, 0, stream>>>(w3, w3t, DIM, HID);
  transpose_cast_kernel<<<dim3(DIM / 32, HID / 32, NE), 256, 0, stream>>>(w2, w2t, HID, DIM);
  router_kernel<<<T_TOK / 4, 256, 0, stream>>>(x, gw, cnt, idx, wgt);
  offsets_kernel<<<1, 64, 0, stream>>>(cnt, offs);

  gemm1_kernel<<<8 * (HID / 128) * 64, 256, 0, stream>>>(xb, w1t, w3t, cnt, offs, idx, hb);
  gemm2_kernel<<<8 * (DIM / 128) * 64, 256, 0, stream>>>(hb, w2t, cnt, offs, idx, wgt, out);
}

// Round 5
// 1063.387 us; speedup vs baseline: 1.0409x; 1.0409x over previous
//
#include <hip/hip_runtime.h>
#include <math.h>

// Problem constants
#define T_TOK 8192   // B*S tokens
#define DIM   1024   // D
#define HID   2816   // H
#define NE    8      // experts
// K (top-k) = 2

typedef __attribute__((ext_vector_type(4))) float  f32x4;
typedef __attribute__((ext_vector_type(8))) __bf16 bf16x8;

__device__ __forceinline__ unsigned short f2bf(float f) {
  unsigned int u = __builtin_bit_cast(unsigned int, f);
  unsigned int r = (u + 0x7FFFu + ((u >> 16) & 1u)) >> 16;   // RTNE
  return (unsigned short)r;
}
__device__ __forceinline__ int imin(int a, int b) { return a < b ? a : b; }

// global -> LDS direct DMA, 16B per lane. LDS dest = wave-uniform base + lane*16.
typedef const __attribute__((address_space(1))) void gvoid_t;
typedef __attribute__((address_space(3))) void svoid_t;
__device__ __forceinline__ void g2l16(const void* g, void* l) {
  __builtin_amdgcn_global_load_lds((gvoid_t*)g, (svoid_t*)l, 16, 0, 0);
}

// ---------------- x -> bf16 cast ----------------
__global__ __launch_bounds__(256) void cast_x_kernel(const float* __restrict__ x,
                                                     unsigned short* __restrict__ xb) {
  size_t i = ((size_t)blockIdx.x * 256 + threadIdx.x) * 8;
  float4 a = *(const float4*)(x + i);
  float4 b = *(const float4*)(x + i + 4);
  typedef __attribute__((ext_vector_type(8))) unsigned short u16x8;
  u16x8 v;
  v[0] = f2bf(a.x); v[1] = f2bf(a.y); v[2] = f2bf(a.z); v[3] = f2bf(a.w);
  v[4] = f2bf(b.x); v[5] = f2bf(b.y); v[6] = f2bf(b.z); v[7] = f2bf(b.w);
  *(u16x8*)(xb + i) = v;
}

// ------------- fp32 [E][R][C] -> bf16 [E][C][R] transpose-cast -------------
__global__ __launch_bounds__(256) void transpose_cast_kernel(const float* __restrict__ src,
                                                             unsigned short* __restrict__ dst,
                                                             int R, int C) {
  __shared__ float tile[32][33];
  int e = blockIdx.z;
  const float* s = src + (size_t)e * R * C;
  unsigned short* d = dst + (size_t)e * R * C;
  int tx = threadIdx.x & 31, ty = threadIdx.x >> 5;
  int r0 = blockIdx.y * 32, c0 = blockIdx.x * 32;
#pragma unroll
  for (int j = 0; j < 4; ++j)
    tile[ty + 8 * j][tx] = s[(size_t)(r0 + ty + 8 * j) * C + c0 + tx];
  __syncthreads();
#pragma unroll
  for (int j = 0; j < 4; ++j)
    d[(size_t)(c0 + ty + 8 * j) * R + r0 + tx] = f2bf(tile[tx][ty + 8 * j]);
}

// ---------------- router: scores (fp64), top-2, softmax, compact ----------------
__global__ __launch_bounds__(256) void router_kernel(const float* __restrict__ x,
                                                     const float* __restrict__ gw,
                                                     int* __restrict__ cnt,
                                                     int* __restrict__ idx,
                                                     float* __restrict__ wgt) {
  int wid = threadIdx.x >> 6;
  int lane = threadIdx.x & 63;
  int t = blockIdx.x * 4 + wid;
  double acc[NE];
#pragma unroll
  for (int e = 0; e < NE; ++e) acc[e] = 0.0;
  const float* xr = x + (size_t)t * DIM;
#pragma unroll 4
  for (int i = 0; i < DIM / 64; ++i) {
    int d = i * 64 + lane;
    double xv = (double)xr[d];
#pragma unroll
    for (int e = 0; e < NE; ++e) acc[e] += xv * (double)gw[e * DIM + d];
  }
#pragma unroll
  for (int e = 0; e < NE; ++e) {
#pragma unroll
    for (int off = 32; off >= 1; off >>= 1) acc[e] += __shfl_xor(acc[e], off);
  }
  if (lane == 0) {
    int e0 = 0; double s0 = acc[0];
#pragma unroll
    for (int e = 1; e < NE; ++e) if (acc[e] > s0) { s0 = acc[e]; e0 = e; }
    int e1 = -1; double s1 = -1.0e300;
#pragma unroll
    for (int e = 0; e < NE; ++e) if (e != e0 && acc[e] > s1) { s1 = acc[e]; e1 = e; }
    double w0 = 1.0 / (1.0 + exp(s1 - s0));   // softmax over {s0,s1}, s0 >= s1
    int p0 = atomicAdd(&cnt[e0], 1);
    idx[e0 * T_TOK + p0] = t; wgt[e0 * T_TOK + p0] = (float)w0;
    int p1 = atomicAdd(&cnt[e1], 1);
    idx[e1 * T_TOK + p1] = t; wgt[e1 * T_TOK + p1] = (float)(1.0 - w0);
  }
}

__global__ void offsets_kernel(const int* __restrict__ cnt, int* __restrict__ offs) {
  if (threadIdx.x == 0) {
    int s = 0;
    for (int e = 0; e < NE; ++e) { offs[e] = s; s += cnt[e]; }
  }
}

// Pipeline fences: raw s_barrier + counted vmcnt (T4); sched_barrier pins motion (rule #18).
#define WAITV(N) asm volatile("s_waitcnt vmcnt(" #N ")" ::: "memory")
#define SBAR __builtin_amdgcn_s_barrier()
#define SCHEDB __builtin_amdgcn_sched_barrier(0)

// ---------------- GEMM1: h = silu(Xg @ w1) * (Xg @ w3), bf16 out ----------------
// 3-deep prefetch, counted vmcnt: 6 loads/stage; tile t resident when vmcnt<=12.
__global__ __launch_bounds__(256) void gemm1_kernel(const unsigned short* __restrict__ xb,
                                                    const unsigned short* __restrict__ w1t,
                                                    const unsigned short* __restrict__ w3t,
                                                    const int* __restrict__ cnt,
                                                    const int* __restrict__ offs,
                                                    const int* __restrict__ idx,
                                                    unsigned short* __restrict__ hbuf) {
  int bid = blockIdx.x;
  int e = bid & 7;
  int g = bid >> 3;
  int n0 = (g >> 6) * 128;        // 22 n-tiles, slow
  int m0 = (g & 63) * 128;        // 64 m-slots, fast (early exit past c)
  int c = cnt[e];
  if (m0 >= c) return;

  __shared__ __align__(16) unsigned short As[3 * 4096];
  __shared__ __align__(16) unsigned short B1s[3 * 4096];
  __shared__ __align__(16) unsigned short B3s[3 * 4096];

  int t = threadIdx.x;
  int wid = t >> 6, lane = t & 63;
  int wr = (wid >> 1) * 64, wc = (wid & 1) * 64;
  int lr = lane & 15, lk = (lane >> 4) * 8;

  // staging: wave `wid` owns rows [wid*32, wid*32+32), 2 DMA instrs of 16 rows
  int sr0 = wid * 32 + (lane >> 2);
  int sr1 = sr0 + 16;
  int sb = (lane & 3) * 8;    // elem offset within 32-elem row
  const int* idx_e = idx + e * T_TOK;
  int tokA0 = (m0 + sr0 < c) ? idx_e[m0 + sr0] : 0;
  int tokA1 = (m0 + sr1 < c) ? idx_e[m0 + sr1] : 0;
  const unsigned short* aG0 = xb + (size_t)tokA0 * DIM + sb;
  const unsigned short* aG1 = xb + (size_t)tokA1 * DIM + sb;
  const unsigned short* w1e = w1t + ((size_t)e * HID + n0) * DIM;
  const unsigned short* w3e = w3t + ((size_t)e * HID + n0) * DIM;
  const unsigned short* b1G0 = w1e + (size_t)sr0 * DIM + sb;
  const unsigned short* b1G1 = w1e + (size_t)sr1 * DIM + sb;
  const unsigned short* b3G0 = w3e + (size_t)sr0 * DIM + sb;
  const unsigned short* b3G1 = w3e + (size_t)sr1 * DIM + sb;
  int lofs0 = wid * 1024;          // elems within a 4096-elem buffer
  int lofs1 = wid * 1024 + 512;

  f32x4 acc1[4][4], acc3[4][4];
#pragma unroll
  for (int i = 0; i < 4; ++i)
#pragma unroll
    for (int j = 0; j < 4; ++j) {
      acc1[i][j] = f32x4{0.f, 0.f, 0.f, 0.f};
      acc3[i][j] = f32x4{0.f, 0.f, 0.f, 0.f};
    }

#define STAGE1(K0, S)                                     \
  do {                                                    \
    const int bo = (S) * 4096;                            \
    g2l16(aG0 + (K0), As + bo + lofs0);                   \
    g2l16(aG1 + (K0), As + bo + lofs1);                   \
    g2l16(b1G0 + (K0), B1s + bo + lofs0);                 \
    g2l16(b1G1 + (K0), B1s + bo + lofs1);                 \
    g2l16(b3G0 + (K0), B3s + bo + lofs0);                 \
    g2l16(b3G1 + (K0), B3s + bo + lofs1);                 \
  } while (0)

#define COMPUTE1(S)                                                          \
  do {                                                                       \
    const int bo = (S) * 4096;                                               \
    bf16x8 a[4], b1[4], b3[4];                                               \
    _Pragma("unroll") for (int f = 0; f < 4; ++f) {                          \
      a[f]  = *(const bf16x8*)(As  + bo + (wr + f * 16 + lr) * 32 + lk);     \
      b1[f] = *(const bf16x8*)(B1s + bo + (wc + f * 16 + lr) * 32 + lk);     \
      b3[f] = *(const bf16x8*)(B3s + bo + (wc + f * 16 + lr) * 32 + lk);     \
    }                                                                        \
    _Pragma("unroll") for (int i = 0; i < 4; ++i)                            \
      _Pragma("unroll") for (int j = 0; j < 4; ++j) {                        \
        acc1[i][j] = __builtin_amdgcn_mfma_f32_16x16x32_bf16(a[i], b1[j], acc1[i][j], 0, 0, 0); \
        acc3[i][j] = __builtin_amdgcn_mfma_f32_16x16x32_bf16(a[i], b3[j], acc3[i][j], 0, 0, 0); \
      }                                                                      \
  } while (0)

  const int NK = DIM / 32;   // 32
  STAGE1(0, 0);
  STAGE1(32, 1);
  int sc = 0, sp = 2;        // compute slot, prefetch slot = (t+2)%3
#pragma unroll 1
  for (int ks = 0; ks < NK - 2; ++ks) {
    STAGE1((ks + 2) * 32, sp);
    WAITV(12);               // oldest 6 (tile ks) retired; 12 newer stay in flight
    SBAR; SCHEDB;
    COMPUTE1(sc);
    SCHEDB; SBAR; SCHEDB;    // all waves done reading slot sc before it's re-DMA'd
    sc = sc == 2 ? 0 : sc + 1;
    sp = sp == 2 ? 0 : sp + 1;
  }
  WAITV(6);
  SBAR; SCHEDB;
  COMPUTE1(sc);
  SCHEDB; SBAR; SCHEDB;
  sc = sc == 2 ? 0 : sc + 1;
  WAITV(0);
  SBAR; SCHEDB;
  COMPUTE1(sc);

  int base = offs[e];
#pragma unroll
  for (int i = 0; i < 4; ++i)
#pragma unroll
    for (int q = 0; q < 4; ++q) {
      int pl = m0 + wr + i * 16 + (lane >> 4) * 4 + q;
      if (pl >= c) continue;
      unsigned short* hrow = hbuf + (size_t)(base + pl) * HID + n0 + wc + (lane & 15);
#pragma unroll
      for (int j = 0; j < 4; ++j) {
        float v1 = acc1[i][j][q];
        float v3 = acc3[i][j][q];
        float hv = v1 / (1.0f + __expf(-v1)) * v3;   // silu(v1) * v3
        hrow[j * 16] = f2bf(hv);
      }
    }
}

// ---------------- GEMM2: out[tok] += w * (h @ w2), 128m x 256n tile ----------------
__global__ __launch_bounds__(256) void gemm2_kernel(const unsigned short* __restrict__ hbuf,
                                                    const unsigned short* __restrict__ w2t,
                                                    const int* __restrict__ cnt,
                                                    const int* __restrict__ offs,
                                                    const int* __restrict__ idx,
                                                    const float* __restrict__ wgt,
                                                    float* __restrict__ out) {
  int bid = blockIdx.x;
  int e = bid & 7;
  int g = bid >> 3;
  int n0 = (g >> 6) * 256;        // 4 n-tiles of 256, slow
  int m0 = (g & 63) * 128;        // 64 m-slots, fast
  int c = cnt[e];
  if (m0 >= c) return;

  __shared__ __align__(16) unsigned short As[3 * 4096];   // [128][32] x3
  __shared__ __align__(16) unsigned short Bs[3 * 8192];   // [256][32] x3

  int t = threadIdx.x;
  int wid = t >> 6, lane = t & 63;
  int wrm = (wid >> 1) * 64, wcn = (wid & 1) * 128;
  int lr = lane & 15, lk = (lane >> 4) * 8;
  int base = offs[e];

  // A staging: wave owns 32 rows (2 instrs); B staging: wave owns 64 rows (4 instrs)
  int sra = wid * 32 + (lane >> 2);
  int srb = wid * 64 + (lane >> 2);
  int sb = (lane & 3) * 8;
  size_t ha0 = (size_t)imin(base + m0 + sra, 2 * T_TOK - 1) * HID;
  size_t ha1 = (size_t)imin(base + m0 + sra + 16, 2 * T_TOK - 1) * HID;
  const unsigned short* aG0 = hbuf + ha0 + sb;
  const unsigned short* aG1 = hbuf + ha1 + sb;
  const unsigned short* w2e = w2t + ((size_t)e * DIM + n0) * HID;
  const unsigned short* bG0 = w2e + (size_t)srb * HID + sb;
  const unsigned short* bG1 = w2e + (size_t)(srb + 16) * HID + sb;
  const unsigned short* bG2 = w2e + (size_t)(srb + 32) * HID + sb;
  const unsigned short* bG3 = w2e + (size_t)(srb + 48) * HID + sb;
  int lofsA0 = wid * 1024, lofsA1 = wid * 1024 + 512;
  int lofsB0 = wid * 2048, lofsB1 = wid * 2048 + 512;
  int lofsB2 = wid * 2048 + 1024, lofsB3 = wid * 2048 + 1536;

  f32x4 acc[4][8];
#pragma unroll
  for (int i = 0; i < 4; ++i)
#pragma unroll
    for (int j = 0; j < 8; ++j) acc[i][j] = f32x4{0.f, 0.f, 0.f, 0.f};

#define STAGE2(K0, S)                                     \
  do {                                                    \
    const int boA = (S) * 4096, boB = (S) * 8192;         \
    g2l16(aG0 + (K0), As + boA + lofsA0);                 \
    g2l16(aG1 + (K0), As + boA + lofsA1);                 \
    g2l16(bG0 + (K0), Bs + boB + lofsB0);                 \
    g2l16(bG1 + (K0), Bs + boB + lofsB1);                 \
    g2l16(bG2 + (K0), Bs + boB + lofsB2);                 \
    g2l16(bG3 + (K0), Bs + boB + lofsB3);                 \
  } while (0)

#define COMPUTE2(S)                                                          \
  do {                                                                       \
    const int boA = (S) * 4096, boB = (S) * 8192;                            \
    bf16x8 a[4], b[8];                                                       \
    _Pragma("unroll") for (int f = 0; f < 4; ++f)                            \
      a[f] = *(const bf16x8*)(As + boA + (wrm + f * 16 + lr) * 32 + lk);     \
    _Pragma("unroll") for (int j = 0; j < 8; ++j)                            \
      b[j] = *(const bf16x8*)(Bs + boB + (wcn + j * 16 + lr) * 32 + lk);     \
    _Pragma("unroll") for (int i = 0; i < 4; ++i)                            \
      _Pragma("unroll") for (int j = 0; j < 8; ++j)                          \
        acc[i][j] = __builtin_amdgcn_mfma_f32_16x16x32_bf16(a[i], b[j], acc[i][j], 0, 0, 0); \
  } while (0)

  const int NK = HID / 32;   // 88
  STAGE2(0, 0);
  STAGE2(32, 1);
  int sc = 0, sp = 2;
#pragma unroll 1
  for (int ks = 0; ks < NK - 2; ++ks) {
    STAGE2((ks + 2) * 32, sp);
    WAITV(12);
    SBAR; SCHEDB;
    COMPUTE2(sc);
    SCHEDB; SBAR; SCHEDB;
    sc = sc == 2 ? 0 : sc + 1;
    sp = sp == 2 ? 0 : sp + 1;
  }
  WAITV(6);
  SBAR; SCHEDB;
  COMPUTE2(sc);
  SCHEDB; SBAR; SCHEDB;
  sc = sc == 2 ? 0 : sc + 1;
  WAITV(0);
  SBAR; SCHEDB;
  COMPUTE2(sc);

  const int* idx_e = idx + e * T_TOK;
  const float* wgt_e = wgt + e * T_TOK;
#pragma unroll
  for (int i = 0; i < 4; ++i)
#pragma unroll
    for (int q = 0; q < 4; ++q) {
      int pl = m0 + wrm + i * 16 + (lane >> 4) * 4 + q;
      if (pl >= c) continue;
      int tok = idx_e[pl];
      float w = wgt_e[pl];
      float* orow = out + (size_t)tok * DIM + n0 + wcn + (lane & 15);
#pragma unroll
      for (int j = 0; j < 8; ++j)
        atomicAdd(orow + j * 16, w * acc[i][j][q]);
    }
}

extern "C" void kernel_launch(void* const* d_in, const int* in_sizes, int n_in,
                              void* d_out, int out_size, void* d_ws, size_t ws_size,
                              hipStream_t stream) {
  const float* x  = (const float*)d_in[0];
  const float* gw = (const float*)d_in[1];
  const float* w1 = (const float*)d_in[2];
  const float* w2 = (const float*)d_in[3];
  const float* w3 = (const float*)d_in[4];
  float* out = (float*)d_out;

  // Workspace layout (~248 MB total)
  char* ws = (char*)d_ws;
  size_t off = 0;
  auto alloc = [&](size_t bytes) {
    char* p = ws + off;
    off += (bytes + 255) & ~(size_t)255;
    return p;
  };
  unsigned short* xb  = (unsigned short*)alloc((size_t)T_TOK * DIM * 2);       // 16.8 MB
  unsigned short* w1t = (unsigned short*)alloc((size_t)NE * DIM * HID * 2);    // 46.1 MB  [E][H][D]
  unsigned short* w3t = (unsigned short*)alloc((size_t)NE * DIM * HID * 2);    // 46.1 MB  [E][H][D]
  unsigned short* w2t = (unsigned short*)alloc((size_t)NE * DIM * HID * 2);    // 46.1 MB  [E][D][H]
  unsigned short* hb  = (unsigned short*)alloc((size_t)2 * T_TOK * HID * 2);   // 92.3 MB
  int*   cnt  = (int*)alloc(NE * sizeof(int));
  int*   offs = (int*)alloc(NE * sizeof(int));
  int*   idx  = (int*)alloc((size_t)NE * T_TOK * sizeof(int));
  float* wgt  = (float*)alloc((size_t)NE * T_TOK * sizeof(float));

  hipMemsetAsync(d_out, 0, (size_t)out_size * sizeof(float), stream);
  hipMemsetAsync(cnt, 0, NE * sizeof(int), stream);

  cast_x_kernel<<<(T_TOK * DIM) / (256 * 8), 256, 0, stream>>>(x, xb);
  transpose_cast_kernel<<<dim3(HID / 32, DIM / 32, NE), 256, 0, stream>>>(w1, w1t, DIM, HID);
  transpose_cast_kernel<<<dim3(HID / 32, DIM / 32, NE), 256, 0, stream>>>(w3, w3t, DIM, HID);
  transpose_cast_kernel<<<dim3(DIM / 32, HID / 32, NE), 256, 0, stream>>>(w2, w2t, HID, DIM);
  router_kernel<<<T_TOK / 4, 256, 0, stream>>>(x, gw, cnt, idx, wgt);
  offsets_kernel<<<1, 64, 0, stream>>>(cnt, offs);

  gemm1_kernel<<<8 * (HID / 128) * 64, 256, 0, stream>>>(xb, w1t, w3t, cnt, offs, idx, hb);
  gemm2_kernel<<<8 * (DIM / 256) * 64, 256, 0, stream>>>(hb, w2t, cnt, offs, idx, wgt, out);
}

// Round 6
// 859.683 us; speedup vs baseline: 1.2875x; 1.2370x over previous
//
#include <hip/hip_runtime.h>
#include <math.h>

// Problem constants
#define T_TOK 8192   // B*S tokens
#define DIM   1024   // D
#define HID   2816   // H
#define NE    8      // experts
// K (top-k) = 2

typedef __attribute__((ext_vector_type(4))) float  f32x4;
typedef __attribute__((ext_vector_type(8))) __bf16 bf16x8;

__device__ __forceinline__ unsigned short f2bf(float f) {
  unsigned int u = __builtin_bit_cast(unsigned int, f);
  unsigned int r = (u + 0x7FFFu + ((u >> 16) & 1u)) >> 16;   // RTNE
  return (unsigned short)r;
}
__device__ __forceinline__ int imin(int a, int b) { return a < b ? a : b; }

// global -> LDS direct DMA, 16B per lane. LDS dest = wave-uniform base + lane*16.
typedef const __attribute__((address_space(1))) void gvoid_t;
typedef __attribute__((address_space(3))) void svoid_t;
__device__ __forceinline__ void g2l16(const void* g, void* l) {
  __builtin_amdgcn_global_load_lds((gvoid_t*)g, (svoid_t*)l, 16, 0, 0);
}

// ---------------- x -> bf16 cast ----------------
__global__ __launch_bounds__(256) void cast_x_kernel(const float* __restrict__ x,
                                                     unsigned short* __restrict__ xb) {
  size_t i = ((size_t)blockIdx.x * 256 + threadIdx.x) * 8;
  float4 a = *(const float4*)(x + i);
  float4 b = *(const float4*)(x + i + 4);
  typedef __attribute__((ext_vector_type(8))) unsigned short u16x8;
  u16x8 v;
  v[0] = f2bf(a.x); v[1] = f2bf(a.y); v[2] = f2bf(a.z); v[3] = f2bf(a.w);
  v[4] = f2bf(b.x); v[5] = f2bf(b.y); v[6] = f2bf(b.z); v[7] = f2bf(b.w);
  *(u16x8*)(xb + i) = v;
}

// ------------- fp32 [E][R][C] -> bf16 [E][C][R] transpose-cast -------------
__global__ __launch_bounds__(256) void transpose_cast_kernel(const float* __restrict__ src,
                                                             unsigned short* __restrict__ dst,
                                                             int R, int C) {
  __shared__ float tile[32][33];
  int e = blockIdx.z;
  const float* s = src + (size_t)e * R * C;
  unsigned short* d = dst + (size_t)e * R * C;
  int tx = threadIdx.x & 31, ty = threadIdx.x >> 5;
  int r0 = blockIdx.y * 32, c0 = blockIdx.x * 32;
#pragma unroll
  for (int j = 0; j < 4; ++j)
    tile[ty + 8 * j][tx] = s[(size_t)(r0 + ty + 8 * j) * C + c0 + tx];
  __syncthreads();
#pragma unroll
  for (int j = 0; j < 4; ++j)
    d[(size_t)(c0 + ty + 8 * j) * R + r0 + tx] = f2bf(tile[tx][ty + 8 * j]);
}

// ---------------- router: scores (fp64), top-2, softmax, compact ----------------
__global__ __launch_bounds__(256) void router_kernel(const float* __restrict__ x,
                                                     const float* __restrict__ gw,
                                                     int* __restrict__ cnt,
                                                     int* __restrict__ idx,
                                                     float* __restrict__ wgt) {
  int wid = threadIdx.x >> 6;
  int lane = threadIdx.x & 63;
  int t = blockIdx.x * 4 + wid;
  double acc[NE];
#pragma unroll
  for (int e = 0; e < NE; ++e) acc[e] = 0.0;
  const float* xr = x + (size_t)t * DIM;
#pragma unroll 4
  for (int i = 0; i < DIM / 64; ++i) {
    int d = i * 64 + lane;
    double xv = (double)xr[d];
#pragma unroll
    for (int e = 0; e < NE; ++e) acc[e] += xv * (double)gw[e * DIM + d];
  }
#pragma unroll
  for (int e = 0; e < NE; ++e) {
#pragma unroll
    for (int off = 32; off >= 1; off >>= 1) acc[e] += __shfl_xor(acc[e], off);
  }
  if (lane == 0) {
    int e0 = 0; double s0 = acc[0];
#pragma unroll
    for (int e = 1; e < NE; ++e) if (acc[e] > s0) { s0 = acc[e]; e0 = e; }
    int e1 = -1; double s1 = -1.0e300;
#pragma unroll
    for (int e = 0; e < NE; ++e) if (e != e0 && acc[e] > s1) { s1 = acc[e]; e1 = e; }
    double w0 = 1.0 / (1.0 + exp(s1 - s0));   // softmax over {s0,s1}, s0 >= s1
    int p0 = atomicAdd(&cnt[e0], 1);
    idx[e0 * T_TOK + p0] = t; wgt[e0 * T_TOK + p0] = (float)w0;
    int p1 = atomicAdd(&cnt[e1], 1);
    idx[e1 * T_TOK + p1] = t; wgt[e1 * T_TOK + p1] = (float)(1.0 - w0);
  }
}

// ------------- prep: offsets + compact tile lists (sorted e,n,m) -------------
// tl entry = (e<<16)|(n<<8)|m.  ntl[0] = #gemm1 tiles, ntl[1] = #gemm2 tiles.
__global__ __launch_bounds__(256) void prep_kernel(const int* __restrict__ cnt,
                                                   int* __restrict__ offs,
                                                   int* __restrict__ ntl,
                                                   int* __restrict__ tl1,
                                                   int* __restrict__ tl2) {
  __shared__ int smt[NE], stb1[NE + 1], stb2[NE + 1];
  if (threadIdx.x == 0) {
    int s = 0, t1 = 0, t2 = 0;
    for (int e = 0; e < NE; ++e) {
      offs[e] = s; s += cnt[e];
      int mt = (cnt[e] + 127) >> 7;
      smt[e] = mt;
      stb1[e] = t1; t1 += mt * (HID / 128);
      stb2[e] = t2; t2 += mt * (DIM / 128);
    }
    stb1[NE] = t1; stb2[NE] = t2;
    ntl[0] = t1; ntl[1] = t2;
  }
  __syncthreads();
  for (int k = threadIdx.x; k < stb1[NE]; k += 256) {
    int e = 0;
    while (e < NE - 1 && k >= stb1[e + 1]) ++e;
    int rem = k - stb1[e], mt = smt[e];
    int n = rem / mt, m = rem - n * mt;
    tl1[k] = (e << 16) | (n << 8) | m;
  }
  for (int k = threadIdx.x; k < stb2[NE]; k += 256) {
    int e = 0;
    while (e < NE - 1 && k >= stb2[e + 1]) ++e;
    int rem = k - stb2[e], mt = smt[e];
    int n = rem / mt, m = rem - n * mt;
    tl2[k] = (e << 16) | (n << 8) | m;
  }
}

// Bijective XCD-chunk decode (m204): consecutive bids round-robin XCDs, so each
// XCD gets a contiguous chunk of the (e,n,m)-sorted list. Dead blocks = tail bids.
__device__ __forceinline__ bool tile_decode(const int* ntl, int slot, const int* tl,
                                            int& e, int& n0, int& m0) {
  int nt = ntl[slot];
  int q = nt >> 3, r = nt & 7;
  int xcd = blockIdx.x & 7, pos = blockIdx.x >> 3;
  int cap = xcd < r ? q + 1 : q;
  if (pos >= cap) return false;
  int lid = (xcd < r ? xcd * (q + 1) : r * (q + 1) + (xcd - r) * q) + pos;
  int ent = tl[lid];
  e = ent >> 16;
  n0 = ((ent >> 8) & 255) * 128;
  m0 = (ent & 255) * 128;
  return true;
}

// ---------------- GEMM1: h = silu(Xg @ w1) * (Xg @ w3), bf16 out ----------------
// r3-proven 2-phase dbuf K-loop; compact-list grid.
__global__ __launch_bounds__(256) void gemm1_kernel(const unsigned short* __restrict__ xb,
                                                    const unsigned short* __restrict__ w1t,
                                                    const unsigned short* __restrict__ w3t,
                                                    const int* __restrict__ cnt,
                                                    const int* __restrict__ offs,
                                                    const int* __restrict__ ntl,
                                                    const int* __restrict__ tl1,
                                                    const int* __restrict__ idx,
                                                    unsigned short* __restrict__ hbuf) {
  int e, n0, m0;
  if (!tile_decode(ntl, 0, tl1, e, n0, m0)) return;
  int c = cnt[e];

  __shared__ __align__(16) unsigned short As[2 * 4096];
  __shared__ __align__(16) unsigned short B1s[2 * 4096];
  __shared__ __align__(16) unsigned short B3s[2 * 4096];

  int t = threadIdx.x;
  int wid = t >> 6, lane = t & 63;
  int wr = (wid >> 1) * 64, wc = (wid & 1) * 64;
  int lr = lane & 15, lk = (lane >> 4) * 8;

  // staging: wave `wid` owns rows [wid*32, wid*32+32), 2 DMA instrs of 16 rows
  int sr0 = wid * 32 + (lane >> 2);
  int sr1 = sr0 + 16;
  int sb = (lane & 3) * 8;    // elem offset within 32-elem row
  const int* idx_e = idx + e * T_TOK;
  int tokA0 = (m0 + sr0 < c) ? idx_e[m0 + sr0] : 0;
  int tokA1 = (m0 + sr1 < c) ? idx_e[m0 + sr1] : 0;
  const unsigned short* aG0 = xb + (size_t)tokA0 * DIM + sb;
  const unsigned short* aG1 = xb + (size_t)tokA1 * DIM + sb;
  const unsigned short* w1e = w1t + ((size_t)e * HID + n0) * DIM;
  const unsigned short* w3e = w3t + ((size_t)e * HID + n0) * DIM;
  const unsigned short* b1G0 = w1e + (size_t)sr0 * DIM + sb;
  const unsigned short* b1G1 = w1e + (size_t)sr1 * DIM + sb;
  const unsigned short* b3G0 = w3e + (size_t)sr0 * DIM + sb;
  const unsigned short* b3G1 = w3e + (size_t)sr1 * DIM + sb;
  int lofs0 = wid * 1024;          // elems within a 4096-elem buffer
  int lofs1 = wid * 1024 + 512;

  f32x4 acc1[4][4], acc3[4][4];
#pragma unroll
  for (int i = 0; i < 4; ++i)
#pragma unroll
    for (int j = 0; j < 4; ++j) {
      acc1[i][j] = f32x4{0.f, 0.f, 0.f, 0.f};
      acc3[i][j] = f32x4{0.f, 0.f, 0.f, 0.f};
    }

#define STAGE1(K0, BUF)                                   \
  do {                                                    \
    int bo = (BUF) * 4096;                                \
    g2l16(aG0 + (K0), As + bo + lofs0);                   \
    g2l16(aG1 + (K0), As + bo + lofs1);                   \
    g2l16(b1G0 + (K0), B1s + bo + lofs0);                 \
    g2l16(b1G1 + (K0), B1s + bo + lofs1);                 \
    g2l16(b3G0 + (K0), B3s + bo + lofs0);                 \
    g2l16(b3G1 + (K0), B3s + bo + lofs1);                 \
  } while (0)

  STAGE1(0, 0);
  __syncthreads();          // vmcnt(0) drain: buf0 ready
  int cur = 0;

  const int NK = DIM / 32;
  for (int ks = 0; ks < NK; ++ks) {
    if (ks + 1 < NK) STAGE1((ks + 1) * 32, cur ^ 1);   // in flight under compute

    int bo = cur * 4096;
    bf16x8 a[4], b1[4], b3[4];
#pragma unroll
    for (int f = 0; f < 4; ++f) {
      a[f]  = *(const bf16x8*)(As  + bo + (wr + f * 16 + lr) * 32 + lk);
      b1[f] = *(const bf16x8*)(B1s + bo + (wc + f * 16 + lr) * 32 + lk);
      b3[f] = *(const bf16x8*)(B3s + bo + (wc + f * 16 + lr) * 32 + lk);
    }
#pragma unroll
    for (int i = 0; i < 4; ++i)
#pragma unroll
      for (int j = 0; j < 4; ++j) {
        acc1[i][j] = __builtin_amdgcn_mfma_f32_16x16x32_bf16(a[i], b1[j], acc1[i][j], 0, 0, 0);
        acc3[i][j] = __builtin_amdgcn_mfma_f32_16x16x32_bf16(a[i], b3[j], acc3[i][j], 0, 0, 0);
      }
    __syncthreads();        // drains vmcnt(0): next buf ready; all readers done with cur
    cur ^= 1;
  }

  int base = offs[e];
#pragma unroll
  for (int i = 0; i < 4; ++i)
#pragma unroll
    for (int q = 0; q < 4; ++q) {
      int pl = m0 + wr + i * 16 + (lane >> 4) * 4 + q;
      if (pl >= c) continue;
      unsigned short* hrow = hbuf + (size_t)(base + pl) * HID + n0 + wc + (lane & 15);
#pragma unroll
      for (int j = 0; j < 4; ++j) {
        float v1 = acc1[i][j][q];
        float v3 = acc3[i][j][q];
        float hv = v1 / (1.0f + __expf(-v1)) * v3;   // silu(v1) * v3
        hrow[j * 16] = f2bf(hv);
      }
    }
}

// ---------------- GEMM2: out[tok] += w * (h @ w2) ----------------
__global__ __launch_bounds__(256) void gemm2_kernel(const unsigned short* __restrict__ hbuf,
                                                    const unsigned short* __restrict__ w2t,
                                                    const int* __restrict__ cnt,
                                                    const int* __restrict__ offs,
                                                    const int* __restrict__ ntl,
                                                    const int* __restrict__ tl2,
                                                    const int* __restrict__ idx,
                                                    const float* __restrict__ wgt,
                                                    float* __restrict__ out) {
  int e, n0, m0;
  if (!tile_decode(ntl, 1, tl2, e, n0, m0)) return;
  int c = cnt[e];

  __shared__ __align__(16) unsigned short As[2 * 4096];
  __shared__ __align__(16) unsigned short Bs[2 * 4096];

  int t = threadIdx.x;
  int wid = t >> 6, lane = t & 63;
  int wr = (wid >> 1) * 64, wc = (wid & 1) * 64;
  int lr = lane & 15, lk = (lane >> 4) * 8;
  int base = offs[e];

  int sr0 = wid * 32 + (lane >> 2);
  int sr1 = sr0 + 16;
  int sb = (lane & 3) * 8;
  size_t ha0 = (size_t)imin(base + m0 + sr0, 2 * T_TOK - 1) * HID;
  size_t ha1 = (size_t)imin(base + m0 + sr1, 2 * T_TOK - 1) * HID;
  const unsigned short* aG0 = hbuf + ha0 + sb;
  const unsigned short* aG1 = hbuf + ha1 + sb;
  const unsigned short* w2e = w2t + ((size_t)e * DIM + n0) * HID;
  const unsigned short* bG0 = w2e + (size_t)sr0 * HID + sb;
  const unsigned short* bG1 = w2e + (size_t)sr1 * HID + sb;
  int lofs0 = wid * 1024;
  int lofs1 = wid * 1024 + 512;

  f32x4 acc[4][4];
#pragma unroll
  for (int i = 0; i < 4; ++i)
#pragma unroll
    for (int j = 0; j < 4; ++j) acc[i][j] = f32x4{0.f, 0.f, 0.f, 0.f};

#define STAGE2(K0, BUF)                                   \
  do {                                                    \
    int bo = (BUF) * 4096;                                \
    g2l16(aG0 + (K0), As + bo + lofs0);                   \
    g2l16(aG1 + (K0), As + bo + lofs1);                   \
    g2l16(bG0 + (K0), Bs + bo + lofs0);                   \
    g2l16(bG1 + (K0), Bs + bo + lofs1);                   \
  } while (0)

  STAGE2(0, 0);
  __syncthreads();
  int cur = 0;

  const int NK = HID / 32;
  for (int ks = 0; ks < NK; ++ks) {
    if (ks + 1 < NK) STAGE2((ks + 1) * 32, cur ^ 1);

    int bo = cur * 4096;
    bf16x8 a[4], b[4];
#pragma unroll
    for (int f = 0; f < 4; ++f) {
      a[f] = *(const bf16x8*)(As + bo + (wr + f * 16 + lr) * 32 + lk);
      b[f] = *(const bf16x8*)(Bs + bo + (wc + f * 16 + lr) * 32 + lk);
    }
#pragma unroll
    for (int i = 0; i < 4; ++i)
#pragma unroll
      for (int j = 0; j < 4; ++j)
        acc[i][j] = __builtin_amdgcn_mfma_f32_16x16x32_bf16(a[i], b[j], acc[i][j], 0, 0, 0);
    __syncthreads();
    cur ^= 1;
  }

  const int* idx_e = idx + e * T_TOK;
  const float* wgt_e = wgt + e * T_TOK;
#pragma unroll
  for (int i = 0; i < 4; ++i)
#pragma unroll
    for (int q = 0; q < 4; ++q) {
      int pl = m0 + wr + i * 16 + (lane >> 4) * 4 + q;
      if (pl >= c) continue;
      int tok = idx_e[pl];
      float w = wgt_e[pl];
      float* orow = out + (size_t)tok * DIM + n0 + wc + (lane & 15);
#pragma unroll
      for (int j = 0; j < 4; ++j)
        atomicAdd(orow + j * 16, w * acc[i][j][q]);
    }
}

extern "C" void kernel_launch(void* const* d_in, const int* in_sizes, int n_in,
                              void* d_out, int out_size, void* d_ws, size_t ws_size,
                              hipStream_t stream) {
  const float* x  = (const float*)d_in[0];
  const float* gw = (const float*)d_in[1];
  const float* w1 = (const float*)d_in[2];
  const float* w2 = (const float*)d_in[3];
  const float* w3 = (const float*)d_in[4];
  float* out = (float*)d_out;

  // Workspace layout (~249 MB total)
  char* ws = (char*)d_ws;
  size_t off = 0;
  auto alloc = [&](size_t bytes) {
    char* p = ws + off;
    off += (bytes + 255) & ~(size_t)255;
    return p;
  };
  unsigned short* xb  = (unsigned short*)alloc((size_t)T_TOK * DIM * 2);       // 16.8 MB
  unsigned short* w1t = (unsigned short*)alloc((size_t)NE * DIM * HID * 2);    // 46.1 MB  [E][H][D]
  unsigned short* w3t = (unsigned short*)alloc((size_t)NE * DIM * HID * 2);    // 46.1 MB  [E][H][D]
  unsigned short* w2t = (unsigned short*)alloc((size_t)NE * DIM * HID * 2);    // 46.1 MB  [E][D][H]
  unsigned short* hb  = (unsigned short*)alloc((size_t)2 * T_TOK * HID * 2);   // 92.3 MB
  int*   cnt  = (int*)alloc(NE * sizeof(int));
  int*   offs = (int*)alloc(NE * sizeof(int));
  int*   ntl  = (int*)alloc(2 * sizeof(int));
  int*   idx  = (int*)alloc((size_t)NE * T_TOK * sizeof(int));
  float* wgt  = (float*)alloc((size_t)NE * T_TOK * sizeof(float));
  int*   tl1  = (int*)alloc((size_t)NE * 64 * (HID / 128) * sizeof(int));     // 45 KB
  int*   tl2  = (int*)alloc((size_t)NE * 64 * (DIM / 128) * sizeof(int));     // 16 KB

  hipMemsetAsync(d_out, 0, (size_t)out_size * sizeof(float), stream);
  hipMemsetAsync(cnt, 0, NE * sizeof(int), stream);

  cast_x_kernel<<<(T_TOK * DIM) / (256 * 8), 256, 0, stream>>>(x, xb);
  transpose_cast_kernel<<<dim3(HID / 32, DIM / 32, NE), 256, 0, stream>>>(w1, w1t, DIM, HID);
  transpose_cast_kernel<<<dim3(HID / 32, DIM / 32, NE), 256, 0, stream>>>(w3, w3t, DIM, HID);
  transpose_cast_kernel<<<dim3(DIM / 32, HID / 32, NE), 256, 0, stream>>>(w2, w2t, HID, DIM);
  router_kernel<<<T_TOK / 4, 256, 0, stream>>>(x, gw, cnt, idx, wgt);
  prep_kernel<<<1, 256, 0, stream>>>(cnt, offs, ntl, tl1, tl2);

  gemm1_kernel<<<NE * 64 * (HID / 128), 256, 0, stream>>>(xb, w1t, w3t, cnt, offs, ntl, tl1, idx, hb);
  gemm2_kernel<<<NE * 64 * (DIM / 128), 256, 0, stream>>>(hb, w2t, cnt, offs, ntl, tl2, idx, wgt, out);
}

// Round 7
// 771.989 us; speedup vs baseline: 1.4338x; 1.1136x over previous
//
#include <hip/hip_runtime.h>
#include <math.h>

// Problem constants
#define T_TOK 8192   // B*S tokens
#define DIM   1024   // D
#define HID   2816   // H
#define NE    8      // experts
// K (top-k) = 2

typedef __attribute__((ext_vector_type(4))) float  f32x4;
typedef __attribute__((ext_vector_type(8))) __bf16 bf16x8;

__device__ __forceinline__ unsigned short f2bf(float f) {
  unsigned int u = __builtin_bit_cast(unsigned int, f);
  unsigned int r = (u + 0x7FFFu + ((u >> 16) & 1u)) >> 16;   // RTNE
  return (unsigned short)r;
}
__device__ __forceinline__ int imin(int a, int b) { return a < b ? a : b; }

// global -> LDS direct DMA, 16B per lane. LDS dest = wave-uniform base + lane*16.
typedef const __attribute__((address_space(1))) void gvoid_t;
typedef __attribute__((address_space(3))) void svoid_t;
__device__ __forceinline__ void g2l16(const void* g, void* l) {
  __builtin_amdgcn_global_load_lds((gvoid_t*)g, (svoid_t*)l, 16, 0, 0);
}

// Pipeline fences (T3/T4): raw s_barrier + counted waits; sched_barrier pins motion.
#define WAITV0 asm volatile("s_waitcnt vmcnt(0)" ::: "memory")
#define LGKM0  asm volatile("s_waitcnt lgkmcnt(0)" ::: "memory")
#define FENCE  asm volatile("" ::: "memory")
#define SBAR   __builtin_amdgcn_s_barrier()
#define SCHED0 __builtin_amdgcn_sched_barrier(0)
#define PRIO(x) __builtin_amdgcn_s_setprio(x)
#define PH_PRE  do { FENCE; SBAR; LGKM0; SCHED0; PRIO(1); } while (0)
#define PH_POST do { PRIO(0); FENCE; SBAR; SCHED0; } while (0)

// ---------------- x -> bf16 cast ----------------
__global__ __launch_bounds__(256) void cast_x_kernel(const float* __restrict__ x,
                                                     unsigned short* __restrict__ xb) {
  size_t i = ((size_t)blockIdx.x * 256 + threadIdx.x) * 8;
  float4 a = *(const float4*)(x + i);
  float4 b = *(const float4*)(x + i + 4);
  typedef __attribute__((ext_vector_type(8))) unsigned short u16x8;
  u16x8 v;
  v[0] = f2bf(a.x); v[1] = f2bf(a.y); v[2] = f2bf(a.z); v[3] = f2bf(a.w);
  v[4] = f2bf(b.x); v[5] = f2bf(b.y); v[6] = f2bf(b.z); v[7] = f2bf(b.w);
  *(u16x8*)(xb + i) = v;
}

// ------------- fp32 [E][R][C] -> bf16 [E][C][R] transpose-cast -------------
__global__ __launch_bounds__(256) void transpose_cast_kernel(const float* __restrict__ src,
                                                             unsigned short* __restrict__ dst,
                                                             int R, int C) {
  __shared__ float tile[32][33];
  int e = blockIdx.z;
  const float* s = src + (size_t)e * R * C;
  unsigned short* d = dst + (size_t)e * R * C;
  int tx = threadIdx.x & 31, ty = threadIdx.x >> 5;
  int r0 = blockIdx.y * 32, c0 = blockIdx.x * 32;
#pragma unroll
  for (int j = 0; j < 4; ++j)
    tile[ty + 8 * j][tx] = s[(size_t)(r0 + ty + 8 * j) * C + c0 + tx];
  __syncthreads();
#pragma unroll
  for (int j = 0; j < 4; ++j)
    d[(size_t)(c0 + ty + 8 * j) * R + r0 + tx] = f2bf(tile[tx][ty + 8 * j]);
}

// ---------------- router: scores (fp64), top-2, softmax, compact ----------------
__global__ __launch_bounds__(256) void router_kernel(const float* __restrict__ x,
                                                     const float* __restrict__ gw,
                                                     int* __restrict__ cnt,
                                                     int* __restrict__ idx,
                                                     float* __restrict__ wgt) {
  int wid = threadIdx.x >> 6;
  int lane = threadIdx.x & 63;
  int t = blockIdx.x * 4 + wid;
  double acc[NE];
#pragma unroll
  for (int e = 0; e < NE; ++e) acc[e] = 0.0;
  const float* xr = x + (size_t)t * DIM;
#pragma unroll 4
  for (int i = 0; i < DIM / 64; ++i) {
    int d = i * 64 + lane;
    double xv = (double)xr[d];
#pragma unroll
    for (int e = 0; e < NE; ++e) acc[e] += xv * (double)gw[e * DIM + d];
  }
#pragma unroll
  for (int e = 0; e < NE; ++e) {
#pragma unroll
    for (int off = 32; off >= 1; off >>= 1) acc[e] += __shfl_xor(acc[e], off);
  }
  if (lane == 0) {
    int e0 = 0; double s0 = acc[0];
#pragma unroll
    for (int e = 1; e < NE; ++e) if (acc[e] > s0) { s0 = acc[e]; e0 = e; }
    int e1 = -1; double s1 = -1.0e300;
#pragma unroll
    for (int e = 0; e < NE; ++e) if (e != e0 && acc[e] > s1) { s1 = acc[e]; e1 = e; }
    double w0 = 1.0 / (1.0 + exp(s1 - s0));   // softmax over {s0,s1}, s0 >= s1
    int p0 = atomicAdd(&cnt[e0], 1);
    idx[e0 * T_TOK + p0] = t; wgt[e0 * T_TOK + p0] = (float)w0;
    int p1 = atomicAdd(&cnt[e1], 1);
    idx[e1 * T_TOK + p1] = t; wgt[e1 * T_TOK + p1] = (float)(1.0 - w0);
  }
}

// ------------- prep: offsets + compact tile lists (sorted e,n,m; BM=256) -------------
// tl entry = (e<<16)|(n<<8)|m.  ntl[0] = #gemm1 tiles, ntl[1] = #gemm2 tiles.
#define NT1 (HID / 128)   // 22
#define NT2 (DIM / 128)   // 8
__global__ __launch_bounds__(256) void prep_kernel(const int* __restrict__ cnt,
                                                   int* __restrict__ offs,
                                                   int* __restrict__ ntl,
                                                   int* __restrict__ tl1,
                                                   int* __restrict__ tl2) {
  __shared__ int smt[NE], stb1[NE + 1], stb2[NE + 1];
  if (threadIdx.x == 0) {
    int s = 0, t1 = 0, t2 = 0;
    for (int e = 0; e < NE; ++e) {
      offs[e] = s; s += cnt[e];
      int mt = (cnt[e] + 255) >> 8;
      smt[e] = mt;
      stb1[e] = t1; t1 += mt * NT1;
      stb2[e] = t2; t2 += mt * NT2;
    }
    stb1[NE] = t1; stb2[NE] = t2;
    ntl[0] = t1; ntl[1] = t2;
  }
  __syncthreads();
  for (int k = threadIdx.x; k < stb1[NE]; k += 256) {
    int e = 0;
    while (e < NE - 1 && k >= stb1[e + 1]) ++e;
    int rem = k - stb1[e], mt = smt[e];
    int n = rem / mt, m = rem - n * mt;
    tl1[k] = (e << 16) | (n << 8) | m;
  }
  for (int k = threadIdx.x; k < stb2[NE]; k += 256) {
    int e = 0;
    while (e < NE - 1 && k >= stb2[e + 1]) ++e;
    int rem = k - stb2[e], mt = smt[e];
    int n = rem / mt, m = rem - n * mt;
    tl2[k] = (e << 16) | (n << 8) | m;
  }
}

// Bijective XCD-chunk decode (m204): each XCD gets a contiguous chunk of the
// (e,n,m)-sorted list. Dead blocks = dispatch tail.
__device__ __forceinline__ bool tile_decode(const int* ntl, int slot, const int* tl,
                                            int& e, int& n0, int& m0) {
  int nt = ntl[slot];
  int q = nt >> 3, r = nt & 7;
  int xcd = blockIdx.x & 7, pos = blockIdx.x >> 3;
  int cap = xcd < r ? q + 1 : q;
  if (pos >= cap) return false;
  int lid = (xcd < r ? xcd * (q + 1) : r * (q + 1) + (xcd - r) * q) + pos;
  int ent = tl[lid];
  e = ent >> 16;
  n0 = ((ent >> 8) & 255) * 128;
  m0 = (ent & 255) * 256;
  return true;
}

// ============ GEMM1: h = silu(Xg @ w1) * (Xg @ w3) — 8-phase template ============
// BM=256, BN=128 (dual-B), BK=64, 8 waves (2M x 4N), dbuf LDS 128KB.
// T2 swizzle via rule #21: linear LDS dest, global source k-chunk = (t&7)^((t>>3)&7),
// read k-chunk xor (lane&7).
__global__ __launch_bounds__(512, 1) void gemm1_kernel(const unsigned short* __restrict__ xb,
                                                       const unsigned short* __restrict__ w1t,
                                                       const unsigned short* __restrict__ w3t,
                                                       const int* __restrict__ cnt,
                                                       const int* __restrict__ offs,
                                                       const int* __restrict__ ntl,
                                                       const int* __restrict__ tl1,
                                                       const int* __restrict__ idx,
                                                       unsigned short* __restrict__ hbuf) {
  int e, n0, m0;
  if (!tile_decode(ntl, 0, tl1, e, n0, m0)) return;
  int c = cnt[e];

  __shared__ __align__(16) unsigned short As[2 * 16384];   // [2][256][64]
  __shared__ __align__(16) unsigned short B1s[2 * 8192];   // [2][128][64]
  __shared__ __align__(16) unsigned short B3s[2 * 8192];

  const int t = threadIdx.x;
  const int wid = t >> 6, lane = t & 63;
  const int wm = wid >> 2, wn = wid & 3;
  const int lr = lane & 15, kc = lane >> 4, sw = lane & 7;
  const int ldst = wid * 512;           // wave-uniform elems within an 8KB instr chunk
  const int trow = t >> 3;              // 0..63
  const int swzk = ((t & 7) ^ ((t >> 3) & 7)) * 8;   // pre-swizzled source k-chunk

  const int* idx_e = idx + e * T_TOK;
  int g0 = m0 + trow, g1 = m0 + 64 + trow, g2 = m0 + 128 + trow, g3 = m0 + 192 + trow;
  int tk0 = (g0 < c) ? idx_e[g0] : 0;
  int tk1 = (g1 < c) ? idx_e[g1] : 0;
  int tk2 = (g2 < c) ? idx_e[g2] : 0;
  int tk3 = (g3 < c) ? idx_e[g3] : 0;
  const unsigned short* aS0 = xb + (size_t)tk0 * DIM + swzk;
  const unsigned short* aS1 = xb + (size_t)tk1 * DIM + swzk;
  const unsigned short* aS2 = xb + (size_t)tk2 * DIM + swzk;
  const unsigned short* aS3 = xb + (size_t)tk3 * DIM + swzk;
  const unsigned short* w1e = w1t + ((size_t)e * HID + n0) * DIM;
  const unsigned short* w3e = w3t + ((size_t)e * HID + n0) * DIM;
  const unsigned short* b1S0 = w1e + (size_t)trow * DIM + swzk;
  const unsigned short* b1S1 = w1e + (size_t)(64 + trow) * DIM + swzk;
  const unsigned short* b3S0 = w3e + (size_t)trow * DIM + swzk;
  const unsigned short* b3S1 = w3e + (size_t)(64 + trow) * DIM + swzk;

  f32x4 acc1[8][2], acc3[8][2];
#pragma unroll
  for (int i = 0; i < 8; ++i)
#pragma unroll
    for (int j = 0; j < 2; ++j) {
      acc1[i][j] = f32x4{0.f, 0.f, 0.f, 0.f};
      acc3[i][j] = f32x4{0.f, 0.f, 0.f, 0.f};
    }
  bf16x8 ra[4], rb1[2], rb3[2];

#define G1_STG_A(CUR, TILE) do {                                      \
    g2l16(aS0 + (TILE) * 64, As + (CUR) * 16384 + 0 * 4096 + ldst);   \
    g2l16(aS1 + (TILE) * 64, As + (CUR) * 16384 + 1 * 4096 + ldst);   \
    g2l16(aS2 + (TILE) * 64, As + (CUR) * 16384 + 2 * 4096 + ldst);   \
    g2l16(aS3 + (TILE) * 64, As + (CUR) * 16384 + 3 * 4096 + ldst);   \
  } while (0)
#define G1_STG_B(CUR, TILE) do {                                      \
    g2l16(b1S0 + (TILE) * 64, B1s + (CUR) * 8192 + 0 * 4096 + ldst);  \
    g2l16(b1S1 + (TILE) * 64, B1s + (CUR) * 8192 + 1 * 4096 + ldst);  \
    g2l16(b3S0 + (TILE) * 64, B3s + (CUR) * 8192 + 0 * 4096 + ldst);  \
    g2l16(b3S1 + (TILE) * 64, B3s + (CUR) * 8192 + 1 * 4096 + ldst);  \
  } while (0)
#define G1_LDB(CUR, KS2) do {                                                          \
    const int se = ((((KS2) * 4) + kc) ^ sw) * 8;                                      \
    rb1[0] = *(const bf16x8*)(B1s + (CUR) * 8192 + (wn * 32 + lr) * 64 + se);          \
    rb1[1] = *(const bf16x8*)(B1s + (CUR) * 8192 + (wn * 32 + 16 + lr) * 64 + se);     \
    rb3[0] = *(const bf16x8*)(B3s + (CUR) * 8192 + (wn * 32 + lr) * 64 + se);          \
    rb3[1] = *(const bf16x8*)(B3s + (CUR) * 8192 + (wn * 32 + 16 + lr) * 64 + se);     \
  } while (0)
#define G1_LDA(CUR, KS2, IH) do {                                                      \
    const int se = ((((KS2) * 4) + kc) ^ sw) * 8;                                      \
    const int ab = (CUR) * 16384 + (wm * 128 + lr) * 64 + (IH) * 4096 + se;            \
    ra[0] = *(const bf16x8*)(As + ab + 0 * 1024);                                      \
    ra[1] = *(const bf16x8*)(As + ab + 1 * 1024);                                      \
    ra[2] = *(const bf16x8*)(As + ab + 2 * 1024);                                      \
    ra[3] = *(const bf16x8*)(As + ab + 3 * 1024);                                      \
  } while (0)
#define G1_MM(IH) do {                                                                 \
    _Pragma("unroll") for (int f = 0; f < 4; ++f)                                      \
      _Pragma("unroll") for (int j = 0; j < 2; ++j) {                                  \
        acc1[(IH) * 4 + f][j] =                                                        \
            __builtin_amdgcn_mfma_f32_16x16x32_bf16(ra[f], rb1[j], acc1[(IH) * 4 + f][j], 0, 0, 0); \
        acc3[(IH) * 4 + f][j] =                                                        \
            __builtin_amdgcn_mfma_f32_16x16x32_bf16(ra[f], rb3[j], acc3[(IH) * 4 + f][j], 0, 0, 0); \
      }                                                                                \
  } while (0)
#define G1_ITER(CUR, KT, DOSTAGE) do {                                                 \
    G1_LDB(CUR, 0); G1_LDA(CUR, 0, 0);                                                 \
    if (DOSTAGE) G1_STG_A((CUR) ^ 1, (KT) + 1);                                        \
    PH_PRE; G1_MM(0); PH_POST;                                                         \
    G1_LDA(CUR, 0, 1);                                                                 \
    if (DOSTAGE) G1_STG_B((CUR) ^ 1, (KT) + 1);                                        \
    PH_PRE; G1_MM(1); PH_POST;                                                         \
    G1_LDB(CUR, 1); G1_LDA(CUR, 1, 0);                                                 \
    PH_PRE; G1_MM(0); PH_POST;                                                         \
    G1_LDA(CUR, 1, 1);                                                                 \
    FENCE; SBAR; LGKM0; SCHED0; PRIO(1); G1_MM(1); PRIO(0);                            \
    WAITV0; FENCE; SBAR; SCHED0;                                                       \
  } while (0)

  // prologue: tile 0 -> buf 0, drain, barrier
  G1_STG_A(0, 0); G1_STG_B(0, 0);
  WAITV0; FENCE; SBAR; SCHED0;

  const int NK = DIM / 64;   // 16
#pragma unroll 1
  for (int kt = 0; kt < NK; kt += 2) {
    G1_ITER(0, kt, true);                    // kt+1 < NK always (kt <= NK-2)
    G1_ITER(1, kt + 1, (kt + 2) < NK);
  }

  int base = offs[e];
#pragma unroll
  for (int i = 0; i < 8; ++i)
#pragma unroll
    for (int q = 0; q < 4; ++q) {
      int pl = m0 + wm * 128 + i * 16 + kc * 4 + q;
      if (pl >= c) continue;
      unsigned short* hrow = hbuf + (size_t)(base + pl) * HID + n0 + wn * 32 + lr;
#pragma unroll
      for (int j = 0; j < 2; ++j) {
        float v1 = acc1[i][j][q];
        float v3 = acc3[i][j][q];
        float hv = v1 / (1.0f + __expf(-v1)) * v3;   // silu(v1) * v3
        hrow[j * 16] = f2bf(hv);
      }
    }
}

// ============ GEMM2: out[tok] += w * (h @ w2) — 8-phase template ============
// BM=256, BN=128, BK=64, 8 waves (2M x 4N), dbuf LDS 96KB, 2 phases/K-tile.
__global__ __launch_bounds__(512, 1) void gemm2_kernel(const unsigned short* __restrict__ hbuf,
                                                       const unsigned short* __restrict__ w2t,
                                                       const int* __restrict__ cnt,
                                                       const int* __restrict__ offs,
                                                       const int* __restrict__ ntl,
                                                       const int* __restrict__ tl2,
                                                       const int* __restrict__ idx,
                                                       const float* __restrict__ wgt,
                                                       float* __restrict__ out) {
  int e, n0, m0;
  if (!tile_decode(ntl, 1, tl2, e, n0, m0)) return;
  int c = cnt[e];
  int base = offs[e];

  __shared__ __align__(16) unsigned short As[2 * 16384];   // [2][256][64]
  __shared__ __align__(16) unsigned short Bs[2 * 8192];    // [2][128][64]

  const int t = threadIdx.x;
  const int wid = t >> 6, lane = t & 63;
  const int wm = wid >> 2, wn = wid & 3;
  const int lr = lane & 15, kc = lane >> 4, sw = lane & 7;
  const int ldst = wid * 512;
  const int trow = t >> 3;
  const int swzk = ((t & 7) ^ ((t >> 3) & 7)) * 8;

  int r0 = imin(base + m0 + trow,       2 * T_TOK - 1);
  int r1 = imin(base + m0 + 64 + trow,  2 * T_TOK - 1);
  int r2 = imin(base + m0 + 128 + trow, 2 * T_TOK - 1);
  int r3 = imin(base + m0 + 192 + trow, 2 * T_TOK - 1);
  const unsigned short* aS0 = hbuf + (size_t)r0 * HID + swzk;
  const unsigned short* aS1 = hbuf + (size_t)r1 * HID + swzk;
  const unsigned short* aS2 = hbuf + (size_t)r2 * HID + swzk;
  const unsigned short* aS3 = hbuf + (size_t)r3 * HID + swzk;
  const unsigned short* w2e = w2t + ((size_t)e * DIM + n0) * HID;
  const unsigned short* bS0 = w2e + (size_t)trow * HID + swzk;
  const unsigned short* bS1 = w2e + (size_t)(64 + trow) * HID + swzk;

  f32x4 acc[8][2];
#pragma unroll
  for (int i = 0; i < 8; ++i)
#pragma unroll
    for (int j = 0; j < 2; ++j) acc[i][j] = f32x4{0.f, 0.f, 0.f, 0.f};
  bf16x8 ra[8], rb[2];

#define G2_STG(CUR, TILE) do {                                        \
    g2l16(aS0 + (TILE) * 64, As + (CUR) * 16384 + 0 * 4096 + ldst);   \
    g2l16(aS1 + (TILE) * 64, As + (CUR) * 16384 + 1 * 4096 + ldst);   \
    g2l16(aS2 + (TILE) * 64, As + (CUR) * 16384 + 2 * 4096 + ldst);   \
    g2l16(aS3 + (TILE) * 64, As + (CUR) * 16384 + 3 * 4096 + ldst);   \
    g2l16(bS0 + (TILE) * 64, Bs + (CUR) * 8192 + 0 * 4096 + ldst);    \
    g2l16(bS1 + (TILE) * 64, Bs + (CUR) * 8192 + 1 * 4096 + ldst);    \
  } while (0)
#define G2_LD(CUR, KS2) do {                                                          \
    const int se = ((((KS2) * 4) + kc) ^ sw) * 8;                                     \
    const int ab = (CUR) * 16384 + (wm * 128 + lr) * 64 + se;                         \
    _Pragma("unroll") for (int f = 0; f < 8; ++f)                                     \
      ra[f] = *(const bf16x8*)(As + ab + f * 1024);                                   \
    rb[0] = *(const bf16x8*)(Bs + (CUR) * 8192 + (wn * 32 + lr) * 64 + se);           \
    rb[1] = *(const bf16x8*)(Bs + (CUR) * 8192 + (wn * 32 + 16 + lr) * 64 + se);      \
  } while (0)
#define G2_MM() do {                                                                  \
    _Pragma("unroll") for (int f = 0; f < 8; ++f)                                     \
      _Pragma("unroll") for (int j = 0; j < 2; ++j)                                   \
        acc[f][j] = __builtin_amdgcn_mfma_f32_16x16x32_bf16(ra[f], rb[j], acc[f][j], 0, 0, 0); \
  } while (0)
#define G2_ITER(CUR, KT, DOSTAGE) do {                                                \
    G2_LD(CUR, 0);                                                                    \
    if (DOSTAGE) G2_STG((CUR) ^ 1, (KT) + 1);                                         \
    PH_PRE; G2_MM(); PH_POST;                                                         \
    G2_LD(CUR, 1);                                                                    \
    FENCE; SBAR; LGKM0; SCHED0; PRIO(1); G2_MM(); PRIO(0);                            \
    WAITV0; FENCE; SBAR; SCHED0;                                                      \
  } while (0)

  G2_STG(0, 0);
  WAITV0; FENCE; SBAR; SCHED0;

  const int NK = HID / 64;   // 44
#pragma unroll 1
  for (int kt = 0; kt < NK; kt += 2) {
    G2_ITER(0, kt, true);
    G2_ITER(1, kt + 1, (kt + 2) < NK);
  }

  const int* idx_e = idx + e * T_TOK;
  const float* wgt_e = wgt + e * T_TOK;
#pragma unroll
  for (int i = 0; i < 8; ++i)
#pragma unroll
    for (int q = 0; q < 4; ++q) {
      int pl = m0 + wm * 128 + i * 16 + kc * 4 + q;
      if (pl >= c) continue;
      int tok = idx_e[pl];
      float w = wgt_e[pl];
      float* orow = out + (size_t)tok * DIM + n0 + wn * 32 + lr;
#pragma unroll
      for (int j = 0; j < 2; ++j)
        atomicAdd(orow + j * 16, w * acc[i][j][q]);
    }
}

extern "C" void kernel_launch(void* const* d_in, const int* in_sizes, int n_in,
                              void* d_out, int out_size, void* d_ws, size_t ws_size,
                              hipStream_t stream) {
  const float* x  = (const float*)d_in[0];
  const float* gw = (const float*)d_in[1];
  const float* w1 = (const float*)d_in[2];
  const float* w2 = (const float*)d_in[3];
  const float* w3 = (const float*)d_in[4];
  float* out = (float*)d_out;

  // Workspace layout (~249 MB total)
  char* ws = (char*)d_ws;
  size_t off = 0;
  auto alloc = [&](size_t bytes) {
    char* p = ws + off;
    off += (bytes + 255) & ~(size_t)255;
    return p;
  };
  unsigned short* xb  = (unsigned short*)alloc((size_t)T_TOK * DIM * 2);       // 16.8 MB
  unsigned short* w1t = (unsigned short*)alloc((size_t)NE * DIM * HID * 2);    // 46.1 MB  [E][H][D]
  unsigned short* w3t = (unsigned short*)alloc((size_t)NE * DIM * HID * 2);    // 46.1 MB  [E][H][D]
  unsigned short* w2t = (unsigned short*)alloc((size_t)NE * DIM * HID * 2);    // 46.1 MB  [E][D][H]
  unsigned short* hb  = (unsigned short*)alloc((size_t)2 * T_TOK * HID * 2);   // 92.3 MB
  int*   cnt  = (int*)alloc(NE * sizeof(int));
  int*   offs = (int*)alloc(NE * sizeof(int));
  int*   ntl  = (int*)alloc(2 * sizeof(int));
  int*   idx  = (int*)alloc((size_t)NE * T_TOK * sizeof(int));
  float* wgt  = (float*)alloc((size_t)NE * T_TOK * sizeof(float));
  // max m-tiles total: sum ceil(c_e/256) <= 16384/256 + 8 = 72
  int*   tl1  = (int*)alloc((size_t)72 * NT1 * sizeof(int));
  int*   tl2  = (int*)alloc((size_t)72 * NT2 * sizeof(int));

  hipMemsetAsync(d_out, 0, (size_t)out_size * sizeof(float), stream);
  hipMemsetAsync(cnt, 0, NE * sizeof(int), stream);

  cast_x_kernel<<<(T_TOK * DIM) / (256 * 8), 256, 0, stream>>>(x, xb);
  transpose_cast_kernel<<<dim3(HID / 32, DIM / 32, NE), 256, 0, stream>>>(w1, w1t, DIM, HID);
  transpose_cast_kernel<<<dim3(HID / 32, DIM / 32, NE), 256, 0, stream>>>(w3, w3t, DIM, HID);
  transpose_cast_kernel<<<dim3(DIM / 32, HID / 32, NE), 256, 0, stream>>>(w2, w2t, HID, DIM);
  router_kernel<<<T_TOK / 4, 256, 0, stream>>>(x, gw, cnt, idx, wgt);
  prep_kernel<<<1, 256, 0, stream>>>(cnt, offs, ntl, tl1, tl2);

  gemm1_kernel<<<72 * NT1, 512, 0, stream>>>(xb, w1t, w3t, cnt, offs, ntl, tl1, idx, hb);
  gemm2_kernel<<<72 * NT2, 512, 0, stream>>>(hb, w2t, cnt, offs, ntl, tl2, idx, wgt, out);
}

// Round 8
// 756.357 us; speedup vs baseline: 1.4634x; 1.0207x over previous
//
#include <hip/hip_runtime.h>
#include <math.h>

// Problem constants
#define T_TOK 8192   // B*S tokens
#define DIM   1024   // D
#define HID   2816   // H
#define NE    8      // experts
// K (top-k) = 2

typedef __attribute__((ext_vector_type(4))) float  f32x4;
typedef __attribute__((ext_vector_type(8))) __bf16 bf16x8;

__device__ __forceinline__ unsigned short f2bf(float f) {
  unsigned int u = __builtin_bit_cast(unsigned int, f);
  unsigned int r = (u + 0x7FFFu + ((u >> 16) & 1u)) >> 16;   // RTNE
  return (unsigned short)r;
}
__device__ __forceinline__ int imin(int a, int b) { return a < b ? a : b; }

// global -> LDS direct DMA, 16B per lane. LDS dest = wave-uniform base + lane*16.
typedef const __attribute__((address_space(1))) void gvoid_t;
typedef __attribute__((address_space(3))) void svoid_t;
__device__ __forceinline__ void g2l16(const void* g, void* l) {
  __builtin_amdgcn_global_load_lds((gvoid_t*)g, (svoid_t*)l, 16, 0, 0);
}

// Pipeline fences (T3/T4): raw s_barrier + counted waits; sched_barrier pins motion.
#define WAITV(N) asm volatile("s_waitcnt vmcnt(" #N ")" ::: "memory")
#define WAITV0 asm volatile("s_waitcnt vmcnt(0)" ::: "memory")
#define LGKM0  asm volatile("s_waitcnt lgkmcnt(0)" ::: "memory")
#define FENCE  asm volatile("" ::: "memory")
#define SBAR   __builtin_amdgcn_s_barrier()
#define SCHED0 __builtin_amdgcn_sched_barrier(0)
#define PRIO(x) __builtin_amdgcn_s_setprio(x)
#define PH_PRE  do { FENCE; SBAR; LGKM0; SCHED0; PRIO(1); } while (0)
#define PH_POST do { PRIO(0); FENCE; SBAR; SCHED0; } while (0)

// ---------------- x -> bf16 cast ----------------
__global__ __launch_bounds__(256) void cast_x_kernel(const float* __restrict__ x,
                                                     unsigned short* __restrict__ xb) {
  size_t i = ((size_t)blockIdx.x * 256 + threadIdx.x) * 8;
  float4 a = *(const float4*)(x + i);
  float4 b = *(const float4*)(x + i + 4);
  typedef __attribute__((ext_vector_type(8))) unsigned short u16x8;
  u16x8 v;
  v[0] = f2bf(a.x); v[1] = f2bf(a.y); v[2] = f2bf(a.z); v[3] = f2bf(a.w);
  v[4] = f2bf(b.x); v[5] = f2bf(b.y); v[6] = f2bf(b.z); v[7] = f2bf(b.w);
  *(u16x8*)(xb + i) = v;
}

// ------------- fp32 [E][R][C] -> bf16 [E][C][R] transpose-cast -------------
__global__ __launch_bounds__(256) void transpose_cast_kernel(const float* __restrict__ src,
                                                             unsigned short* __restrict__ dst,
                                                             int R, int C) {
  __shared__ float tile[32][33];
  int e = blockIdx.z;
  const float* s = src + (size_t)e * R * C;
  unsigned short* d = dst + (size_t)e * R * C;
  int tx = threadIdx.x & 31, ty = threadIdx.x >> 5;
  int r0 = blockIdx.y * 32, c0 = blockIdx.x * 32;
#pragma unroll
  for (int j = 0; j < 4; ++j)
    tile[ty + 8 * j][tx] = s[(size_t)(r0 + ty + 8 * j) * C + c0 + tx];
  __syncthreads();
#pragma unroll
  for (int j = 0; j < 4; ++j)
    d[(size_t)(c0 + ty + 8 * j) * R + r0 + tx] = f2bf(tile[tx][ty + 8 * j]);
}

// ---------------- router: scores (fp64), top-2, softmax, compact ----------------
__global__ __launch_bounds__(256) void router_kernel(const float* __restrict__ x,
                                                     const float* __restrict__ gw,
                                                     int* __restrict__ cnt,
                                                     int* __restrict__ idx,
                                                     float* __restrict__ wgt) {
  int wid = threadIdx.x >> 6;
  int lane = threadIdx.x & 63;
  int t = blockIdx.x * 4 + wid;
  double acc[NE];
#pragma unroll
  for (int e = 0; e < NE; ++e) acc[e] = 0.0;
  const float* xr = x + (size_t)t * DIM;
#pragma unroll 4
  for (int i = 0; i < DIM / 64; ++i) {
    int d = i * 64 + lane;
    double xv = (double)xr[d];
#pragma unroll
    for (int e = 0; e < NE; ++e) acc[e] += xv * (double)gw[e * DIM + d];
  }
#pragma unroll
  for (int e = 0; e < NE; ++e) {
#pragma unroll
    for (int off = 32; off >= 1; off >>= 1) acc[e] += __shfl_xor(acc[e], off);
  }
  if (lane == 0) {
    int e0 = 0; double s0 = acc[0];
#pragma unroll
    for (int e = 1; e < NE; ++e) if (acc[e] > s0) { s0 = acc[e]; e0 = e; }
    int e1 = -1; double s1 = -1.0e300;
#pragma unroll
    for (int e = 0; e < NE; ++e) if (e != e0 && acc[e] > s1) { s1 = acc[e]; e1 = e; }
    double w0 = 1.0 / (1.0 + exp(s1 - s0));   // softmax over {s0,s1}, s0 >= s1
    int p0 = atomicAdd(&cnt[e0], 1);
    idx[e0 * T_TOK + p0] = t; wgt[e0 * T_TOK + p0] = (float)w0;
    int p1 = atomicAdd(&cnt[e1], 1);
    idx[e1 * T_TOK + p1] = t; wgt[e1 * T_TOK + p1] = (float)(1.0 - w0);
  }
}

// ------------- prep: offsets + compact tile lists (sorted e,n,m; BM=256) -------------
#define NT1 (HID / 128)   // 22
#define NT2 (DIM / 128)   // 8
__global__ __launch_bounds__(256) void prep_kernel(const int* __restrict__ cnt,
                                                   int* __restrict__ offs,
                                                   int* __restrict__ ntl,
                                                   int* __restrict__ tl1,
                                                   int* __restrict__ tl2) {
  __shared__ int smt[NE], stb1[NE + 1], stb2[NE + 1];
  if (threadIdx.x == 0) {
    int s = 0, t1 = 0, t2 = 0;
    for (int e = 0; e < NE; ++e) {
      offs[e] = s; s += cnt[e];
      int mt = (cnt[e] + 255) >> 8;
      smt[e] = mt;
      stb1[e] = t1; t1 += mt * NT1;
      stb2[e] = t2; t2 += mt * NT2;
    }
    stb1[NE] = t1; stb2[NE] = t2;
    ntl[0] = t1; ntl[1] = t2;
  }
  __syncthreads();
  for (int k = threadIdx.x; k < stb1[NE]; k += 256) {
    int e = 0;
    while (e < NE - 1 && k >= stb1[e + 1]) ++e;
    int rem = k - stb1[e], mt = smt[e];
    int n = rem / mt, m = rem - n * mt;
    tl1[k] = (e << 16) | (n << 8) | m;
  }
  for (int k = threadIdx.x; k < stb2[NE]; k += 256) {
    int e = 0;
    while (e < NE - 1 && k >= stb2[e + 1]) ++e;
    int rem = k - stb2[e], mt = smt[e];
    int n = rem / mt, m = rem - n * mt;
    tl2[k] = (e << 16) | (n << 8) | m;
  }
}

// Bijective XCD-chunk decode (m204).
__device__ __forceinline__ bool tile_decode(const int* ntl, int slot, const int* tl,
                                            int& e, int& n0, int& m0) {
  int nt = ntl[slot];
  int q = nt >> 3, r = nt & 7;
  int xcd = blockIdx.x & 7, pos = blockIdx.x >> 3;
  int cap = xcd < r ? q + 1 : q;
  if (pos >= cap) return false;
  int lid = (xcd < r ? xcd * (q + 1) : r * (q + 1) + (xcd - r) * q) + pos;
  int ent = tl[lid];
  e = ent >> 16;
  n0 = ((ent >> 8) & 255) * 128;
  m0 = (ent & 255) * 256;
  return true;
}

// ============ GEMM1: h = silu(Xg @ w1) * (Xg @ w3) — 8-phase, counted vmcnt ============
// BM=256, BN=128 (dual-B), BK=64, 8 waves (2M x 4N), dbuf LDS 128KB.
// Tile kt lives in buf kt&1. Stage for kt+2 issued at END of iter kt (into the
// just-read buffer), then vmcnt(8): kt+1's 8 loads complete, kt+2's stay in flight.
__global__ __launch_bounds__(512, 1) void gemm1_kernel(const unsigned short* __restrict__ xb,
                                                       const unsigned short* __restrict__ w1t,
                                                       const unsigned short* __restrict__ w3t,
                                                       const int* __restrict__ cnt,
                                                       const int* __restrict__ offs,
                                                       const int* __restrict__ ntl,
                                                       const int* __restrict__ tl1,
                                                       const int* __restrict__ idx,
                                                       unsigned short* __restrict__ hbuf) {
  int e, n0, m0;
  if (!tile_decode(ntl, 0, tl1, e, n0, m0)) return;
  int c = cnt[e];

  __shared__ __align__(16) unsigned short As[2 * 16384];   // [2][256][64]
  __shared__ __align__(16) unsigned short B1s[2 * 8192];   // [2][128][64]
  __shared__ __align__(16) unsigned short B3s[2 * 8192];

  const int t = threadIdx.x;
  const int wid = t >> 6, lane = t & 63;
  const int wm = wid >> 2, wn = wid & 3;
  const int lr = lane & 15, kc = lane >> 4, sw = lane & 7;
  const int ldst = wid * 512;           // wave-uniform elems within an 8KB instr chunk
  const int trow = t >> 3;              // 0..63
  const int swzk = ((t & 7) ^ ((t >> 3) & 7)) * 8;   // pre-swizzled source k-chunk

  const int* idx_e = idx + e * T_TOK;
  int g0 = m0 + trow, g1 = m0 + 64 + trow, g2 = m0 + 128 + trow, g3 = m0 + 192 + trow;
  int tk0 = (g0 < c) ? idx_e[g0] : 0;
  int tk1 = (g1 < c) ? idx_e[g1] : 0;
  int tk2 = (g2 < c) ? idx_e[g2] : 0;
  int tk3 = (g3 < c) ? idx_e[g3] : 0;
  const unsigned short* aS0 = xb + (size_t)tk0 * DIM + swzk;
  const unsigned short* aS1 = xb + (size_t)tk1 * DIM + swzk;
  const unsigned short* aS2 = xb + (size_t)tk2 * DIM + swzk;
  const unsigned short* aS3 = xb + (size_t)tk3 * DIM + swzk;
  const unsigned short* w1e = w1t + ((size_t)e * HID + n0) * DIM;
  const unsigned short* w3e = w3t + ((size_t)e * HID + n0) * DIM;
  const unsigned short* b1S0 = w1e + (size_t)trow * DIM + swzk;
  const unsigned short* b1S1 = w1e + (size_t)(64 + trow) * DIM + swzk;
  const unsigned short* b3S0 = w3e + (size_t)trow * DIM + swzk;
  const unsigned short* b3S1 = w3e + (size_t)(64 + trow) * DIM + swzk;

  f32x4 acc1[8][2], acc3[8][2];
#pragma unroll
  for (int i = 0; i < 8; ++i)
#pragma unroll
    for (int j = 0; j < 2; ++j) {
      acc1[i][j] = f32x4{0.f, 0.f, 0.f, 0.f};
      acc3[i][j] = f32x4{0.f, 0.f, 0.f, 0.f};
    }
  bf16x8 ra[4], rb1[2], rb3[2];

#define G1_STG_A(CUR, TILE) do {                                      \
    g2l16(aS0 + (TILE) * 64, As + (CUR) * 16384 + 0 * 4096 + ldst);   \
    g2l16(aS1 + (TILE) * 64, As + (CUR) * 16384 + 1 * 4096 + ldst);   \
    g2l16(aS2 + (TILE) * 64, As + (CUR) * 16384 + 2 * 4096 + ldst);   \
    g2l16(aS3 + (TILE) * 64, As + (CUR) * 16384 + 3 * 4096 + ldst);   \
  } while (0)
#define G1_STG_B(CUR, TILE) do {                                      \
    g2l16(b1S0 + (TILE) * 64, B1s + (CUR) * 8192 + 0 * 4096 + ldst);  \
    g2l16(b1S1 + (TILE) * 64, B1s + (CUR) * 8192 + 1 * 4096 + ldst);  \
    g2l16(b3S0 + (TILE) * 64, B3s + (CUR) * 8192 + 0 * 4096 + ldst);  \
    g2l16(b3S1 + (TILE) * 64, B3s + (CUR) * 8192 + 1 * 4096 + ldst);  \
  } while (0)
#define G1_LDB(CUR, KS2) do {                                                          \
    const int se = ((((KS2) * 4) + kc) ^ sw) * 8;                                      \
    rb1[0] = *(const bf16x8*)(B1s + (CUR) * 8192 + (wn * 32 + lr) * 64 + se);          \
    rb1[1] = *(const bf16x8*)(B1s + (CUR) * 8192 + (wn * 32 + 16 + lr) * 64 + se);     \
    rb3[0] = *(const bf16x8*)(B3s + (CUR) * 8192 + (wn * 32 + lr) * 64 + se);          \
    rb3[1] = *(const bf16x8*)(B3s + (CUR) * 8192 + (wn * 32 + 16 + lr) * 64 + se);     \
  } while (0)
#define G1_LDA(CUR, KS2, IH) do {                                                      \
    const int se = ((((KS2) * 4) + kc) ^ sw) * 8;                                      \
    const int ab = (CUR) * 16384 + (wm * 128 + lr) * 64 + (IH) * 4096 + se;            \
    ra[0] = *(const bf16x8*)(As + ab + 0 * 1024);                                      \
    ra[1] = *(const bf16x8*)(As + ab + 1 * 1024);                                      \
    ra[2] = *(const bf16x8*)(As + ab + 2 * 1024);                                      \
    ra[3] = *(const bf16x8*)(As + ab + 3 * 1024);                                      \
  } while (0)
#define G1_MM(IH) do {                                                                 \
    _Pragma("unroll") for (int f = 0; f < 4; ++f)                                      \
      _Pragma("unroll") for (int j = 0; j < 2; ++j) {                                  \
        acc1[(IH) * 4 + f][j] =                                                        \
            __builtin_amdgcn_mfma_f32_16x16x32_bf16(ra[f], rb1[j], acc1[(IH) * 4 + f][j], 0, 0, 0); \
        acc3[(IH) * 4 + f][j] =                                                        \
            __builtin_amdgcn_mfma_f32_16x16x32_bf16(ra[f], rb3[j], acc3[(IH) * 4 + f][j], 0, 0, 0); \
      }                                                                                \
  } while (0)
// End-of-iter stage + counted wait (T4): kt+1's tile is guaranteed by vmcnt(8),
// kt+2's 8 loads remain in flight across the barrier.
#define G1_ITER(CUR, KT, DOSTAGE) do {                                                 \
    G1_LDB(CUR, 0); G1_LDA(CUR, 0, 0);                                                 \
    PH_PRE; G1_MM(0); PH_POST;                                                         \
    G1_LDA(CUR, 0, 1);                                                                 \
    PH_PRE; G1_MM(1); PH_POST;                                                         \
    G1_LDB(CUR, 1); G1_LDA(CUR, 1, 0);                                                 \
    PH_PRE; G1_MM(0); PH_POST;                                                         \
    G1_LDA(CUR, 1, 1);                                                                 \
    FENCE; SBAR; LGKM0; SCHED0; PRIO(1); G1_MM(1); PRIO(0); SCHED0;                    \
    if (DOSTAGE) { G1_STG_A(CUR, (KT) + 2); G1_STG_B(CUR, (KT) + 2); WAITV(8); }       \
    else WAITV0;                                                                       \
    FENCE; SBAR; SCHED0;                                                               \
  } while (0)

  // prologue: tiles 0,1 -> bufs 0,1; counted wait leaves tile1 in flight
  G1_STG_A(0, 0); G1_STG_B(0, 0);
  G1_STG_A(1, 1); G1_STG_B(1, 1);
  WAITV(8); FENCE; SBAR; SCHED0;

  const int NK = DIM / 64;   // 16
#pragma unroll 1
  for (int kt = 0; kt < NK; kt += 2) {
    G1_ITER(0, kt, (kt + 2) < NK);
    G1_ITER(1, kt + 1, (kt + 3) < NK);
  }

  int base = offs[e];
#pragma unroll
  for (int i = 0; i < 8; ++i)
#pragma unroll
    for (int q = 0; q < 4; ++q) {
      int pl = m0 + wm * 128 + i * 16 + kc * 4 + q;
      if (pl >= c) continue;
      unsigned short* hrow = hbuf + (size_t)(base + pl) * HID + n0 + wn * 32 + lr;
#pragma unroll
      for (int j = 0; j < 2; ++j) {
        float v1 = acc1[i][j][q];
        float v3 = acc3[i][j][q];
        float hv = v1 / (1.0f + __expf(-v1)) * v3;   // silu(v1) * v3
        hrow[j * 16] = f2bf(hv);
      }
    }
}

// ============ GEMM2: out[tok] += w * (h @ w2) — counted vmcnt, 4Mx2N waves ============
// BM=256, BN=128, BK=64, 8 waves (4M x 2N, per-wave 64x64), dbuf LDS 96KB.
__global__ __launch_bounds__(512, 1) void gemm2_kernel(const unsigned short* __restrict__ hbuf,
                                                       const unsigned short* __restrict__ w2t,
                                                       const int* __restrict__ cnt,
                                                       const int* __restrict__ offs,
                                                       const int* __restrict__ ntl,
                                                       const int* __restrict__ tl2,
                                                       const int* __restrict__ idx,
                                                       const float* __restrict__ wgt,
                                                       float* __restrict__ out) {
  int e, n0, m0;
  if (!tile_decode(ntl, 1, tl2, e, n0, m0)) return;
  int c = cnt[e];
  int base = offs[e];

  __shared__ __align__(16) unsigned short As[2 * 16384];   // [2][256][64]
  __shared__ __align__(16) unsigned short Bs[2 * 8192];    // [2][128][64]

  const int t = threadIdx.x;
  const int wid = t >> 6, lane = t & 63;
  const int wm = wid >> 1, wn = wid & 1;       // 4M x 2N
  const int lr = lane & 15, kc = lane >> 4, sw = lane & 7;
  const int ldst = wid * 512;
  const int trow = t >> 3;
  const int swzk = ((t & 7) ^ ((t >> 3) & 7)) * 8;

  int r0 = imin(base + m0 + trow,       2 * T_TOK - 1);
  int r1 = imin(base + m0 + 64 + trow,  2 * T_TOK - 1);
  int r2 = imin(base + m0 + 128 + trow, 2 * T_TOK - 1);
  int r3 = imin(base + m0 + 192 + trow, 2 * T_TOK - 1);
  const unsigned short* aS0 = hbuf + (size_t)r0 * HID + swzk;
  const unsigned short* aS1 = hbuf + (size_t)r1 * HID + swzk;
  const unsigned short* aS2 = hbuf + (size_t)r2 * HID + swzk;
  const unsigned short* aS3 = hbuf + (size_t)r3 * HID + swzk;
  const unsigned short* w2e = w2t + ((size_t)e * DIM + n0) * HID;
  const unsigned short* bS0 = w2e + (size_t)trow * HID + swzk;
  const unsigned short* bS1 = w2e + (size_t)(64 + trow) * HID + swzk;

  f32x4 acc[4][4];
#pragma unroll
  for (int i = 0; i < 4; ++i)
#pragma unroll
    for (int j = 0; j < 4; ++j) acc[i][j] = f32x4{0.f, 0.f, 0.f, 0.f};
  bf16x8 ra[4], rb[4];

#define G2_STG(CUR, TILE) do {                                        \
    g2l16(aS0 + (TILE) * 64, As + (CUR) * 16384 + 0 * 4096 + ldst);   \
    g2l16(aS1 + (TILE) * 64, As + (CUR) * 16384 + 1 * 4096 + ldst);   \
    g2l16(aS2 + (TILE) * 64, As + (CUR) * 16384 + 2 * 4096 + ldst);   \
    g2l16(aS3 + (TILE) * 64, As + (CUR) * 16384 + 3 * 4096 + ldst);   \
    g2l16(bS0 + (TILE) * 64, Bs + (CUR) * 8192 + 0 * 4096 + ldst);    \
    g2l16(bS1 + (TILE) * 64, Bs + (CUR) * 8192 + 1 * 4096 + ldst);    \
  } while (0)
#define G2_LD(CUR, KS2) do {                                                          \
    const int se = ((((KS2) * 4) + kc) ^ sw) * 8;                                     \
    const int ab = (CUR) * 16384 + (wm * 64 + lr) * 64 + se;                          \
    _Pragma("unroll") for (int f = 0; f < 4; ++f)                                     \
      ra[f] = *(const bf16x8*)(As + ab + f * 1024);                                   \
    const int bb = (CUR) * 8192 + (wn * 64 + lr) * 64 + se;                           \
    _Pragma("unroll") for (int j = 0; j < 4; ++j)                                     \
      rb[j] = *(const bf16x8*)(Bs + bb + j * 1024);                                   \
  } while (0)
#define G2_MM() do {                                                                  \
    _Pragma("unroll") for (int f = 0; f < 4; ++f)                                     \
      _Pragma("unroll") for (int j = 0; j < 4; ++j)                                   \
        acc[f][j] = __builtin_amdgcn_mfma_f32_16x16x32_bf16(ra[f], rb[j], acc[f][j], 0, 0, 0); \
  } while (0)
#define G2_ITER(CUR, KT, DOSTAGE) do {                                                \
    G2_LD(CUR, 0);                                                                    \
    PH_PRE; G2_MM(); PH_POST;                                                         \
    G2_LD(CUR, 1);                                                                    \
    FENCE; SBAR; LGKM0; SCHED0; PRIO(1); G2_MM(); PRIO(0); SCHED0;                    \
    if (DOSTAGE) { G2_STG(CUR, (KT) + 2); WAITV(6); }                                 \
    else WAITV0;                                                                      \
    FENCE; SBAR; SCHED0;                                                              \
  } while (0)

  G2_STG(0, 0);
  G2_STG(1, 1);
  WAITV(6); FENCE; SBAR; SCHED0;

  const int NK = HID / 64;   // 44
#pragma unroll 1
  for (int kt = 0; kt < NK; kt += 2) {
    G2_ITER(0, kt, (kt + 2) < NK);
    G2_ITER(1, kt + 1, (kt + 3) < NK);
  }

  const int* idx_e = idx + e * T_TOK;
  const float* wgt_e = wgt + e * T_TOK;
#pragma unroll
  for (int i = 0; i < 4; ++i)
#pragma unroll
    for (int q = 0; q < 4; ++q) {
      int pl = m0 + wm * 64 + i * 16 + kc * 4 + q;
      if (pl >= c) continue;
      int tok = idx_e[pl];
      float w = wgt_e[pl];
      float* orow = out + (size_t)tok * DIM + n0 + wn * 64 + lr;
#pragma unroll
      for (int j = 0; j < 4; ++j)
        atomicAdd(orow + j * 16, w * acc[i][j][q]);
    }
}

extern "C" void kernel_launch(void* const* d_in, const int* in_sizes, int n_in,
                              void* d_out, int out_size, void* d_ws, size_t ws_size,
                              hipStream_t stream) {
  const float* x  = (const float*)d_in[0];
  const float* gw = (const float*)d_in[1];
  const float* w1 = (const float*)d_in[2];
  const float* w2 = (const float*)d_in[3];
  const float* w3 = (const float*)d_in[4];
  float* out = (float*)d_out;

  // Workspace layout (~249 MB total)
  char* ws = (char*)d_ws;
  size_t off = 0;
  auto alloc = [&](size_t bytes) {
    char* p = ws + off;
    off += (bytes + 255) & ~(size_t)255;
    return p;
  };
  unsigned short* xb  = (unsigned short*)alloc((size_t)T_TOK * DIM * 2);       // 16.8 MB
  unsigned short* w1t = (unsigned short*)alloc((size_t)NE * DIM * HID * 2);    // 46.1 MB  [E][H][D]
  unsigned short* w3t = (unsigned short*)alloc((size_t)NE * DIM * HID * 2);    // 46.1 MB  [E][H][D]
  unsigned short* w2t = (unsigned short*)alloc((size_t)NE * DIM * HID * 2);    // 46.1 MB  [E][D][H]
  unsigned short* hb  = (unsigned short*)alloc((size_t)2 * T_TOK * HID * 2);   // 92.3 MB
  int*   cnt  = (int*)alloc(NE * sizeof(int));
  int*   offs = (int*)alloc(NE * sizeof(int));
  int*   ntl  = (int*)alloc(2 * sizeof(int));
  int*   idx  = (int*)alloc((size_t)NE * T_TOK * sizeof(int));
  float* wgt  = (float*)alloc((size_t)NE * T_TOK * sizeof(float));
  // max m-tiles total: sum ceil(c_e/256) <= 16384/256 + 8 = 72
  int*   tl1  = (int*)alloc((size_t)72 * NT1 * sizeof(int));
  int*   tl2  = (int*)alloc((size_t)72 * NT2 * sizeof(int));

  hipMemsetAsync(d_out, 0, (size_t)out_size * sizeof(float), stream);
  hipMemsetAsync(cnt, 0, NE * sizeof(int), stream);

  cast_x_kernel<<<(T_TOK * DIM) / (256 * 8), 256, 0, stream>>>(x, xb);
  transpose_cast_kernel<<<dim3(HID / 32, DIM / 32, NE), 256, 0, stream>>>(w1, w1t, DIM, HID);
  transpose_cast_kernel<<<dim3(HID / 32, DIM / 32, NE), 256, 0, stream>>>(w3, w3t, DIM, HID);
  transpose_cast_kernel<<<dim3(DIM / 32, HID / 32, NE), 256, 0, stream>>>(w2, w2t, HID, DIM);
  router_kernel<<<T_TOK / 4, 256, 0, stream>>>(x, gw, cnt, idx, wgt);
  prep_kernel<<<1, 256, 0, stream>>>(cnt, offs, ntl, tl1, tl2);

  gemm1_kernel<<<72 * NT1, 512, 0, stream>>>(xb, w1t, w3t, cnt, offs, ntl, tl1, idx, hb);
  gemm2_kernel<<<72 * NT2, 512, 0, stream>>>(hb, w2t, cnt, offs, ntl, tl2, idx, wgt, out);
}

// Round 9
// 726.882 us; speedup vs baseline: 1.5227x; 1.0406x over previous
//
#include <hip/hip_runtime.h>
#include <math.h>

// Problem constants
#define T_TOK 8192   // B*S tokens
#define DIM   1024   // D
#define HID   2816   // H
#define NE    8      // experts
// K (top-k) = 2

typedef __attribute__((ext_vector_type(4))) float  f32x4;
typedef __attribute__((ext_vector_type(8))) __bf16 bf16x8;

__device__ __forceinline__ unsigned short f2bf(float f) {
  unsigned int u = __builtin_bit_cast(unsigned int, f);
  unsigned int r = (u + 0x7FFFu + ((u >> 16) & 1u)) >> 16;   // RTNE
  return (unsigned short)r;
}
__device__ __forceinline__ int imin(int a, int b) { return a < b ? a : b; }

// global -> LDS direct DMA, 16B per lane. LDS dest = wave-uniform base + lane*16.
typedef const __attribute__((address_space(1))) void gvoid_t;
typedef __attribute__((address_space(3))) void svoid_t;
__device__ __forceinline__ void g2l16(const void* g, void* l) {
  __builtin_amdgcn_global_load_lds((gvoid_t*)g, (svoid_t*)l, 16, 0, 0);
}

// Pipeline fences (T3/T4): raw s_barrier + counted waits; sched_barrier pins motion.
#define WAITV(N) asm volatile("s_waitcnt vmcnt(" #N ")" ::: "memory")
#define WAITV0 asm volatile("s_waitcnt vmcnt(0)" ::: "memory")
#define LGKM0  asm volatile("s_waitcnt lgkmcnt(0)" ::: "memory")
#define FENCE  asm volatile("" ::: "memory")
#define SBAR   __builtin_amdgcn_s_barrier()
#define SCHED0 __builtin_amdgcn_sched_barrier(0)
#define PRIO(x) __builtin_amdgcn_s_setprio(x)
#define PH_PRE  do { FENCE; SBAR; LGKM0; SCHED0; PRIO(1); } while (0)
#define PH_POST do { PRIO(0); FENCE; SBAR; SCHED0; } while (0)

// ------------- fp32 [E][R][C] -> bf16 [E][C][R] transpose-cast, 64x64 tiles -------------
__global__ __launch_bounds__(256) void transpose_cast_kernel(const float* __restrict__ src,
                                                             unsigned short* __restrict__ dst,
                                                             int R, int C) {
  __shared__ float tile[64][68];   // row stride 272B, 16B-aligned
  int e = blockIdx.z;
  const float* s = src + (size_t)e * R * C;
  unsigned short* d = dst + (size_t)e * R * C;
  int r0 = blockIdx.y * 64, c0 = blockIdx.x * 64;
  int tr = threadIdx.x >> 4;            // 0..15
  int tc = (threadIdx.x & 15) * 4;      // 0..60
#pragma unroll
  for (int s4 = 0; s4 < 4; ++s4) {
    float4 v = *(const float4*)(s + (size_t)(r0 + tr + s4 * 16) * C + c0 + tc);
    *(float4*)&tile[tr + s4 * 16][tc] = v;
  }
  __syncthreads();
  int c = threadIdx.x >> 2;             // 0..63
  int s2 = threadIdx.x & 3;             // 0..3
#pragma unroll
  for (int p = 0; p < 4; ++p) {
    int rr = s2 * 4 + p * 16;
    ushort4 o;
    o.x = f2bf(tile[rr + 0][c]);
    o.y = f2bf(tile[rr + 1][c]);
    o.z = f2bf(tile[rr + 2][c]);
    o.w = f2bf(tile[rr + 3][c]);
    *(ushort4*)(d + (size_t)(c0 + c) * R + r0 + rr) = o;
  }
}

// ------- router (fused x->bf16 cast): scores (fp64), top-2, softmax, compact -------
// idx entry = tok | (slot<<15); wslot[0][t], wslot[1][t] = softmax weights by slot.
__global__ __launch_bounds__(256) void router_kernel(const float* __restrict__ x,
                                                     const float* __restrict__ gw,
                                                     unsigned short* __restrict__ xb,
                                                     int* __restrict__ cnt,
                                                     int* __restrict__ idx,
                                                     float* __restrict__ wslot) {
  int wid = threadIdx.x >> 6;
  int lane = threadIdx.x & 63;
  int t = blockIdx.x * 4 + wid;
  double acc[NE];
#pragma unroll
  for (int e = 0; e < NE; ++e) acc[e] = 0.0;
  const float* xr = x + (size_t)t * DIM;
  unsigned short* xbr = xb + (size_t)t * DIM;
#pragma unroll 4
  for (int i = 0; i < DIM / 64; ++i) {
    int d = i * 64 + lane;
    float xf = xr[d];
    xbr[d] = f2bf(xf);                 // fused cast (coalesced 2B/lane)
    double xv = (double)xf;
#pragma unroll
    for (int e = 0; e < NE; ++e) acc[e] += xv * (double)gw[e * DIM + d];
  }
#pragma unroll
  for (int e = 0; e < NE; ++e) {
#pragma unroll
    for (int off = 32; off >= 1; off >>= 1) acc[e] += __shfl_xor(acc[e], off);
  }
  if (lane == 0) {
    int e0 = 0; double s0 = acc[0];
#pragma unroll
    for (int e = 1; e < NE; ++e) if (acc[e] > s0) { s0 = acc[e]; e0 = e; }
    int e1 = -1; double s1 = -1.0e300;
#pragma unroll
    for (int e = 0; e < NE; ++e) if (e != e0 && acc[e] > s1) { s1 = acc[e]; e1 = e; }
    double w0 = 1.0 / (1.0 + exp(s1 - s0));   // softmax over {s0,s1}, s0 >= s1
    wslot[t] = (float)w0;
    wslot[T_TOK + t] = (float)(1.0 - w0);
    int p0 = atomicAdd(&cnt[e0], 1);
    idx[e0 * T_TOK + p0] = t;                 // slot 0
    int p1 = atomicAdd(&cnt[e1], 1);
    idx[e1 * T_TOK + p1] = t | (1 << 15);     // slot 1
  }
}

// ------------- prep: offsets + compact tile lists (sorted e,n,m; BM=256) -------------
#define NT1 (HID / 128)   // 22
#define NT2 (DIM / 128)   // 8
__global__ __launch_bounds__(256) void prep_kernel(const int* __restrict__ cnt,
                                                   int* __restrict__ offs,
                                                   int* __restrict__ ntl,
                                                   int* __restrict__ tl1,
                                                   int* __restrict__ tl2) {
  __shared__ int smt[NE], stb1[NE + 1], stb2[NE + 1];
  if (threadIdx.x == 0) {
    int s = 0, t1 = 0, t2 = 0;
    for (int e = 0; e < NE; ++e) {
      offs[e] = s; s += cnt[e];
      int mt = (cnt[e] + 255) >> 8;
      smt[e] = mt;
      stb1[e] = t1; t1 += mt * NT1;
      stb2[e] = t2; t2 += mt * NT2;
    }
    stb1[NE] = t1; stb2[NE] = t2;
    ntl[0] = t1; ntl[1] = t2;
  }
  __syncthreads();
  for (int k = threadIdx.x; k < stb1[NE]; k += 256) {
    int e = 0;
    while (e < NE - 1 && k >= stb1[e + 1]) ++e;
    int rem = k - stb1[e], mt = smt[e];
    int n = rem / mt, m = rem - n * mt;
    tl1[k] = (e << 16) | (n << 8) | m;
  }
  for (int k = threadIdx.x; k < stb2[NE]; k += 256) {
    int e = 0;
    while (e < NE - 1 && k >= stb2[e + 1]) ++e;
    int rem = k - stb2[e], mt = smt[e];
    int n = rem / mt, m = rem - n * mt;
    tl2[k] = (e << 16) | (n << 8) | m;
  }
}

// Bijective XCD-chunk decode (m204).
__device__ __forceinline__ bool tile_decode(const int* ntl, int slot, const int* tl,
                                            int& e, int& n0, int& m0) {
  int nt = ntl[slot];
  int q = nt >> 3, r = nt & 7;
  int xcd = blockIdx.x & 7, pos = blockIdx.x >> 3;
  int cap = xcd < r ? q + 1 : q;
  if (pos >= cap) return false;
  int lid = (xcd < r ? xcd * (q + 1) : r * (q + 1) + (xcd - r) * q) + pos;
  int ent = tl[lid];
  e = ent >> 16;
  n0 = ((ent >> 8) & 255) * 128;
  m0 = (ent & 255) * 256;
  return true;
}

// ============ GEMM1: h = silu(Xg @ w1) * (Xg @ w3) — 8-phase, counted vmcnt ============
// BM=256, BN=128 (dual-B), BK=64, 8 waves (2M x 4N), dbuf LDS 128KB.
__global__ __launch_bounds__(512, 1) void gemm1_kernel(const unsigned short* __restrict__ xb,
                                                       const unsigned short* __restrict__ w1t,
                                                       const unsigned short* __restrict__ w3t,
                                                       const int* __restrict__ cnt,
                                                       const int* __restrict__ offs,
                                                       const int* __restrict__ ntl,
                                                       const int* __restrict__ tl1,
                                                       const int* __restrict__ idx,
                                                       unsigned short* __restrict__ hbuf) {
  int e, n0, m0;
  if (!tile_decode(ntl, 0, tl1, e, n0, m0)) return;
  int c = cnt[e];

  __shared__ __align__(16) unsigned short As[2 * 16384];   // [2][256][64]
  __shared__ __align__(16) unsigned short B1s[2 * 8192];   // [2][128][64]
  __shared__ __align__(16) unsigned short B3s[2 * 8192];

  const int t = threadIdx.x;
  const int wid = t >> 6, lane = t & 63;
  const int wm = wid >> 2, wn = wid & 3;
  const int lr = lane & 15, kc = lane >> 4, sw = lane & 7;
  const int ldst = wid * 512;           // wave-uniform elems within an 8KB instr chunk
  const int trow = t >> 3;              // 0..63
  const int swzk = ((t & 7) ^ ((t >> 3) & 7)) * 8;   // pre-swizzled source k-chunk

  const int* idx_e = idx + e * T_TOK;
  int g0 = m0 + trow, g1 = m0 + 64 + trow, g2 = m0 + 128 + trow, g3 = m0 + 192 + trow;
  int tk0 = (g0 < c) ? (idx_e[g0] & 0x1FFF) : 0;
  int tk1 = (g1 < c) ? (idx_e[g1] & 0x1FFF) : 0;
  int tk2 = (g2 < c) ? (idx_e[g2] & 0x1FFF) : 0;
  int tk3 = (g3 < c) ? (idx_e[g3] & 0x1FFF) : 0;
  const unsigned short* aS0 = xb + (size_t)tk0 * DIM + swzk;
  const unsigned short* aS1 = xb + (size_t)tk1 * DIM + swzk;
  const unsigned short* aS2 = xb + (size_t)tk2 * DIM + swzk;
  const unsigned short* aS3 = xb + (size_t)tk3 * DIM + swzk;
  const unsigned short* w1e = w1t + ((size_t)e * HID + n0) * DIM;
  const unsigned short* w3e = w3t + ((size_t)e * HID + n0) * DIM;
  const unsigned short* b1S0 = w1e + (size_t)trow * DIM + swzk;
  const unsigned short* b1S1 = w1e + (size_t)(64 + trow) * DIM + swzk;
  const unsigned short* b3S0 = w3e + (size_t)trow * DIM + swzk;
  const unsigned short* b3S1 = w3e + (size_t)(64 + trow) * DIM + swzk;

  f32x4 acc1[8][2], acc3[8][2];
#pragma unroll
  for (int i = 0; i < 8; ++i)
#pragma unroll
    for (int j = 0; j < 2; ++j) {
      acc1[i][j] = f32x4{0.f, 0.f, 0.f, 0.f};
      acc3[i][j] = f32x4{0.f, 0.f, 0.f, 0.f};
    }
  bf16x8 ra[4], rb1[2], rb3[2];

#define G1_STG_A(CUR, TILE) do {                                      \
    g2l16(aS0 + (TILE) * 64, As + (CUR) * 16384 + 0 * 4096 + ldst);   \
    g2l16(aS1 + (TILE) * 64, As + (CUR) * 16384 + 1 * 4096 + ldst);   \
    g2l16(aS2 + (TILE) * 64, As + (CUR) * 16384 + 2 * 4096 + ldst);   \
    g2l16(aS3 + (TILE) * 64, As + (CUR) * 16384 + 3 * 4096 + ldst);   \
  } while (0)
#define G1_STG_B(CUR, TILE) do {                                      \
    g2l16(b1S0 + (TILE) * 64, B1s + (CUR) * 8192 + 0 * 4096 + ldst);  \
    g2l16(b1S1 + (TILE) * 64, B1s + (CUR) * 8192 + 1 * 4096 + ldst);  \
    g2l16(b3S0 + (TILE) * 64, B3s + (CUR) * 8192 + 0 * 4096 + ldst);  \
    g2l16(b3S1 + (TILE) * 64, B3s + (CUR) * 8192 + 1 * 4096 + ldst);  \
  } while (0)
#define G1_LDB(CUR, KS2) do {                                                          \
    const int se = ((((KS2) * 4) + kc) ^ sw) * 8;                                      \
    rb1[0] = *(const bf16x8*)(B1s + (CUR) * 8192 + (wn * 32 + lr) * 64 + se);          \
    rb1[1] = *(const bf16x8*)(B1s + (CUR) * 8192 + (wn * 32 + 16 + lr) * 64 + se);     \
    rb3[0] = *(const bf16x8*)(B3s + (CUR) * 8192 + (wn * 32 + lr) * 64 + se);          \
    rb3[1] = *(const bf16x8*)(B3s + (CUR) * 8192 + (wn * 32 + 16 + lr) * 64 + se);     \
  } while (0)
#define G1_LDA(CUR, KS2, IH) do {                                                      \
    const int se = ((((KS2) * 4) + kc) ^ sw) * 8;                                      \
    const int ab = (CUR) * 16384 + (wm * 128 + lr) * 64 + (IH) * 4096 + se;            \
    ra[0] = *(const bf16x8*)(As + ab + 0 * 1024);                                      \
    ra[1] = *(const bf16x8*)(As + ab + 1 * 1024);                                      \
    ra[2] = *(const bf16x8*)(As + ab + 2 * 1024);                                      \
    ra[3] = *(const bf16x8*)(As + ab + 3 * 1024);                                      \
  } while (0)
#define G1_MM(IH) do {                                                                 \
    _Pragma("unroll") for (int f = 0; f < 4; ++f)                                      \
      _Pragma("unroll") for (int j = 0; j < 2; ++j) {                                  \
        acc1[(IH) * 4 + f][j] =                                                        \
            __builtin_amdgcn_mfma_f32_16x16x32_bf16(ra[f], rb1[j], acc1[(IH) * 4 + f][j], 0, 0, 0); \
        acc3[(IH) * 4 + f][j] =                                                        \
            __builtin_amdgcn_mfma_f32_16x16x32_bf16(ra[f], rb3[j], acc3[(IH) * 4 + f][j], 0, 0, 0); \
      }                                                                                \
  } while (0)
#define G1_ITER(CUR, KT, DOSTAGE) do {                                                 \
    G1_LDB(CUR, 0); G1_LDA(CUR, 0, 0);                                                 \
    PH_PRE; G1_MM(0); PH_POST;                                                         \
    G1_LDA(CUR, 0, 1);                                                                 \
    PH_PRE; G1_MM(1); PH_POST;                                                         \
    G1_LDB(CUR, 1); G1_LDA(CUR, 1, 0);                                                 \
    PH_PRE; G1_MM(0); PH_POST;                                                         \
    G1_LDA(CUR, 1, 1);                                                                 \
    FENCE; SBAR; LGKM0; SCHED0; PRIO(1); G1_MM(1); PRIO(0); SCHED0;                    \
    if (DOSTAGE) { G1_STG_A(CUR, (KT) + 2); G1_STG_B(CUR, (KT) + 2); WAITV(8); }       \
    else WAITV0;                                                                       \
    FENCE; SBAR; SCHED0;                                                               \
  } while (0)

  // prologue: tiles 0,1 -> bufs 0,1; counted wait leaves tile1 in flight
  G1_STG_A(0, 0); G1_STG_B(0, 0);
  G1_STG_A(1, 1); G1_STG_B(1, 1);
  WAITV(8); FENCE; SBAR; SCHED0;

  const int NK = DIM / 64;   // 16
#pragma unroll 1
  for (int kt = 0; kt < NK; kt += 2) {
    G1_ITER(0, kt, (kt + 2) < NK);
    G1_ITER(1, kt + 1, (kt + 3) < NK);
  }

  int base = offs[e];
#pragma unroll
  for (int i = 0; i < 8; ++i)
#pragma unroll
    for (int q = 0; q < 4; ++q) {
      int pl = m0 + wm * 128 + i * 16 + kc * 4 + q;
      if (pl >= c) continue;
      unsigned short* hrow = hbuf + (size_t)(base + pl) * HID + n0 + wn * 32 + lr;
#pragma unroll
      for (int j = 0; j < 2; ++j) {
        float v1 = acc1[i][j][q];
        float v3 = acc3[i][j][q];
        float hv = v1 / (1.0f + __expf(-v1)) * v3;   // silu(v1) * v3
        hrow[j * 16] = f2bf(hv);
      }
    }
}

// ============ GEMM2: part[slot][tok] = h @ w2 — counted vmcnt, 4Mx2N waves ============
// BM=256, BN=128, BK=64, 8 waves (4M x 2N, per-wave 64x64), dbuf LDS 96KB.
// No atomics: each (slot, tok, d) is written exactly once; combine applies weights.
__global__ __launch_bounds__(512, 1) void gemm2_kernel(const unsigned short* __restrict__ hbuf,
                                                       const unsigned short* __restrict__ w2t,
                                                       const int* __restrict__ cnt,
                                                       const int* __restrict__ offs,
                                                       const int* __restrict__ ntl,
                                                       const int* __restrict__ tl2,
                                                       const int* __restrict__ idx,
                                                       float* __restrict__ part0,
                                                       float* __restrict__ part1) {
  int e, n0, m0;
  if (!tile_decode(ntl, 1, tl2, e, n0, m0)) return;
  int c = cnt[e];
  int base = offs[e];

  __shared__ __align__(16) unsigned short As[2 * 16384];   // [2][256][64]
  __shared__ __align__(16) unsigned short Bs[2 * 8192];    // [2][128][64]

  const int t = threadIdx.x;
  const int wid = t >> 6, lane = t & 63;
  const int wm = wid >> 1, wn = wid & 1;       // 4M x 2N
  const int lr = lane & 15, kc = lane >> 4, sw = lane & 7;
  const int ldst = wid * 512;
  const int trow = t >> 3;
  const int swzk = ((t & 7) ^ ((t >> 3) & 7)) * 8;

  int r0 = imin(base + m0 + trow,       2 * T_TOK - 1);
  int r1 = imin(base + m0 + 64 + trow,  2 * T_TOK - 1);
  int r2 = imin(base + m0 + 128 + trow, 2 * T_TOK - 1);
  int r3 = imin(base + m0 + 192 + trow, 2 * T_TOK - 1);
  const unsigned short* aS0 = hbuf + (size_t)r0 * HID + swzk;
  const unsigned short* aS1 = hbuf + (size_t)r1 * HID + swzk;
  const unsigned short* aS2 = hbuf + (size_t)r2 * HID + swzk;
  const unsigned short* aS3 = hbuf + (size_t)r3 * HID + swzk;
  const unsigned short* w2e = w2t + ((size_t)e * DIM + n0) * HID;
  const unsigned short* bS0 = w2e + (size_t)trow * HID + swzk;
  const unsigned short* bS1 = w2e + (size_t)(64 + trow) * HID + swzk;

  f32x4 acc[4][4];
#pragma unroll
  for (int i = 0; i < 4; ++i)
#pragma unroll
    for (int j = 0; j < 4; ++j) acc[i][j] = f32x4{0.f, 0.f, 0.f, 0.f};
  bf16x8 ra[4], rb[4];

#define G2_STG(CUR, TILE) do {                                        \
    g2l16(aS0 + (TILE) * 64, As + (CUR) * 16384 + 0 * 4096 + ldst);   \
    g2l16(aS1 + (TILE) * 64, As + (CUR) * 16384 + 1 * 4096 + ldst);   \
    g2l16(aS2 + (TILE) * 64, As + (CUR) * 16384 + 2 * 4096 + ldst);   \
    g2l16(aS3 + (TILE) * 64, As + (CUR) * 16384 + 3 * 4096 + ldst);   \
    g2l16(bS0 + (TILE) * 64, Bs + (CUR) * 8192 + 0 * 4096 + ldst);    \
    g2l16(bS1 + (TILE) * 64, Bs + (CUR) * 8192 + 1 * 4096 + ldst);    \
  } while (0)
#define G2_LD(CUR, KS2) do {                                                          \
    const int se = ((((KS2) * 4) + kc) ^ sw) * 8;                                     \
    const int ab = (CUR) * 16384 + (wm * 64 + lr) * 64 + se;                          \
    _Pragma("unroll") for (int f = 0; f < 4; ++f)                                     \
      ra[f] = *(const bf16x8*)(As + ab + f * 1024);                                   \
    const int bb = (CUR) * 8192 + (wn * 64 + lr) * 64 + se;                           \
    _Pragma("unroll") for (int j = 0; j < 4; ++j)                                     \
      rb[j] = *(const bf16x8*)(Bs + bb + j * 1024);                                   \
  } while (0)
#define G2_MM() do {                                                                  \
    _Pragma("unroll") for (int f = 0; f < 4; ++f)                                     \
      _Pragma("unroll") for (int j = 0; j < 4; ++j)                                   \
        acc[f][j] = __builtin_amdgcn_mfma_f32_16x16x32_bf16(ra[f], rb[j], acc[f][j], 0, 0, 0); \
  } while (0)
#define G2_ITER(CUR, KT, DOSTAGE) do {                                                \
    G2_LD(CUR, 0);                                                                    \
    PH_PRE; G2_MM(); PH_POST;                                                         \
    G2_LD(CUR, 1);                                                                    \
    FENCE; SBAR; LGKM0; SCHED0; PRIO(1); G2_MM(); PRIO(0); SCHED0;                    \
    if (DOSTAGE) { G2_STG(CUR, (KT) + 2); WAITV(6); }                                 \
    else WAITV0;                                                                      \
    FENCE; SBAR; SCHED0;                                                              \
  } while (0)

  G2_STG(0, 0);
  G2_STG(1, 1);
  WAITV(6); FENCE; SBAR; SCHED0;

  const int NK = HID / 64;   // 44
#pragma unroll 1
  for (int kt = 0; kt < NK; kt += 2) {
    G2_ITER(0, kt, (kt + 2) < NK);
    G2_ITER(1, kt + 1, (kt + 3) < NK);
  }

  const int* idx_e = idx + e * T_TOK;
#pragma unroll
  for (int i = 0; i < 4; ++i)
#pragma unroll
    for (int q = 0; q < 4; ++q) {
      int pl = m0 + wm * 64 + i * 16 + kc * 4 + q;
      if (pl >= c) continue;
      int ent = idx_e[pl];
      int tok = ent & 0x1FFF;
      float* pp = (ent & (1 << 15)) ? part1 : part0;
      float* orow = pp + (size_t)tok * DIM + n0 + wn * 64 + lr;
#pragma unroll
      for (int j = 0; j < 4; ++j)
        orow[j * 16] = acc[i][j][q];
    }
}

// ---------------- combine: out = w0*part0 + w1*part1 ----------------
__global__ __launch_bounds__(256) void combine_kernel(const float* __restrict__ p0,
                                                      const float* __restrict__ p1,
                                                      const float* __restrict__ wslot,
                                                      float* __restrict__ out) {
  int i = blockIdx.x * 256 + threadIdx.x;     // float4 index
  int tok = i >> 8;                           // DIM/4 = 256 float4 per token
  float w0 = wslot[tok], w1 = wslot[T_TOK + tok];
  float4 a = ((const float4*)p0)[i];
  float4 b = ((const float4*)p1)[i];
  float4 o;
  o.x = w0 * a.x + w1 * b.x;
  o.y = w0 * a.y + w1 * b.y;
  o.z = w0 * a.z + w1 * b.z;
  o.w = w0 * a.w + w1 * b.w;
  ((float4*)out)[i] = o;
}

extern "C" void kernel_launch(void* const* d_in, const int* in_sizes, int n_in,
                              void* d_out, int out_size, void* d_ws, size_t ws_size,
                              hipStream_t stream) {
  const float* x  = (const float*)d_in[0];
  const float* gw = (const float*)d_in[1];
  const float* w1 = (const float*)d_in[2];
  const float* w2 = (const float*)d_in[3];
  const float* w3 = (const float*)d_in[4];
  float* out = (float*)d_out;

  // Workspace layout (~249 MB total); part[2] aliases w1t/w3t (dead after gemm1).
  char* ws = (char*)d_ws;
  size_t off = 0;
  auto alloc = [&](size_t bytes) {
    char* p = ws + off;
    off += (bytes + 255) & ~(size_t)255;
    return p;
  };
  unsigned short* xb  = (unsigned short*)alloc((size_t)T_TOK * DIM * 2);       // 16.8 MB
  unsigned short* w1t = (unsigned short*)alloc((size_t)NE * DIM * HID * 2);    // 46.1 MB  [E][H][D]
  unsigned short* w3t = (unsigned short*)alloc((size_t)NE * DIM * HID * 2);    // 46.1 MB  [E][H][D]
  unsigned short* w2t = (unsigned short*)alloc((size_t)NE * DIM * HID * 2);    // 46.1 MB  [E][D][H]
  unsigned short* hb  = (unsigned short*)alloc((size_t)2 * T_TOK * HID * 2);   // 92.3 MB
  int*   cnt   = (int*)alloc(NE * sizeof(int));
  int*   offs  = (int*)alloc(NE * sizeof(int));
  int*   ntl   = (int*)alloc(2 * sizeof(int));
  int*   idx   = (int*)alloc((size_t)NE * T_TOK * sizeof(int));
  float* wslot = (float*)alloc((size_t)2 * T_TOK * sizeof(float));
  int*   tl1   = (int*)alloc((size_t)72 * NT1 * sizeof(int));
  int*   tl2   = (int*)alloc((size_t)72 * NT2 * sizeof(int));
  // part aliases w1t..w3t region: 2*T*D*4 = 67.1 MB <= 92.2 MB
  float* part0 = (float*)w1t;
  float* part1 = part0 + (size_t)T_TOK * DIM;

  hipMemsetAsync(cnt, 0, NE * sizeof(int), stream);

  router_kernel<<<T_TOK / 4, 256, 0, stream>>>(x, gw, xb, cnt, idx, wslot);
  transpose_cast_kernel<<<dim3(HID / 64, DIM / 64, NE), 256, 0, stream>>>(w1, w1t, DIM, HID);
  transpose_cast_kernel<<<dim3(HID / 64, DIM / 64, NE), 256, 0, stream>>>(w3, w3t, DIM, HID);
  transpose_cast_kernel<<<dim3(DIM / 64, HID / 64, NE), 256, 0, stream>>>(w2, w2t, HID, DIM);
  prep_kernel<<<1, 256, 0, stream>>>(cnt, offs, ntl, tl1, tl2);

  gemm1_kernel<<<72 * NT1, 512, 0, stream>>>(xb, w1t, w3t, cnt, offs, ntl, tl1, idx, hb);
  gemm2_kernel<<<72 * NT2, 512, 0, stream>>>(hb, w2t, cnt, offs, ntl, tl2, idx, part0, part1);
  combine_kernel<<<(T_TOK * DIM) / (4 * 256), 256, 0, stream>>>(part0, part1, wslot, out);
}

// Round 10
// 713.014 us; speedup vs baseline: 1.5523x; 1.0194x over previous
//
#include <hip/hip_runtime.h>
#include <math.h>

// Problem constants
#define T_TOK 8192   // B*S tokens
#define DIM   1024   // D
#define HID   2816   // H
#define NE    8      // experts
// K (top-k) = 2

typedef __attribute__((ext_vector_type(4))) float  f32x4;
typedef __attribute__((ext_vector_type(8))) __bf16 bf16x8;
typedef __attribute__((ext_vector_type(8))) unsigned short u16x8;

__device__ __forceinline__ unsigned short f2bf(float f) {
  unsigned int u = __builtin_bit_cast(unsigned int, f);
  unsigned int r = (u + 0x7FFFu + ((u >> 16) & 1u)) >> 16;   // RTNE
  return (unsigned short)r;
}
__device__ __forceinline__ int imin(int a, int b) { return a < b ? a : b; }

// global -> LDS direct DMA, 16B per lane. LDS dest = wave-uniform base + lane*16.
typedef const __attribute__((address_space(1))) void gvoid_t;
typedef __attribute__((address_space(3))) void svoid_t;
__device__ __forceinline__ void g2l16(const void* g, void* l) {
  __builtin_amdgcn_global_load_lds((gvoid_t*)g, (svoid_t*)l, 16, 0, 0);
}

// Pipeline fences (T3/T4): raw s_barrier + counted waits; sched_barrier pins motion.
#define WAITV(N) asm volatile("s_waitcnt vmcnt(" #N ")" ::: "memory")
#define WAITV0 asm volatile("s_waitcnt vmcnt(0)" ::: "memory")
#define LGKM0  asm volatile("s_waitcnt lgkmcnt(0)" ::: "memory")
#define FENCE  asm volatile("" ::: "memory")
#define SBAR   __builtin_amdgcn_s_barrier()
#define SCHED0 __builtin_amdgcn_sched_barrier(0)
#define PRIO(x) __builtin_amdgcn_s_setprio(x)
#define PH_PRE  do { FENCE; SBAR; LGKM0; SCHED0; PRIO(1); } while (0)
#define PH_POST do { PRIO(0); FENCE; SBAR; SCHED0; } while (0)

// ------- fp32 [E][R][C] -> bf16 [E][C][R] transpose-cast, 64x64, coalesced ushort8 -------
__global__ __launch_bounds__(256) void transpose_cast_kernel(const float* __restrict__ src,
                                                             unsigned short* __restrict__ dst,
                                                             int R, int C) {
  __shared__ float tile_t[64][68];   // transposed store; row stride 272B (16B mult)
  int e = blockIdx.z;
  const float* s = src + (size_t)e * R * C;
  unsigned short* d = dst + (size_t)e * R * C;
  int r0 = blockIdx.y * 64, c0 = blockIdx.x * 64;
  int tr = threadIdx.x >> 4;            // 0..15
  int tc4 = (threadIdx.x & 15) * 4;     // 0..60
#pragma unroll
  for (int s4 = 0; s4 < 4; ++s4) {
    float4 v = *(const float4*)(s + (size_t)(r0 + tr + s4 * 16) * C + c0 + tc4);
    tile_t[tc4 + 0][tr + s4 * 16] = v.x;
    tile_t[tc4 + 1][tr + s4 * 16] = v.y;
    tile_t[tc4 + 2][tr + s4 * 16] = v.z;
    tile_t[tc4 + 3][tr + s4 * 16] = v.w;
  }
  __syncthreads();
  int cw = threadIdx.x >> 3;            // 0..31
  int r8 = (threadIdx.x & 7) * 8;       // 0..56
#pragma unroll
  for (int pass = 0; pass < 2; ++pass) {
    int c = cw + pass * 32;
    float4 a = *(const float4*)&tile_t[c][r8];
    float4 b = *(const float4*)&tile_t[c][r8 + 4];
    u16x8 o;
    o[0] = f2bf(a.x); o[1] = f2bf(a.y); o[2] = f2bf(a.z); o[3] = f2bf(a.w);
    o[4] = f2bf(b.x); o[5] = f2bf(b.y); o[6] = f2bf(b.z); o[7] = f2bf(b.w);
    *(u16x8*)(d + (size_t)(c0 + c) * R + r0 + r8) = o;   // 8 lanes = 128B contiguous
  }
}

// ------- router (fused x->bf16 cast): scores (fp64), top-2, softmax, compact -------
// idx entry = tok | (slot<<15); wslot[0][t], wslot[1][t] = softmax weights by slot.
__global__ __launch_bounds__(256) void router_kernel(const float* __restrict__ x,
                                                     const float* __restrict__ gw,
                                                     unsigned short* __restrict__ xb,
                                                     int* __restrict__ cnt,
                                                     int* __restrict__ idx,
                                                     float* __restrict__ wslot) {
  int wid = threadIdx.x >> 6;
  int lane = threadIdx.x & 63;
  int t = blockIdx.x * 4 + wid;
  double acc[NE];
#pragma unroll
  for (int e = 0; e < NE; ++e) acc[e] = 0.0;
  const float* xr = x + (size_t)t * DIM;
  unsigned short* xbr = xb + (size_t)t * DIM;
#pragma unroll 4
  for (int i = 0; i < DIM / 64; ++i) {
    int d = i * 64 + lane;
    float xf = xr[d];
    xbr[d] = f2bf(xf);                 // fused cast (coalesced 2B/lane)
    double xv = (double)xf;
#pragma unroll
    for (int e = 0; e < NE; ++e) acc[e] += xv * (double)gw[e * DIM + d];
  }
#pragma unroll
  for (int e = 0; e < NE; ++e) {
#pragma unroll
    for (int off = 32; off >= 1; off >>= 1) acc[e] += __shfl_xor(acc[e], off);
  }
  if (lane == 0) {
    int e0 = 0; double s0 = acc[0];
#pragma unroll
    for (int e = 1; e < NE; ++e) if (acc[e] > s0) { s0 = acc[e]; e0 = e; }
    int e1 = -1; double s1 = -1.0e300;
#pragma unroll
    for (int e = 0; e < NE; ++e) if (e != e0 && acc[e] > s1) { s1 = acc[e]; e1 = e; }
    double w0 = 1.0 / (1.0 + exp(s1 - s0));   // softmax over {s0,s1}, s0 >= s1
    wslot[t] = (float)w0;
    wslot[T_TOK + t] = (float)(1.0 - w0);
    int p0 = atomicAdd(&cnt[e0], 1);
    idx[e0 * T_TOK + p0] = t;                 // slot 0
    int p1 = atomicAdd(&cnt[e1], 1);
    idx[e1 * T_TOK + p1] = t | (1 << 15);     // slot 1
  }
}

// ------------- prep: offsets + compact tile lists (sorted e,n,m; BM=256) -------------
#define NT1 (HID / 128)   // 22 (gemm1 BN=128)
#define NT2 (DIM / 256)   // 4  (gemm2 BN=256)
__global__ __launch_bounds__(256) void prep_kernel(const int* __restrict__ cnt,
                                                   int* __restrict__ offs,
                                                   int* __restrict__ ntl,
                                                   int* __restrict__ tl1,
                                                   int* __restrict__ tl2) {
  __shared__ int smt[NE], stb1[NE + 1], stb2[NE + 1];
  if (threadIdx.x == 0) {
    int s = 0, t1 = 0, t2 = 0;
    for (int e = 0; e < NE; ++e) {
      offs[e] = s; s += cnt[e];
      int mt = (cnt[e] + 255) >> 8;
      smt[e] = mt;
      stb1[e] = t1; t1 += mt * NT1;
      stb2[e] = t2; t2 += mt * NT2;
    }
    stb1[NE] = t1; stb2[NE] = t2;
    ntl[0] = t1; ntl[1] = t2;
  }
  __syncthreads();
  for (int k = threadIdx.x; k < stb1[NE]; k += 256) {
    int e = 0;
    while (e < NE - 1 && k >= stb1[e + 1]) ++e;
    int rem = k - stb1[e], mt = smt[e];
    int n = rem / mt, m = rem - n * mt;
    tl1[k] = (e << 16) | (n << 8) | m;
  }
  for (int k = threadIdx.x; k < stb2[NE]; k += 256) {
    int e = 0;
    while (e < NE - 1 && k >= stb2[e + 1]) ++e;
    int rem = k - stb2[e], mt = smt[e];
    int n = rem / mt, m = rem - n * mt;
    tl2[k] = (e << 16) | (n << 8) | m;
  }
}

// Bijective XCD-chunk decode (m204). NSCALE = BN of the consumer.
__device__ __forceinline__ bool tile_decode(const int* ntl, int slot, const int* tl,
                                            int nscale, int& e, int& n0, int& m0) {
  int nt = ntl[slot];
  int q = nt >> 3, r = nt & 7;
  int xcd = blockIdx.x & 7, pos = blockIdx.x >> 3;
  int cap = xcd < r ? q + 1 : q;
  if (pos >= cap) return false;
  int lid = (xcd < r ? xcd * (q + 1) : r * (q + 1) + (xcd - r) * q) + pos;
  int ent = tl[lid];
  e = ent >> 16;
  n0 = ((ent >> 8) & 255) * nscale;
  m0 = (ent & 255) * 256;
  return true;
}

// ============ GEMM1: h = silu(Xg @ w1) * (Xg @ w3) — 8-phase, counted vmcnt ============
// BM=256, BN=128 (dual-B), BK=64, 8 waves (2M x 4N), dbuf LDS 128KB. (r8-proven, unchanged)
__global__ __launch_bounds__(512, 1) void gemm1_kernel(const unsigned short* __restrict__ xb,
                                                       const unsigned short* __restrict__ w1t,
                                                       const unsigned short* __restrict__ w3t,
                                                       const int* __restrict__ cnt,
                                                       const int* __restrict__ offs,
                                                       const int* __restrict__ ntl,
                                                       const int* __restrict__ tl1,
                                                       const int* __restrict__ idx,
                                                       unsigned short* __restrict__ hbuf) {
  int e, n0, m0;
  if (!tile_decode(ntl, 0, tl1, 128, e, n0, m0)) return;
  int c = cnt[e];

  __shared__ __align__(16) unsigned short As[2 * 16384];   // [2][256][64]
  __shared__ __align__(16) unsigned short B1s[2 * 8192];   // [2][128][64]
  __shared__ __align__(16) unsigned short B3s[2 * 8192];

  const int t = threadIdx.x;
  const int wid = t >> 6, lane = t & 63;
  const int wm = wid >> 2, wn = wid & 3;
  const int lr = lane & 15, kc = lane >> 4, sw = lane & 7;
  const int ldst = wid * 512;           // wave-uniform elems within an 8KB instr chunk
  const int trow = t >> 3;              // 0..63
  const int swzk = ((t & 7) ^ ((t >> 3) & 7)) * 8;   // pre-swizzled source k-chunk

  const int* idx_e = idx + e * T_TOK;
  int g0 = m0 + trow, g1 = m0 + 64 + trow, g2 = m0 + 128 + trow, g3 = m0 + 192 + trow;
  int tk0 = (g0 < c) ? (idx_e[g0] & 0x1FFF) : 0;
  int tk1 = (g1 < c) ? (idx_e[g1] & 0x1FFF) : 0;
  int tk2 = (g2 < c) ? (idx_e[g2] & 0x1FFF) : 0;
  int tk3 = (g3 < c) ? (idx_e[g3] & 0x1FFF) : 0;
  const unsigned short* aS0 = xb + (size_t)tk0 * DIM + swzk;
  const unsigned short* aS1 = xb + (size_t)tk1 * DIM + swzk;
  const unsigned short* aS2 = xb + (size_t)tk2 * DIM + swzk;
  const unsigned short* aS3 = xb + (size_t)tk3 * DIM + swzk;
  const unsigned short* w1e = w1t + ((size_t)e * HID + n0) * DIM;
  const unsigned short* w3e = w3t + ((size_t)e * HID + n0) * DIM;
  const unsigned short* b1S0 = w1e + (size_t)trow * DIM + swzk;
  const unsigned short* b1S1 = w1e + (size_t)(64 + trow) * DIM + swzk;
  const unsigned short* b3S0 = w3e + (size_t)trow * DIM + swzk;
  const unsigned short* b3S1 = w3e + (size_t)(64 + trow) * DIM + swzk;

  f32x4 acc1[8][2], acc3[8][2];
#pragma unroll
  for (int i = 0; i < 8; ++i)
#pragma unroll
    for (int j = 0; j < 2; ++j) {
      acc1[i][j] = f32x4{0.f, 0.f, 0.f, 0.f};
      acc3[i][j] = f32x4{0.f, 0.f, 0.f, 0.f};
    }
  bf16x8 ra[4], rb1[2], rb3[2];

#define G1_STG_A(CUR, TILE) do {                                      \
    g2l16(aS0 + (TILE) * 64, As + (CUR) * 16384 + 0 * 4096 + ldst);   \
    g2l16(aS1 + (TILE) * 64, As + (CUR) * 16384 + 1 * 4096 + ldst);   \
    g2l16(aS2 + (TILE) * 64, As + (CUR) * 16384 + 2 * 4096 + ldst);   \
    g2l16(aS3 + (TILE) * 64, As + (CUR) * 16384 + 3 * 4096 + ldst);   \
  } while (0)
#define G1_STG_B(CUR, TILE) do {                                      \
    g2l16(b1S0 + (TILE) * 64, B1s + (CUR) * 8192 + 0 * 4096 + ldst);  \
    g2l16(b1S1 + (TILE) * 64, B1s + (CUR) * 8192 + 1 * 4096 + ldst);  \
    g2l16(b3S0 + (TILE) * 64, B3s + (CUR) * 8192 + 0 * 4096 + ldst);  \
    g2l16(b3S1 + (TILE) * 64, B3s + (CUR) * 8192 + 1 * 4096 + ldst);  \
  } while (0)
#define G1_LDB(CUR, KS2) do {                                                          \
    const int se = ((((KS2) * 4) + kc) ^ sw) * 8;                                      \
    rb1[0] = *(const bf16x8*)(B1s + (CUR) * 8192 + (wn * 32 + lr) * 64 + se);          \
    rb1[1] = *(const bf16x8*)(B1s + (CUR) * 8192 + (wn * 32 + 16 + lr) * 64 + se);     \
    rb3[0] = *(const bf16x8*)(B3s + (CUR) * 8192 + (wn * 32 + lr) * 64 + se);          \
    rb3[1] = *(const bf16x8*)(B3s + (CUR) * 8192 + (wn * 32 + 16 + lr) * 64 + se);     \
  } while (0)
#define G1_LDA(CUR, KS2, IH) do {                                                      \
    const int se = ((((KS2) * 4) + kc) ^ sw) * 8;                                      \
    const int ab = (CUR) * 16384 + (wm * 128 + lr) * 64 + (IH) * 4096 + se;            \
    ra[0] = *(const bf16x8*)(As + ab + 0 * 1024);                                      \
    ra[1] = *(const bf16x8*)(As + ab + 1 * 1024);                                      \
    ra[2] = *(const bf16x8*)(As + ab + 2 * 1024);                                      \
    ra[3] = *(const bf16x8*)(As + ab + 3 * 1024);                                      \
  } while (0)
#define G1_MM(IH) do {                                                                 \
    _Pragma("unroll") for (int f = 0; f < 4; ++f)                                      \
      _Pragma("unroll") for (int j = 0; j < 2; ++j) {                                  \
        acc1[(IH) * 4 + f][j] =                                                        \
            __builtin_amdgcn_mfma_f32_16x16x32_bf16(ra[f], rb1[j], acc1[(IH) * 4 + f][j], 0, 0, 0); \
        acc3[(IH) * 4 + f][j] =                                                        \
            __builtin_amdgcn_mfma_f32_16x16x32_bf16(ra[f], rb3[j], acc3[(IH) * 4 + f][j], 0, 0, 0); \
      }                                                                                \
  } while (0)
#define G1_ITER(CUR, KT, DOSTAGE) do {                                                 \
    G1_LDB(CUR, 0); G1_LDA(CUR, 0, 0);                                                 \
    PH_PRE; G1_MM(0); PH_POST;                                                         \
    G1_LDA(CUR, 0, 1);                                                                 \
    PH_PRE; G1_MM(1); PH_POST;                                                         \
    G1_LDB(CUR, 1); G1_LDA(CUR, 1, 0);                                                 \
    PH_PRE; G1_MM(0); PH_POST;                                                         \
    G1_LDA(CUR, 1, 1);                                                                 \
    FENCE; SBAR; LGKM0; SCHED0; PRIO(1); G1_MM(1); PRIO(0); SCHED0;                    \
    if (DOSTAGE) { G1_STG_A(CUR, (KT) + 2); G1_STG_B(CUR, (KT) + 2); WAITV(8); }       \
    else WAITV0;                                                                       \
    FENCE; SBAR; SCHED0;                                                               \
  } while (0)

  G1_STG_A(0, 0); G1_STG_B(0, 0);
  G1_STG_A(1, 1); G1_STG_B(1, 1);
  WAITV(8); FENCE; SBAR; SCHED0;

  const int NK = DIM / 64;   // 16
#pragma unroll 1
  for (int kt = 0; kt < NK; kt += 2) {
    G1_ITER(0, kt, (kt + 2) < NK);
    G1_ITER(1, kt + 1, (kt + 3) < NK);
  }

  int base = offs[e];
#pragma unroll
  for (int i = 0; i < 8; ++i)
#pragma unroll
    for (int q = 0; q < 4; ++q) {
      int pl = m0 + wm * 128 + i * 16 + kc * 4 + q;
      if (pl >= c) continue;
      unsigned short* hrow = hbuf + (size_t)(base + pl) * HID + n0 + wn * 32 + lr;
#pragma unroll
      for (int j = 0; j < 2; ++j) {
        float v1 = acc1[i][j][q];
        float v3 = acc3[i][j][q];
        float hv = v1 / (1.0f + __expf(-v1)) * v3;   // silu(v1) * v3
        hrow[j * 16] = f2bf(hv);
      }
    }
}

// ============ GEMM2: part[slot][tok] = h @ w2 — BN=256, counted vmcnt ============
// BM=256, BN=256, BK=64, 8 waves (4M x 2N, per-wave 64x128), dbuf LDS 128KB.
// ~280 blocks ≈ 1.1/CU; 32 MFMA per phase. No atomics (slot-partitioned outputs).
__global__ __launch_bounds__(512, 1) void gemm2_kernel(const unsigned short* __restrict__ hbuf,
                                                       const unsigned short* __restrict__ w2t,
                                                       const int* __restrict__ cnt,
                                                       const int* __restrict__ offs,
                                                       const int* __restrict__ ntl,
                                                       const int* __restrict__ tl2,
                                                       const int* __restrict__ idx,
                                                       float* __restrict__ part0,
                                                       float* __restrict__ part1) {
  int e, n0, m0;
  if (!tile_decode(ntl, 1, tl2, 256, e, n0, m0)) return;
  int c = cnt[e];
  int base = offs[e];

  __shared__ __align__(16) unsigned short As[2 * 16384];   // [2][256][64]
  __shared__ __align__(16) unsigned short Bs[2 * 16384];   // [2][256][64]

  const int t = threadIdx.x;
  const int wid = t >> 6, lane = t & 63;
  const int wm = wid >> 1, wn = wid & 1;       // 4M x 2N
  const int lr = lane & 15, kc = lane >> 4, sw = lane & 7;
  const int ldst = wid * 512;
  const int trow = t >> 3;
  const int swzk = ((t & 7) ^ ((t >> 3) & 7)) * 8;

  int r0 = imin(base + m0 + trow,       2 * T_TOK - 1);
  int r1 = imin(base + m0 + 64 + trow,  2 * T_TOK - 1);
  int r2 = imin(base + m0 + 128 + trow, 2 * T_TOK - 1);
  int r3 = imin(base + m0 + 192 + trow, 2 * T_TOK - 1);
  const unsigned short* aS0 = hbuf + (size_t)r0 * HID + swzk;
  const unsigned short* aS1 = hbuf + (size_t)r1 * HID + swzk;
  const unsigned short* aS2 = hbuf + (size_t)r2 * HID + swzk;
  const unsigned short* aS3 = hbuf + (size_t)r3 * HID + swzk;
  const unsigned short* w2e = w2t + ((size_t)e * DIM + n0) * HID;
  const unsigned short* bS0 = w2e + (size_t)trow * HID + swzk;
  const unsigned short* bS1 = w2e + (size_t)(64 + trow) * HID + swzk;
  const unsigned short* bS2 = w2e + (size_t)(128 + trow) * HID + swzk;
  const unsigned short* bS3 = w2e + (size_t)(192 + trow) * HID + swzk;

  f32x4 acc[4][8];
#pragma unroll
  for (int i = 0; i < 4; ++i)
#pragma unroll
    for (int j = 0; j < 8; ++j) acc[i][j] = f32x4{0.f, 0.f, 0.f, 0.f};
  bf16x8 ra[4], rb[8];

#define G2_STG(CUR, TILE) do {                                        \
    g2l16(aS0 + (TILE) * 64, As + (CUR) * 16384 + 0 * 4096 + ldst);   \
    g2l16(aS1 + (TILE) * 64, As + (CUR) * 16384 + 1 * 4096 + ldst);   \
    g2l16(aS2 + (TILE) * 64, As + (CUR) * 16384 + 2 * 4096 + ldst);   \
    g2l16(aS3 + (TILE) * 64, As + (CUR) * 16384 + 3 * 4096 + ldst);   \
    g2l16(bS0 + (TILE) * 64, Bs + (CUR) * 16384 + 0 * 4096 + ldst);   \
    g2l16(bS1 + (TILE) * 64, Bs + (CUR) * 16384 + 1 * 4096 + ldst);   \
    g2l16(bS2 + (TILE) * 64, Bs + (CUR) * 16384 + 2 * 4096 + ldst);   \
    g2l16(bS3 + (TILE) * 64, Bs + (CUR) * 16384 + 3 * 4096 + ldst);   \
  } while (0)
#define G2_LD(CUR, KS2) do {                                                          \
    const int se = ((((KS2) * 4) + kc) ^ sw) * 8;                                     \
    const int ab = (CUR) * 16384 + (wm * 64 + lr) * 64 + se;                          \
    _Pragma("unroll") for (int f = 0; f < 4; ++f)                                     \
      ra[f] = *(const bf16x8*)(As + ab + f * 1024);                                   \
    const int bb = (CUR) * 16384 + (wn * 128 + lr) * 64 + se;                         \
    _Pragma("unroll") for (int j = 0; j < 8; ++j)                                     \
      rb[j] = *(const bf16x8*)(Bs + bb + j * 1024);                                   \
  } while (0)
#define G2_MM() do {                                                                  \
    _Pragma("unroll") for (int f = 0; f < 4; ++f)                                     \
      _Pragma("unroll") for (int j = 0; j < 8; ++j)                                   \
        acc[f][j] = __builtin_amdgcn_mfma_f32_16x16x32_bf16(ra[f], rb[j], acc[f][j], 0, 0, 0); \
  } while (0)
#define G2_ITER(CUR, KT, DOSTAGE) do {                                                \
    G2_LD(CUR, 0);                                                                    \
    PH_PRE; G2_MM(); PH_POST;                                                         \
    G2_LD(CUR, 1);                                                                    \
    FENCE; SBAR; LGKM0; SCHED0; PRIO(1); G2_MM(); PRIO(0); SCHED0;                    \
    if (DOSTAGE) { G2_STG(CUR, (KT) + 2); WAITV(8); }                                 \
    else WAITV0;                                                                      \
    FENCE; SBAR; SCHED0;                                                              \
  } while (0)

  G2_STG(0, 0);
  G2_STG(1, 1);
  WAITV(8); FENCE; SBAR; SCHED0;

  const int NK = HID / 64;   // 44
#pragma unroll 1
  for (int kt = 0; kt < NK; kt += 2) {
    G2_ITER(0, kt, (kt + 2) < NK);
    G2_ITER(1, kt + 1, (kt + 3) < NK);
  }

  const int* idx_e = idx + e * T_TOK;
#pragma unroll
  for (int i = 0; i < 4; ++i)
#pragma unroll
    for (int q = 0; q < 4; ++q) {
      int pl = m0 + wm * 64 + i * 16 + kc * 4 + q;
      if (pl >= c) continue;
      int ent = idx_e[pl];
      int tok = ent & 0x1FFF;
      float* pp = (ent & (1 << 15)) ? part1 : part0;
      float* orow = pp + (size_t)tok * DIM + n0 + wn * 128 + lr;
#pragma unroll
      for (int j = 0; j < 8; ++j)
        orow[j * 16] = acc[i][j][q];
    }
}

// ---------------- combine: out = w0*part0 + w1*part1 ----------------
__global__ __launch_bounds__(256) void combine_kernel(const float* __restrict__ p0,
                                                      const float* __restrict__ p1,
                                                      const float* __restrict__ wslot,
                                                      float* __restrict__ out) {
  int i = blockIdx.x * 256 + threadIdx.x;     // float4 index
  int tok = i >> 8;                           // DIM/4 = 256 float4 per token
  float w0 = wslot[tok], w1 = wslot[T_TOK + tok];
  float4 a = ((const float4*)p0)[i];
  float4 b = ((const float4*)p1)[i];
  float4 o;
  o.x = w0 * a.x + w1 * b.x;
  o.y = w0 * a.y + w1 * b.y;
  o.z = w0 * a.z + w1 * b.z;
  o.w = w0 * a.w + w1 * b.w;
  ((float4*)out)[i] = o;
}

extern "C" void kernel_launch(void* const* d_in, const int* in_sizes, int n_in,
                              void* d_out, int out_size, void* d_ws, size_t ws_size,
                              hipStream_t stream) {
  const float* x  = (const float*)d_in[0];
  const float* gw = (const float*)d_in[1];
  const float* w1 = (const float*)d_in[2];
  const float* w2 = (const float*)d_in[3];
  const float* w3 = (const float*)d_in[4];
  float* out = (float*)d_out;

  // Workspace layout (~249 MB total); part[2] aliases w1t/w3t (dead after gemm1).
  char* ws = (char*)d_ws;
  size_t off = 0;
  auto alloc = [&](size_t bytes) {
    char* p = ws + off;
    off += (bytes + 255) & ~(size_t)255;
    return p;
  };
  unsigned short* xb  = (unsigned short*)alloc((size_t)T_TOK * DIM * 2);       // 16.8 MB
  unsigned short* w1t = (unsigned short*)alloc((size_t)NE * DIM * HID * 2);    // 46.1 MB  [E][H][D]
  unsigned short* w3t = (unsigned short*)alloc((size_t)NE * DIM * HID * 2);    // 46.1 MB  [E][H][D]
  unsigned short* w2t = (unsigned short*)alloc((size_t)NE * DIM * HID * 2);    // 46.1 MB  [E][D][H]
  unsigned short* hb  = (unsigned short*)alloc((size_t)2 * T_TOK * HID * 2);   // 92.3 MB
  int*   cnt   = (int*)alloc(NE * sizeof(int));
  int*   offs  = (int*)alloc(NE * sizeof(int));
  int*   ntl   = (int*)alloc(2 * sizeof(int));
  int*   idx   = (int*)alloc((size_t)NE * T_TOK * sizeof(int));
  float* wslot = (float*)alloc((size_t)2 * T_TOK * sizeof(float));
  int*   tl1   = (int*)alloc((size_t)72 * NT1 * sizeof(int));
  int*   tl2   = (int*)alloc((size_t)72 * NT2 * sizeof(int));
  // part aliases w1t..w3t region: 2*T*D*4 = 67.1 MB <= 92.2 MB
  float* part0 = (float*)w1t;
  float* part1 = part0 + (size_t)T_TOK * DIM;

  hipMemsetAsync(cnt, 0, NE * sizeof(int), stream);

  router_kernel<<<T_TOK / 4, 256, 0, stream>>>(x, gw, xb, cnt, idx, wslot);
  transpose_cast_kernel<<<dim3(HID / 64, DIM / 64, NE), 256, 0, stream>>>(w1, w1t, DIM, HID);
  transpose_cast_kernel<<<dim3(HID / 64, DIM / 64, NE), 256, 0, stream>>>(w3, w3t, DIM, HID);
  transpose_cast_kernel<<<dim3(DIM / 64, HID / 64, NE), 256, 0, stream>>>(w2, w2t, HID, DIM);
  prep_kernel<<<1, 256, 0, stream>>>(cnt, offs, ntl, tl1, tl2);

  gemm1_kernel<<<72 * NT1, 512, 0, stream>>>(xb, w1t, w3t, cnt, offs, ntl, tl1, idx, hb);
  gemm2_kernel<<<72 * NT2, 512, 0, stream>>>(hb, w2t, cnt, offs, ntl, tl2, idx, part0, part1);
  combine_kernel<<<(T_TOK * DIM) / (4 * 256), 256, 0, stream>>>(part0, part1, wslot, out);
}

// Round 11
// 698.937 us; speedup vs baseline: 1.5836x; 1.0201x over previous
//
#include <hip/hip_runtime.h>
#include <math.h>

// Problem constants
#define T_TOK 8192   // B*S tokens
#define DIM   1024   // D
#define HID   2816   // H
#define NE    8      // experts
// K (top-k) = 2

typedef __attribute__((ext_vector_type(4))) float  f32x4;
typedef __attribute__((ext_vector_type(8))) __bf16 bf16x8;
typedef __attribute__((ext_vector_type(8))) unsigned short u16x8;

__device__ __forceinline__ unsigned short f2bf(float f) {
  unsigned int u = __builtin_bit_cast(unsigned int, f);
  unsigned int r = (u + 0x7FFFu + ((u >> 16) & 1u)) >> 16;   // RTNE
  return (unsigned short)r;
}
__device__ __forceinline__ int imin(int a, int b) { return a < b ? a : b; }

// global -> LDS direct DMA, 16B per lane. LDS dest = wave-uniform base + lane*16.
typedef const __attribute__((address_space(1))) void gvoid_t;
typedef __attribute__((address_space(3))) void svoid_t;
__device__ __forceinline__ void g2l16(const void* g, void* l) {
  __builtin_amdgcn_global_load_lds((gvoid_t*)g, (svoid_t*)l, 16, 0, 0);
}

// Pipeline fences (T3/T4): raw s_barrier + counted waits; sched_barrier pins motion.
#define WAITV(N) asm volatile("s_waitcnt vmcnt(" #N ")" ::: "memory")
#define WAITV0 asm volatile("s_waitcnt vmcnt(0)" ::: "memory")
#define LGKM0  asm volatile("s_waitcnt lgkmcnt(0)" ::: "memory")
#define FENCE  asm volatile("" ::: "memory")
#define SBAR   __builtin_amdgcn_s_barrier()
#define SCHED0 __builtin_amdgcn_sched_barrier(0)
#define PRIO(x) __builtin_amdgcn_s_setprio(x)
#define PH_PRE  do { FENCE; SBAR; LGKM0; SCHED0; PRIO(1); } while (0)
#define PH_POST do { PRIO(0); FENCE; SBAR; SCHED0; } while (0)

// ------- router (fused x->bf16 cast): scores (fp64), top-2, softmax, compact -------
// idx entry = tok | (slot<<15); wslot[0][t], wslot[1][t] = softmax weights by slot.
__global__ __launch_bounds__(256) void router_kernel(const float* __restrict__ x,
                                                     const float* __restrict__ gw,
                                                     unsigned short* __restrict__ xb,
                                                     int* __restrict__ cnt,
                                                     int* __restrict__ idx,
                                                     float* __restrict__ wslot) {
  int wid = threadIdx.x >> 6;
  int lane = threadIdx.x & 63;
  int t = blockIdx.x * 4 + wid;
  double acc[NE];
#pragma unroll
  for (int e = 0; e < NE; ++e) acc[e] = 0.0;
  const float* xr = x + (size_t)t * DIM;
  unsigned short* xbr = xb + (size_t)t * DIM;
#pragma unroll 4
  for (int i = 0; i < DIM / 64; ++i) {
    int d = i * 64 + lane;
    float xf = xr[d];
    xbr[d] = f2bf(xf);                 // fused cast (coalesced 2B/lane)
    double xv = (double)xf;
#pragma unroll
    for (int e = 0; e < NE; ++e) acc[e] += xv * (double)gw[e * DIM + d];
  }
#pragma unroll
  for (int e = 0; e < NE; ++e) {
#pragma unroll
    for (int off = 32; off >= 1; off >>= 1) acc[e] += __shfl_xor(acc[e], off);
  }
  if (lane == 0) {
    int e0 = 0; double s0 = acc[0];
#pragma unroll
    for (int e = 1; e < NE; ++e) if (acc[e] > s0) { s0 = acc[e]; e0 = e; }
    int e1 = -1; double s1 = -1.0e300;
#pragma unroll
    for (int e = 0; e < NE; ++e) if (e != e0 && acc[e] > s1) { s1 = acc[e]; e1 = e; }
    double w0 = 1.0 / (1.0 + exp(s1 - s0));   // softmax over {s0,s1}, s0 >= s1
    wslot[t] = (float)w0;
    wslot[T_TOK + t] = (float)(1.0 - w0);
    int p0 = atomicAdd(&cnt[e0], 1);
    idx[e0 * T_TOK + p0] = t;                 // slot 0
    int p1 = atomicAdd(&cnt[e1], 1);
    idx[e1 * T_TOK + p1] = t | (1 << 15);     // slot 1
  }
}

// ------- fused aux: 3x transpose-cast (64x64, coalesced ushort8) + prep (last block) -------
#define NT1 (HID / 128)   // 22 (gemm1 BN=128)
#define NT2 (DIM / 256)   // 4  (gemm2 BN=256)
#define TPM ((DIM / 64) * (HID / 64) * NE)   // 5632 blocks per matrix
__global__ __launch_bounds__(256) void aux_kernel(const float* __restrict__ w1,
                                                  const float* __restrict__ w3,
                                                  const float* __restrict__ w2,
                                                  unsigned short* __restrict__ w1t,
                                                  unsigned short* __restrict__ w3t,
                                                  unsigned short* __restrict__ w2t,
                                                  const int* __restrict__ cnt,
                                                  int* __restrict__ offs,
                                                  int* __restrict__ ntl,
                                                  int* __restrict__ tl1,
                                                  int* __restrict__ tl2) {
  int bid = blockIdx.x;
  if (bid == 3 * TPM) {
    // ---- prep: offsets + compact tile lists (sorted e,n,m; BM=256) ----
    __shared__ int smt[NE], stb1[NE + 1], stb2[NE + 1];
    if (threadIdx.x == 0) {
      int s = 0, t1 = 0, t2 = 0;
      for (int e = 0; e < NE; ++e) {
        offs[e] = s; s += cnt[e];
        int mt = (cnt[e] + 255) >> 8;
        smt[e] = mt;
        stb1[e] = t1; t1 += mt * NT1;
        stb2[e] = t2; t2 += mt * NT2;
      }
      stb1[NE] = t1; stb2[NE] = t2;
      ntl[0] = t1; ntl[1] = t2;
    }
    __syncthreads();
    for (int k = threadIdx.x; k < stb1[NE]; k += 256) {
      int e = 0;
      while (e < NE - 1 && k >= stb1[e + 1]) ++e;
      int rem = k - stb1[e], mt = smt[e];
      int n = rem / mt, m = rem - n * mt;
      tl1[k] = (e << 16) | (n << 8) | m;
    }
    for (int k = threadIdx.x; k < stb2[NE]; k += 256) {
      int e = 0;
      while (e < NE - 1 && k >= stb2[e + 1]) ++e;
      int rem = k - stb2[e], mt = smt[e];
      int n = rem / mt, m = rem - n * mt;
      tl2[k] = (e << 16) | (n << 8) | m;
    }
    return;
  }

  // ---- transpose segment ----
  int seg = bid / TPM, r = bid % TPM;
  const float* srcm; unsigned short* dstm; int R, C;
  if (seg == 0)      { srcm = w1; dstm = w1t; R = DIM; C = HID; }
  else if (seg == 1) { srcm = w3; dstm = w3t; R = DIM; C = HID; }
  else               { srcm = w2; dstm = w2t; R = HID; C = DIM; }
  int per_e = (R / 64) * (C / 64);
  int e = r / per_e, tt = r % per_e;
  int nx = C / 64;
  int c0 = (tt % nx) * 64, r0 = (tt / nx) * 64;

  __shared__ float tile_t[64][68];   // transposed store; row stride 272B (16B mult)
  const float* s = srcm + (size_t)e * R * C;
  unsigned short* d = dstm + (size_t)e * R * C;
  int tr = threadIdx.x >> 4;            // 0..15
  int tc4 = (threadIdx.x & 15) * 4;     // 0..60
#pragma unroll
  for (int s4 = 0; s4 < 4; ++s4) {
    float4 v = *(const float4*)(s + (size_t)(r0 + tr + s4 * 16) * C + c0 + tc4);
    tile_t[tc4 + 0][tr + s4 * 16] = v.x;
    tile_t[tc4 + 1][tr + s4 * 16] = v.y;
    tile_t[tc4 + 2][tr + s4 * 16] = v.z;
    tile_t[tc4 + 3][tr + s4 * 16] = v.w;
  }
  __syncthreads();
  int cw = threadIdx.x >> 3;            // 0..31
  int r8 = (threadIdx.x & 7) * 8;       // 0..56
#pragma unroll
  for (int pass = 0; pass < 2; ++pass) {
    int c = cw + pass * 32;
    float4 a = *(const float4*)&tile_t[c][r8];
    float4 b = *(const float4*)&tile_t[c][r8 + 4];
    u16x8 o;
    o[0] = f2bf(a.x); o[1] = f2bf(a.y); o[2] = f2bf(a.z); o[3] = f2bf(a.w);
    o[4] = f2bf(b.x); o[5] = f2bf(b.y); o[6] = f2bf(b.z); o[7] = f2bf(b.w);
    *(u16x8*)(d + (size_t)(c0 + c) * R + r0 + r8) = o;   // 8 lanes = 128B contiguous
  }
}

// Bijective XCD-chunk decode (m204). NSCALE = BN of the consumer.
__device__ __forceinline__ bool tile_decode(const int* ntl, int slot, const int* tl,
                                            int nscale, int& e, int& n0, int& m0) {
  int nt = ntl[slot];
  int q = nt >> 3, r = nt & 7;
  int xcd = blockIdx.x & 7, pos = blockIdx.x >> 3;
  int cap = xcd < r ? q + 1 : q;
  if (pos >= cap) return false;
  int lid = (xcd < r ? xcd * (q + 1) : r * (q + 1) + (xcd - r) * q) + pos;
  int ent = tl[lid];
  e = ent >> 16;
  n0 = ((ent >> 8) & 255) * nscale;
  m0 = (ent & 255) * 256;
  return true;
}

// ====== GEMM1: h = silu(Xg @ w1) * (Xg @ w3) — 2 phases/K-tile (32 MFMA), counted vmcnt ======
// BM=256, BN=128 (dual-B), BK=64, 8 waves (2M x 4N), dbuf LDS 128KB.
__global__ __launch_bounds__(512, 1) void gemm1_kernel(const unsigned short* __restrict__ xb,
                                                       const unsigned short* __restrict__ w1t,
                                                       const unsigned short* __restrict__ w3t,
                                                       const int* __restrict__ cnt,
                                                       const int* __restrict__ offs,
                                                       const int* __restrict__ ntl,
                                                       const int* __restrict__ tl1,
                                                       const int* __restrict__ idx,
                                                       unsigned short* __restrict__ hbuf) {
  int e, n0, m0;
  if (!tile_decode(ntl, 0, tl1, 128, e, n0, m0)) return;
  int c = cnt[e];

  __shared__ __align__(16) unsigned short As[2 * 16384];   // [2][256][64]
  __shared__ __align__(16) unsigned short B1s[2 * 8192];   // [2][128][64]
  __shared__ __align__(16) unsigned short B3s[2 * 8192];

  const int t = threadIdx.x;
  const int wid = t >> 6, lane = t & 63;
  const int wm = wid >> 2, wn = wid & 3;
  const int lr = lane & 15, kc = lane >> 4, sw = lane & 7;
  const int ldst = wid * 512;           // wave-uniform elems within an 8KB instr chunk
  const int trow = t >> 3;              // 0..63
  const int swzk = ((t & 7) ^ ((t >> 3) & 7)) * 8;   // pre-swizzled source k-chunk

  const int* idx_e = idx + e * T_TOK;
  int g0 = m0 + trow, g1 = m0 + 64 + trow, g2 = m0 + 128 + trow, g3 = m0 + 192 + trow;
  int tk0 = (g0 < c) ? (idx_e[g0] & 0x1FFF) : 0;
  int tk1 = (g1 < c) ? (idx_e[g1] & 0x1FFF) : 0;
  int tk2 = (g2 < c) ? (idx_e[g2] & 0x1FFF) : 0;
  int tk3 = (g3 < c) ? (idx_e[g3] & 0x1FFF) : 0;
  const unsigned short* aS0 = xb + (size_t)tk0 * DIM + swzk;
  const unsigned short* aS1 = xb + (size_t)tk1 * DIM + swzk;
  const unsigned short* aS2 = xb + (size_t)tk2 * DIM + swzk;
  const unsigned short* aS3 = xb + (size_t)tk3 * DIM + swzk;
  const unsigned short* w1e = w1t + ((size_t)e * HID + n0) * DIM;
  const unsigned short* w3e = w3t + ((size_t)e * HID + n0) * DIM;
  const unsigned short* b1S0 = w1e + (size_t)trow * DIM + swzk;
  const unsigned short* b1S1 = w1e + (size_t)(64 + trow) * DIM + swzk;
  const unsigned short* b3S0 = w3e + (size_t)trow * DIM + swzk;
  const unsigned short* b3S1 = w3e + (size_t)(64 + trow) * DIM + swzk;

  f32x4 acc1[8][2], acc3[8][2];
#pragma unroll
  for (int i = 0; i < 8; ++i)
#pragma unroll
    for (int j = 0; j < 2; ++j) {
      acc1[i][j] = f32x4{0.f, 0.f, 0.f, 0.f};
      acc3[i][j] = f32x4{0.f, 0.f, 0.f, 0.f};
    }
  bf16x8 ra0[4], ra1[4], rb1[2], rb3[2];

#define G1_STG_A(CUR, TILE) do {                                      \
    g2l16(aS0 + (TILE) * 64, As + (CUR) * 16384 + 0 * 4096 + ldst);   \
    g2l16(aS1 + (TILE) * 64, As + (CUR) * 16384 + 1 * 4096 + ldst);   \
    g2l16(aS2 + (TILE) * 64, As + (CUR) * 16384 + 2 * 4096 + ldst);   \
    g2l16(aS3 + (TILE) * 64, As + (CUR) * 16384 + 3 * 4096 + ldst);   \
  } while (0)
#define G1_STG_B(CUR, TILE) do {                                      \
    g2l16(b1S0 + (TILE) * 64, B1s + (CUR) * 8192 + 0 * 4096 + ldst);  \
    g2l16(b1S1 + (TILE) * 64, B1s + (CUR) * 8192 + 1 * 4096 + ldst);  \
    g2l16(b3S0 + (TILE) * 64, B3s + (CUR) * 8192 + 0 * 4096 + ldst);  \
    g2l16(b3S1 + (TILE) * 64, B3s + (CUR) * 8192 + 1 * 4096 + ldst);  \
  } while (0)
// full phase loads: B frags + both A halves (12 x ds_read_b128)
#define G1_LDALL(CUR, KS2) do {                                                        \
    const int se = ((((KS2) * 4) + kc) ^ sw) * 8;                                      \
    rb1[0] = *(const bf16x8*)(B1s + (CUR) * 8192 + (wn * 32 + lr) * 64 + se);          \
    rb1[1] = *(const bf16x8*)(B1s + (CUR) * 8192 + (wn * 32 + 16 + lr) * 64 + se);     \
    rb3[0] = *(const bf16x8*)(B3s + (CUR) * 8192 + (wn * 32 + lr) * 64 + se);          \
    rb3[1] = *(const bf16x8*)(B3s + (CUR) * 8192 + (wn * 32 + 16 + lr) * 64 + se);     \
    const int ab = (CUR) * 16384 + (wm * 128 + lr) * 64 + se;                          \
    _Pragma("unroll") for (int f = 0; f < 4; ++f) {                                    \
      ra0[f] = *(const bf16x8*)(As + ab + f * 1024);                                   \
      ra1[f] = *(const bf16x8*)(As + ab + 4096 + f * 1024);                            \
    }                                                                                  \
  } while (0)
#define G1_MM2() do {                                                                  \
    _Pragma("unroll") for (int f = 0; f < 4; ++f)                                      \
      _Pragma("unroll") for (int j = 0; j < 2; ++j) {                                  \
        acc1[f][j] = __builtin_amdgcn_mfma_f32_16x16x32_bf16(ra0[f], rb1[j], acc1[f][j], 0, 0, 0); \
        acc3[f][j] = __builtin_amdgcn_mfma_f32_16x16x32_bf16(ra0[f], rb3[j], acc3[f][j], 0, 0, 0); \
      }                                                                                \
    _Pragma("unroll") for (int f = 0; f < 4; ++f)                                      \
      _Pragma("unroll") for (int j = 0; j < 2; ++j) {                                  \
        acc1[4 + f][j] = __builtin_amdgcn_mfma_f32_16x16x32_bf16(ra1[f], rb1[j], acc1[4 + f][j], 0, 0, 0); \
        acc3[4 + f][j] = __builtin_amdgcn_mfma_f32_16x16x32_bf16(ra1[f], rb3[j], acc3[4 + f][j], 0, 0, 0); \
      }                                                                                \
  } while (0)
// 2 phases per K-tile (32 MFMA each); stage kt+2 at end, counted vmcnt(8).
#define G1_ITER(CUR, KT, DOSTAGE) do {                                                 \
    G1_LDALL(CUR, 0);                                                                  \
    PH_PRE; G1_MM2(); PH_POST;                                                         \
    G1_LDALL(CUR, 1);                                                                  \
    FENCE; SBAR; LGKM0; SCHED0; PRIO(1); G1_MM2(); PRIO(0); SCHED0;                    \
    if (DOSTAGE) { G1_STG_A(CUR, (KT) + 2); G1_STG_B(CUR, (KT) + 2); WAITV(8); }       \
    else WAITV0;                                                                       \
    FENCE; SBAR; SCHED0;                                                               \
  } while (0)

  G1_STG_A(0, 0); G1_STG_B(0, 0);
  G1_STG_A(1, 1); G1_STG_B(1, 1);
  WAITV(8); FENCE; SBAR; SCHED0;

  const int NK = DIM / 64;   // 16
#pragma unroll 1
  for (int kt = 0; kt < NK; kt += 2) {
    G1_ITER(0, kt, (kt + 2) < NK);
    G1_ITER(1, kt + 1, (kt + 3) < NK);
  }

  int base = offs[e];
#pragma unroll
  for (int i = 0; i < 8; ++i)
#pragma unroll
    for (int q = 0; q < 4; ++q) {
      int pl = m0 + wm * 128 + i * 16 + kc * 4 + q;
      if (pl >= c) continue;
      unsigned short* hrow = hbuf + (size_t)(base + pl) * HID + n0 + wn * 32 + lr;
#pragma unroll
      for (int j = 0; j < 2; ++j) {
        float v1 = acc1[i][j][q];
        float v3 = acc3[i][j][q];
        float hv = v1 / (1.0f + __expf(-v1)) * v3;   // silu(v1) * v3
        hrow[j * 16] = f2bf(hv);
      }
    }
}

// ============ GEMM2: part[slot][tok] = h @ w2 — BN=256, counted vmcnt ============
// BM=256, BN=256, BK=64, 8 waves (4M x 2N, per-wave 64x128), dbuf LDS 128KB.
__global__ __launch_bounds__(512, 1) void gemm2_kernel(const unsigned short* __restrict__ hbuf,
                                                       const unsigned short* __restrict__ w2t,
                                                       const int* __restrict__ cnt,
                                                       const int* __restrict__ offs,
                                                       const int* __restrict__ ntl,
                                                       const int* __restrict__ tl2,
                                                       const int* __restrict__ idx,
                                                       float* __restrict__ part0,
                                                       float* __restrict__ part1) {
  int e, n0, m0;
  if (!tile_decode(ntl, 1, tl2, 256, e, n0, m0)) return;
  int c = cnt[e];
  int base = offs[e];

  __shared__ __align__(16) unsigned short As[2 * 16384];   // [2][256][64]
  __shared__ __align__(16) unsigned short Bs[2 * 16384];   // [2][256][64]

  const int t = threadIdx.x;
  const int wid = t >> 6, lane = t & 63;
  const int wm = wid >> 1, wn = wid & 1;       // 4M x 2N
  const int lr = lane & 15, kc = lane >> 4, sw = lane & 7;
  const int ldst = wid * 512;
  const int trow = t >> 3;
  const int swzk = ((t & 7) ^ ((t >> 3) & 7)) * 8;

  int r0 = imin(base + m0 + trow,       2 * T_TOK - 1);
  int r1 = imin(base + m0 + 64 + trow,  2 * T_TOK - 1);
  int r2 = imin(base + m0 + 128 + trow, 2 * T_TOK - 1);
  int r3 = imin(base + m0 + 192 + trow, 2 * T_TOK - 1);
  const unsigned short* aS0 = hbuf + (size_t)r0 * HID + swzk;
  const unsigned short* aS1 = hbuf + (size_t)r1 * HID + swzk;
  const unsigned short* aS2 = hbuf + (size_t)r2 * HID + swzk;
  const unsigned short* aS3 = hbuf + (size_t)r3 * HID + swzk;
  const unsigned short* w2e = w2t + ((size_t)e * DIM + n0) * HID;
  const unsigned short* bS0 = w2e + (size_t)trow * HID + swzk;
  const unsigned short* bS1 = w2e + (size_t)(64 + trow) * HID + swzk;
  const unsigned short* bS2 = w2e + (size_t)(128 + trow) * HID + swzk;
  const unsigned short* bS3 = w2e + (size_t)(192 + trow) * HID + swzk;

  f32x4 acc[4][8];
#pragma unroll
  for (int i = 0; i < 4; ++i)
#pragma unroll
    for (int j = 0; j < 8; ++j) acc[i][j] = f32x4{0.f, 0.f, 0.f, 0.f};
  bf16x8 ra[4], rb[8];

#define G2_STG(CUR, TILE) do {                                        \
    g2l16(aS0 + (TILE) * 64, As + (CUR) * 16384 + 0 * 4096 + ldst);   \
    g2l16(aS1 + (TILE) * 64, As + (CUR) * 16384 + 1 * 4096 + ldst);   \
    g2l16(aS2 + (TILE) * 64, As + (CUR) * 16384 + 2 * 4096 + ldst);   \
    g2l16(aS3 + (TILE) * 64, As + (CUR) * 16384 + 3 * 4096 + ldst);   \
    g2l16(bS0 + (TILE) * 64, Bs + (CUR) * 16384 + 0 * 4096 + ldst);   \
    g2l16(bS1 + (TILE) * 64, Bs + (CUR) * 16384 + 1 * 4096 + ldst);   \
    g2l16(bS2 + (TILE) * 64, Bs + (CUR) * 16384 + 2 * 4096 + ldst);   \
    g2l16(bS3 + (TILE) * 64, Bs + (CUR) * 16384 + 3 * 4096 + ldst);   \
  } while (0)
#define G2_LD(CUR, KS2) do {                                                          \
    const int se = ((((KS2) * 4) + kc) ^ sw) * 8;                                     \
    const int ab = (CUR) * 16384 + (wm * 64 + lr) * 64 + se;                          \
    _Pragma("unroll") for (int f = 0; f < 4; ++f)                                     \
      ra[f] = *(const bf16x8*)(As + ab + f * 1024);                                   \
    const int bb = (CUR) * 16384 + (wn * 128 + lr) * 64 + se;                         \
    _Pragma("unroll") for (int j = 0; j < 8; ++j)                                     \
      rb[j] = *(const bf16x8*)(Bs + bb + j * 1024);                                   \
  } while (0)
#define G2_MM() do {                                                                  \
    _Pragma("unroll") for (int f = 0; f < 4; ++f)                                     \
      _Pragma("unroll") for (int j = 0; j < 8; ++j)                                   \
        acc[f][j] = __builtin_amdgcn_mfma_f32_16x16x32_bf16(ra[f], rb[j], acc[f][j], 0, 0, 0); \
  } while (0)
#define G2_ITER(CUR, KT, DOSTAGE) do {                                                \
    G2_LD(CUR, 0);                                                                    \
    PH_PRE; G2_MM(); PH_POST;                                                         \
    G2_LD(CUR, 1);                                                                    \
    FENCE; SBAR; LGKM0; SCHED0; PRIO(1); G2_MM(); PRIO(0); SCHED0;                    \
    if (DOSTAGE) { G2_STG(CUR, (KT) + 2); WAITV(8); }                                 \
    else WAITV0;                                                                      \
    FENCE; SBAR; SCHED0;                                                              \
  } while (0)

  G2_STG(0, 0);
  G2_STG(1, 1);
  WAITV(8); FENCE; SBAR; SCHED0;

  const int NK = HID / 64;   // 44
#pragma unroll 1
  for (int kt = 0; kt < NK; kt += 2) {
    G2_ITER(0, kt, (kt + 2) < NK);
    G2_ITER(1, kt + 1, (kt + 3) < NK);
  }

  const int* idx_e = idx + e * T_TOK;
#pragma unroll
  for (int i = 0; i < 4; ++i)
#pragma unroll
    for (int q = 0; q < 4; ++q) {
      int pl = m0 + wm * 64 + i * 16 + kc * 4 + q;
      if (pl >= c) continue;
      int ent = idx_e[pl];
      int tok = ent & 0x1FFF;
      float* pp = (ent & (1 << 15)) ? part1 : part0;
      float* orow = pp + (size_t)tok * DIM + n0 + wn * 128 + lr;
#pragma unroll
      for (int j = 0; j < 8; ++j)
        orow[j * 16] = acc[i][j][q];
    }
}

// ---------------- combine: out = w0*part0 + w1*part1 ----------------
__global__ __launch_bounds__(256) void combine_kernel(const float* __restrict__ p0,
                                                      const float* __restrict__ p1,
                                                      const float* __restrict__ wslot,
                                                      float* __restrict__ out) {
  int i = blockIdx.x * 256 + threadIdx.x;     // float4 index
  int tok = i >> 8;                           // DIM/4 = 256 float4 per token
  float w0 = wslot[tok], w1 = wslot[T_TOK + tok];
  float4 a = ((const float4*)p0)[i];
  float4 b = ((const float4*)p1)[i];
  float4 o;
  o.x = w0 * a.x + w1 * b.x;
  o.y = w0 * a.y + w1 * b.y;
  o.z = w0 * a.z + w1 * b.z;
  o.w = w0 * a.w + w1 * b.w;
  ((float4*)out)[i] = o;
}

extern "C" void kernel_launch(void* const* d_in, const int* in_sizes, int n_in,
                              void* d_out, int out_size, void* d_ws, size_t ws_size,
                              hipStream_t stream) {
  const float* x  = (const float*)d_in[0];
  const float* gw = (const float*)d_in[1];
  const float* w1 = (const float*)d_in[2];
  const float* w2 = (const float*)d_in[3];
  const float* w3 = (const float*)d_in[4];
  float* out = (float*)d_out;

  // Workspace layout (~249 MB total); part[2] aliases w1t/w3t (dead after gemm1).
  char* ws = (char*)d_ws;
  size_t off = 0;
  auto alloc = [&](size_t bytes) {
    char* p = ws + off;
    off += (bytes + 255) & ~(size_t)255;
    return p;
  };
  unsigned short* xb  = (unsigned short*)alloc((size_t)T_TOK * DIM * 2);       // 16.8 MB
  unsigned short* w1t = (unsigned short*)alloc((size_t)NE * DIM * HID * 2);    // 46.1 MB  [E][H][D]
  unsigned short* w3t = (unsigned short*)alloc((size_t)NE * DIM * HID * 2);    // 46.1 MB  [E][H][D]
  unsigned short* w2t = (unsigned short*)alloc((size_t)NE * DIM * HID * 2);    // 46.1 MB  [E][D][H]
  unsigned short* hb  = (unsigned short*)alloc((size_t)2 * T_TOK * HID * 2);   // 92.3 MB
  int*   cnt   = (int*)alloc(NE * sizeof(int));
  int*   offs  = (int*)alloc(NE * sizeof(int));
  int*   ntl   = (int*)alloc(2 * sizeof(int));
  int*   idx   = (int*)alloc((size_t)NE * T_TOK * sizeof(int));
  float* wslot = (float*)alloc((size_t)2 * T_TOK * sizeof(float));
  int*   tl1   = (int*)alloc((size_t)72 * NT1 * sizeof(int));
  int*   tl2   = (int*)alloc((size_t)72 * NT2 * sizeof(int));
  // part aliases w1t..w3t region: 2*T*D*4 = 67.1 MB <= 92.2 MB
  float* part0 = (float*)w1t;
  float* part1 = part0 + (size_t)T_TOK * DIM;

  hipMemsetAsync(cnt, 0, NE * sizeof(int), stream);

  router_kernel<<<T_TOK / 4, 256, 0, stream>>>(x, gw, xb, cnt, idx, wslot);
  aux_kernel<<<3 * TPM + 1, 256, 0, stream>>>(w1, w3, w2, w1t, w3t, w2t,
                                              cnt, offs, ntl, tl1, tl2);
  gemm1_kernel<<<72 * NT1, 512, 0, stream>>>(xb, w1t, w3t, cnt, offs, ntl, tl1, idx, hb);
  gemm2_kernel<<<72 * NT2, 512, 0, stream>>>(hb, w2t, cnt, offs, ntl, tl2, idx, part0, part1);
  combine_kernel<<<(T_TOK * DIM) / (4 * 256), 256, 0, stream>>>(part0, part1, wslot, out);
}

// Round 12
// 692.060 us; speedup vs baseline: 1.5993x; 1.0099x over previous
//
#include <hip/hip_runtime.h>
#include <math.h>

// Problem constants
#define T_TOK 8192   // B*S tokens
#define DIM   1024   // D
#define HID   2816   // H
#define NE    8      // experts
// K (top-k) = 2

typedef __attribute__((ext_vector_type(4))) float  f32x4;
typedef __attribute__((ext_vector_type(8))) __bf16 bf16x8;
typedef __attribute__((ext_vector_type(8))) unsigned short u16x8;

__device__ __forceinline__ unsigned short f2bf(float f) {
  unsigned int u = __builtin_bit_cast(unsigned int, f);
  unsigned int r = (u + 0x7FFFu + ((u >> 16) & 1u)) >> 16;   // RTNE
  return (unsigned short)r;
}
__device__ __forceinline__ int imin(int a, int b) { return a < b ? a : b; }

// global -> LDS direct DMA, 16B per lane. LDS dest = wave-uniform base + lane*16.
typedef const __attribute__((address_space(1))) void gvoid_t;
typedef __attribute__((address_space(3))) void svoid_t;
__device__ __forceinline__ void g2l16(const void* g, void* l) {
  __builtin_amdgcn_global_load_lds((gvoid_t*)g, (svoid_t*)l, 16, 0, 0);
}

// Pipeline fences (T3/T4): raw s_barrier + counted waits; sched_barrier pins motion.
#define WAITV(N) asm volatile("s_waitcnt vmcnt(" #N ")" ::: "memory")
#define WAITV0 asm volatile("s_waitcnt vmcnt(0)" ::: "memory")
#define LGKM0  asm volatile("s_waitcnt lgkmcnt(0)" ::: "memory")
#define FENCE  asm volatile("" ::: "memory")
#define SBAR   __builtin_amdgcn_s_barrier()
#define SCHED0 __builtin_amdgcn_sched_barrier(0)
#define PRIO(x) __builtin_amdgcn_s_setprio(x)
#define PH_PRE  do { FENCE; SBAR; LGKM0; SCHED0; PRIO(1); } while (0)
#define PH_POST do { PRIO(0); FENCE; SBAR; SCHED0; } while (0)

#define NT1 (HID / 128)   // 22 (gemm1 BN=128)
#define NT2 (DIM / 256)   // 4  (gemm2 BN=256)
#define TPM ((DIM / 64) * (HID / 64) * NE)   // 5632 transpose blocks per matrix
#define RTB (T_TOK / 4)   // 2048 router blocks

// ===== fused front: router (bid < RTB) + 3x transpose-cast (others) =====
// Router: fused x->bf16 cast, fp64 scores, top-2, softmax, compaction.
// idx entry = tok | (slot<<15); wslot[slot*T + t] = softmax weight.
__global__ __launch_bounds__(256) void front_kernel(const float* __restrict__ x,
                                                    const float* __restrict__ gw,
                                                    const float* __restrict__ w1,
                                                    const float* __restrict__ w3,
                                                    const float* __restrict__ w2,
                                                    unsigned short* __restrict__ xb,
                                                    unsigned short* __restrict__ w1t,
                                                    unsigned short* __restrict__ w3t,
                                                    unsigned short* __restrict__ w2t,
                                                    int* __restrict__ cnt,
                                                    int* __restrict__ idx,
                                                    float* __restrict__ wslot) {
  __shared__ float tile_t[64][68];   // transpose staging (router blocks don't touch)
  int bid = blockIdx.x;
  if (bid < RTB) {
    // ---------------- router ----------------
    int wid = threadIdx.x >> 6;
    int lane = threadIdx.x & 63;
    int t = bid * 4 + wid;
    double acc[NE];
#pragma unroll
    for (int e = 0; e < NE; ++e) acc[e] = 0.0;
    const float* xr = x + (size_t)t * DIM;
    unsigned short* xbr = xb + (size_t)t * DIM;
#pragma unroll 4
    for (int i = 0; i < DIM / 64; ++i) {
      int d = i * 64 + lane;
      float xf = xr[d];
      xbr[d] = f2bf(xf);
      double xv = (double)xf;
#pragma unroll
      for (int e = 0; e < NE; ++e) acc[e] += xv * (double)gw[e * DIM + d];
    }
#pragma unroll
    for (int e = 0; e < NE; ++e) {
#pragma unroll
      for (int off = 32; off >= 1; off >>= 1) acc[e] += __shfl_xor(acc[e], off);
    }
    if (lane == 0) {
      int e0 = 0; double s0 = acc[0];
#pragma unroll
      for (int e = 1; e < NE; ++e) if (acc[e] > s0) { s0 = acc[e]; e0 = e; }
      int e1 = -1; double s1 = -1.0e300;
#pragma unroll
      for (int e = 0; e < NE; ++e) if (e != e0 && acc[e] > s1) { s1 = acc[e]; e1 = e; }
      double w0 = 1.0 / (1.0 + exp(s1 - s0));   // softmax over {s0,s1}
      wslot[t] = (float)w0;
      wslot[T_TOK + t] = (float)(1.0 - w0);
      int p0 = atomicAdd(&cnt[e0], 1);
      idx[e0 * T_TOK + p0] = t;                 // slot 0
      int p1 = atomicAdd(&cnt[e1], 1);
      idx[e1 * T_TOK + p1] = t | (1 << 15);     // slot 1
    }
    return;
  }

  // ---------------- transpose-cast: fp32 [E][R][C] -> bf16 [E][C][R] ----------------
  int r = bid - RTB;
  int seg = r / TPM, rr = r % TPM;
  const float* srcm; unsigned short* dstm; int R, C;
  if (seg == 0)      { srcm = w1; dstm = w1t; R = DIM; C = HID; }
  else if (seg == 1) { srcm = w3; dstm = w3t; R = DIM; C = HID; }
  else               { srcm = w2; dstm = w2t; R = HID; C = DIM; }
  int per_e = (R / 64) * (C / 64);
  int e = rr / per_e, tt = rr % per_e;
  int nx = C / 64;
  int c0 = (tt % nx) * 64, r0 = (tt / nx) * 64;

  const float* s = srcm + (size_t)e * R * C;
  unsigned short* d = dstm + (size_t)e * R * C;
  int tr = threadIdx.x >> 4;            // 0..15
  int tc4 = (threadIdx.x & 15) * 4;     // 0..60
#pragma unroll
  for (int s4 = 0; s4 < 4; ++s4) {
    float4 v = *(const float4*)(s + (size_t)(r0 + tr + s4 * 16) * C + c0 + tc4);
    tile_t[tc4 + 0][tr + s4 * 16] = v.x;
    tile_t[tc4 + 1][tr + s4 * 16] = v.y;
    tile_t[tc4 + 2][tr + s4 * 16] = v.z;
    tile_t[tc4 + 3][tr + s4 * 16] = v.w;
  }
  __syncthreads();
  int cw = threadIdx.x >> 3;            // 0..31
  int r8 = (threadIdx.x & 7) * 8;       // 0..56
#pragma unroll
  for (int pass = 0; pass < 2; ++pass) {
    int c = cw + pass * 32;
    float4 a = *(const float4*)&tile_t[c][r8];
    float4 b = *(const float4*)&tile_t[c][r8 + 4];
    u16x8 o;
    o[0] = f2bf(a.x); o[1] = f2bf(a.y); o[2] = f2bf(a.z); o[3] = f2bf(a.w);
    o[4] = f2bf(b.x); o[5] = f2bf(b.y); o[6] = f2bf(b.z); o[7] = f2bf(b.w);
    *(u16x8*)(d + (size_t)(c0 + c) * R + r0 + r8) = o;   // 8 lanes = 128B contiguous
  }
}

// ===== self-decode: bid -> (e, n0, m0, c, base) straight from cnt[] (no prep kernel) =====
// Bijective XCD chunking (m204) over the implicit (e,n,m)-sorted tile list.
// Scalar locals only (rule #20: no runtime-indexed register arrays).
__device__ __forceinline__ bool decode_tile(const int* __restrict__ cnt, int ntiles_n,
                                            int nscale, int& e, int& n0, int& m0,
                                            int& c, int& base) {
  int nt = 0;
#pragma unroll
  for (int i = 0; i < NE; ++i) nt += ((cnt[i] + 255) >> 8) * ntiles_n;
  int q = nt >> 3, rr = nt & 7;
  int xcd = blockIdx.x & 7, pos = blockIdx.x >> 3;
  int cap = xcd < rr ? q + 1 : q;
  if (pos >= cap) return false;
  int lid = (xcd < rr ? xcd * (q + 1) : rr * (q + 1) + (xcd - rr) * q) + pos;
  int t1 = 0, s = 0;
  e = 0; c = 0; base = 0; n0 = 0; m0 = 0;
#pragma unroll
  for (int i = 0; i < NE; ++i) {
    int ci = cnt[i];
    int mi = (ci + 255) >> 8;
    int w = mi * ntiles_n;
    if (lid >= t1 && lid < t1 + w) {
      e = i; c = ci; base = s;
      int rem = lid - t1;
      int n = rem / mi;
      n0 = n * nscale;
      m0 = (rem - n * mi) * 256;
    }
    t1 += w; s += ci;
  }
  return true;
}

// ====== GEMM1: h = silu(Xg @ w1) * (Xg @ w3) — 2 phases/K-tile, counted vmcnt ======
// BM=256, BN=128 (dual-B), BK=64, 8 waves (2M x 4N), dbuf LDS 128KB.
__global__ __launch_bounds__(512, 1) void gemm1_kernel(const unsigned short* __restrict__ xb,
                                                       const unsigned short* __restrict__ w1t,
                                                       const unsigned short* __restrict__ w3t,
                                                       const int* __restrict__ cnt,
                                                       const int* __restrict__ idx,
                                                       unsigned short* __restrict__ hbuf) {
  int e, n0, m0, c, base;
  if (!decode_tile(cnt, NT1, 128, e, n0, m0, c, base)) return;

  __shared__ __align__(16) unsigned short As[2 * 16384];   // [2][256][64]
  __shared__ __align__(16) unsigned short B1s[2 * 8192];   // [2][128][64]
  __shared__ __align__(16) unsigned short B3s[2 * 8192];

  const int t = threadIdx.x;
  const int wid = t >> 6, lane = t & 63;
  const int wm = wid >> 2, wn = wid & 3;
  const int lr = lane & 15, kc = lane >> 4, sw = lane & 7;
  const int ldst = wid * 512;           // wave-uniform elems within an 8KB instr chunk
  const int trow = t >> 3;              // 0..63
  const int swzk = ((t & 7) ^ ((t >> 3) & 7)) * 8;   // pre-swizzled source k-chunk

  const int* idx_e = idx + e * T_TOK;
  int g0 = m0 + trow, g1 = m0 + 64 + trow, g2 = m0 + 128 + trow, g3 = m0 + 192 + trow;
  int tk0 = (g0 < c) ? (idx_e[g0] & 0x1FFF) : 0;
  int tk1 = (g1 < c) ? (idx_e[g1] & 0x1FFF) : 0;
  int tk2 = (g2 < c) ? (idx_e[g2] & 0x1FFF) : 0;
  int tk3 = (g3 < c) ? (idx_e[g3] & 0x1FFF) : 0;
  const unsigned short* aS0 = xb + (size_t)tk0 * DIM + swzk;
  const unsigned short* aS1 = xb + (size_t)tk1 * DIM + swzk;
  const unsigned short* aS2 = xb + (size_t)tk2 * DIM + swzk;
  const unsigned short* aS3 = xb + (size_t)tk3 * DIM + swzk;
  const unsigned short* w1e = w1t + ((size_t)e * HID + n0) * DIM;
  const unsigned short* w3e = w3t + ((size_t)e * HID + n0) * DIM;
  const unsigned short* b1S0 = w1e + (size_t)trow * DIM + swzk;
  const unsigned short* b1S1 = w1e + (size_t)(64 + trow) * DIM + swzk;
  const unsigned short* b3S0 = w3e + (size_t)trow * DIM + swzk;
  const unsigned short* b3S1 = w3e + (size_t)(64 + trow) * DIM + swzk;

  f32x4 acc1[8][2], acc3[8][2];
#pragma unroll
  for (int i = 0; i < 8; ++i)
#pragma unroll
    for (int j = 0; j < 2; ++j) {
      acc1[i][j] = f32x4{0.f, 0.f, 0.f, 0.f};
      acc3[i][j] = f32x4{0.f, 0.f, 0.f, 0.f};
    }
  bf16x8 ra0[4], ra1[4], rb1[2], rb3[2];

#define G1_STG_A(CUR, TILE) do {                                      \
    g2l16(aS0 + (TILE) * 64, As + (CUR) * 16384 + 0 * 4096 + ldst);   \
    g2l16(aS1 + (TILE) * 64, As + (CUR) * 16384 + 1 * 4096 + ldst);   \
    g2l16(aS2 + (TILE) * 64, As + (CUR) * 16384 + 2 * 4096 + ldst);   \
    g2l16(aS3 + (TILE) * 64, As + (CUR) * 16384 + 3 * 4096 + ldst);   \
  } while (0)
#define G1_STG_B(CUR, TILE) do {                                      \
    g2l16(b1S0 + (TILE) * 64, B1s + (CUR) * 8192 + 0 * 4096 + ldst);  \
    g2l16(b1S1 + (TILE) * 64, B1s + (CUR) * 8192 + 1 * 4096 + ldst);  \
    g2l16(b3S0 + (TILE) * 64, B3s + (CUR) * 8192 + 0 * 4096 + ldst);  \
    g2l16(b3S1 + (TILE) * 64, B3s + (CUR) * 8192 + 1 * 4096 + ldst);  \
  } while (0)
#define G1_LDALL(CUR, KS2) do {                                                        \
    const int se = ((((KS2) * 4) + kc) ^ sw) * 8;                                      \
    rb1[0] = *(const bf16x8*)(B1s + (CUR) * 8192 + (wn * 32 + lr) * 64 + se);          \
    rb1[1] = *(const bf16x8*)(B1s + (CUR) * 8192 + (wn * 32 + 16 + lr) * 64 + se);     \
    rb3[0] = *(const bf16x8*)(B3s + (CUR) * 8192 + (wn * 32 + lr) * 64 + se);          \
    rb3[1] = *(const bf16x8*)(B3s + (CUR) * 8192 + (wn * 32 + 16 + lr) * 64 + se);     \
    const int ab = (CUR) * 16384 + (wm * 128 + lr) * 64 + se;                          \
    _Pragma("unroll") for (int f = 0; f < 4; ++f) {                                    \
      ra0[f] = *(const bf16x8*)(As + ab + f * 1024);                                   \
      ra1[f] = *(const bf16x8*)(As + ab + 4096 + f * 1024);                            \
    }                                                                                  \
  } while (0)
#define G1_MM2() do {                                                                  \
    _Pragma("unroll") for (int f = 0; f < 4; ++f)                                      \
      _Pragma("unroll") for (int j = 0; j < 2; ++j) {                                  \
        acc1[f][j] = __builtin_amdgcn_mfma_f32_16x16x32_bf16(ra0[f], rb1[j], acc1[f][j], 0, 0, 0); \
        acc3[f][j] = __builtin_amdgcn_mfma_f32_16x16x32_bf16(ra0[f], rb3[j], acc3[f][j], 0, 0, 0); \
      }                                                                                \
    _Pragma("unroll") for (int f = 0; f < 4; ++f)                                      \
      _Pragma("unroll") for (int j = 0; j < 2; ++j) {                                  \
        acc1[4 + f][j] = __builtin_amdgcn_mfma_f32_16x16x32_bf16(ra1[f], rb1[j], acc1[4 + f][j], 0, 0, 0); \
        acc3[4 + f][j] = __builtin_amdgcn_mfma_f32_16x16x32_bf16(ra1[f], rb3[j], acc3[4 + f][j], 0, 0, 0); \
      }                                                                                \
  } while (0)
#define G1_ITER(CUR, KT, DOSTAGE) do {                                                 \
    G1_LDALL(CUR, 0);                                                                  \
    PH_PRE; G1_MM2(); PH_POST;                                                         \
    G1_LDALL(CUR, 1);                                                                  \
    FENCE; SBAR; LGKM0; SCHED0; PRIO(1); G1_MM2(); PRIO(0); SCHED0;                    \
    if (DOSTAGE) { G1_STG_A(CUR, (KT) + 2); G1_STG_B(CUR, (KT) + 2); WAITV(8); }       \
    else WAITV0;                                                                       \
    FENCE; SBAR; SCHED0;                                                               \
  } while (0)

  G1_STG_A(0, 0); G1_STG_B(0, 0);
  G1_STG_A(1, 1); G1_STG_B(1, 1);
  WAITV(8); FENCE; SBAR; SCHED0;

  const int NK = DIM / 64;   // 16
#pragma unroll 1
  for (int kt = 0; kt < NK; kt += 2) {
    G1_ITER(0, kt, (kt + 2) < NK);
    G1_ITER(1, kt + 1, (kt + 3) < NK);
  }

#pragma unroll
  for (int i = 0; i < 8; ++i)
#pragma unroll
    for (int q = 0; q < 4; ++q) {
      int pl = m0 + wm * 128 + i * 16 + kc * 4 + q;
      if (pl >= c) continue;
      unsigned short* hrow = hbuf + (size_t)(base + pl) * HID + n0 + wn * 32 + lr;
#pragma unroll
      for (int j = 0; j < 2; ++j) {
        float v1 = acc1[i][j][q];
        float v3 = acc3[i][j][q];
        float hv = v1 / (1.0f + __expf(-v1)) * v3;   // silu(v1) * v3
        hrow[j * 16] = f2bf(hv);
      }
    }
}

// ============ GEMM2: part[slot][tok] = w * (h @ w2) — BN=256, counted vmcnt ============
// BM=256, BN=256, BK=64, 8 waves (4M x 2N, per-wave 64x128), dbuf LDS 128KB. No atomics.
__global__ __launch_bounds__(512, 1) void gemm2_kernel(const unsigned short* __restrict__ hbuf,
                                                       const unsigned short* __restrict__ w2t,
                                                       const int* __restrict__ cnt,
                                                       const int* __restrict__ idx,
                                                       const float* __restrict__ wslot,
                                                       float* __restrict__ part0,
                                                       float* __restrict__ part1) {
  int e, n0, m0, c, base;
  if (!decode_tile(cnt, NT2, 256, e, n0, m0, c, base)) return;

  __shared__ __align__(16) unsigned short As[2 * 16384];   // [2][256][64]
  __shared__ __align__(16) unsigned short Bs[2 * 16384];   // [2][256][64]

  const int t = threadIdx.x;
  const int wid = t >> 6, lane = t & 63;
  const int wm = wid >> 1, wn = wid & 1;       // 4M x 2N
  const int lr = lane & 15, kc = lane >> 4, sw = lane & 7;
  const int ldst = wid * 512;
  const int trow = t >> 3;
  const int swzk = ((t & 7) ^ ((t >> 3) & 7)) * 8;

  int r0 = imin(base + m0 + trow,       2 * T_TOK - 1);
  int r1 = imin(base + m0 + 64 + trow,  2 * T_TOK - 1);
  int r2 = imin(base + m0 + 128 + trow, 2 * T_TOK - 1);
  int r3 = imin(base + m0 + 192 + trow, 2 * T_TOK - 1);
  const unsigned short* aS0 = hbuf + (size_t)r0 * HID + swzk;
  const unsigned short* aS1 = hbuf + (size_t)r1 * HID + swzk;
  const unsigned short* aS2 = hbuf + (size_t)r2 * HID + swzk;
  const unsigned short* aS3 = hbuf + (size_t)r3 * HID + swzk;
  const unsigned short* w2e = w2t + ((size_t)e * DIM + n0) * HID;
  const unsigned short* bS0 = w2e + (size_t)trow * HID + swzk;
  const unsigned short* bS1 = w2e + (size_t)(64 + trow) * HID + swzk;
  const unsigned short* bS2 = w2e + (size_t)(128 + trow) * HID + swzk;
  const unsigned short* bS3 = w2e + (size_t)(192 + trow) * HID + swzk;

  f32x4 acc[4][8];
#pragma unroll
  for (int i = 0; i < 4; ++i)
#pragma unroll
    for (int j = 0; j < 8; ++j) acc[i][j] = f32x4{0.f, 0.f, 0.f, 0.f};
  bf16x8 ra[4], rb[8];

#define G2_STG(CUR, TILE) do {                                        \
    g2l16(aS0 + (TILE) * 64, As + (CUR) * 16384 + 0 * 4096 + ldst);   \
    g2l16(aS1 + (TILE) * 64, As + (CUR) * 16384 + 1 * 4096 + ldst);   \
    g2l16(aS2 + (TILE) * 64, As + (CUR) * 16384 + 2 * 4096 + ldst);   \
    g2l16(aS3 + (TILE) * 64, As + (CUR) * 16384 + 3 * 4096 + ldst);   \
    g2l16(bS0 + (TILE) * 64, Bs + (CUR) * 16384 + 0 * 4096 + ldst);   \
    g2l16(bS1 + (TILE) * 64, Bs + (CUR) * 16384 + 1 * 4096 + ldst);   \
    g2l16(bS2 + (TILE) * 64, Bs + (CUR) * 16384 + 2 * 4096 + ldst);   \
    g2l16(bS3 + (TILE) * 64, Bs + (CUR) * 16384 + 3 * 4096 + ldst);   \
  } while (0)
#define G2_LD(CUR, KS2) do {                                                          \
    const int se = ((((KS2) * 4) + kc) ^ sw) * 8;                                     \
    const int ab = (CUR) * 16384 + (wm * 64 + lr) * 64 + se;                          \
    _Pragma("unroll") for (int f = 0; f < 4; ++f)                                     \
      ra[f] = *(const bf16x8*)(As + ab + f * 1024);                                   \
    const int bb = (CUR) * 16384 + (wn * 128 + lr) * 64 + se;                         \
    _Pragma("unroll") for (int j = 0; j < 8; ++j)                                     \
      rb[j] = *(const bf16x8*)(Bs + bb + j * 1024);                                   \
  } while (0)
#define G2_MM() do {                                                                  \
    _Pragma("unroll") for (int f = 0; f < 4; ++f)                                     \
      _Pragma("unroll") for (int j = 0; j < 8; ++j)                                   \
        acc[f][j] = __builtin_amdgcn_mfma_f32_16x16x32_bf16(ra[f], rb[j], acc[f][j], 0, 0, 0); \
  } while (0)
#define G2_ITER(CUR, KT, DOSTAGE) do {                                                \
    G2_LD(CUR, 0);                                                                    \
    PH_PRE; G2_MM(); PH_POST;                                                         \
    G2_LD(CUR, 1);                                                                    \
    FENCE; SBAR; LGKM0; SCHED0; PRIO(1); G2_MM(); PRIO(0); SCHED0;                    \
    if (DOSTAGE) { G2_STG(CUR, (KT) + 2); WAITV(8); }                                 \
    else WAITV0;                                                                      \
    FENCE; SBAR; SCHED0;                                                              \
  } while (0)

  G2_STG(0, 0);
  G2_STG(1, 1);
  WAITV(8); FENCE; SBAR; SCHED0;

  const int NK = HID / 64;   // 44
#pragma unroll 1
  for (int kt = 0; kt < NK; kt += 2) {
    G2_ITER(0, kt, (kt + 2) < NK);
    G2_ITER(1, kt + 1, (kt + 3) < NK);
  }

  const int* idx_e = idx + e * T_TOK;
#pragma unroll
  for (int i = 0; i < 4; ++i)
#pragma unroll
    for (int q = 0; q < 4; ++q) {
      int pl = m0 + wm * 64 + i * 16 + kc * 4 + q;
      if (pl >= c) continue;
      int ent = idx_e[pl];
      int tok = ent & 0x1FFF;
      int slot = (ent >> 15) & 1;
      float w = wslot[slot * T_TOK + tok];
      float* pp = slot ? part1 : part0;
      float* orow = pp + (size_t)tok * DIM + n0 + wn * 128 + lr;
#pragma unroll
      for (int j = 0; j < 8; ++j)
        orow[j * 16] = w * acc[i][j][q];
    }
}

// ---------------- combine: out = part0 + part1 ----------------
__global__ __launch_bounds__(256) void combine_kernel(const float* __restrict__ p0,
                                                      const float* __restrict__ p1,
                                                      float* __restrict__ out) {
  int i = blockIdx.x * 256 + threadIdx.x;     // float4 index
  float4 a = ((const float4*)p0)[i];
  float4 b = ((const float4*)p1)[i];
  float4 o;
  o.x = a.x + b.x;
  o.y = a.y + b.y;
  o.z = a.z + b.z;
  o.w = a.w + b.w;
  ((float4*)out)[i] = o;
}

extern "C" void kernel_launch(void* const* d_in, const int* in_sizes, int n_in,
                              void* d_out, int out_size, void* d_ws, size_t ws_size,
                              hipStream_t stream) {
  const float* x  = (const float*)d_in[0];
  const float* gw = (const float*)d_in[1];
  const float* w1 = (const float*)d_in[2];
  const float* w2 = (const float*)d_in[3];
  const float* w3 = (const float*)d_in[4];
  float* out = (float*)d_out;

  // Workspace layout (~249 MB); part[2] aliases w1t/w3t (dead after gemm1).
  char* ws = (char*)d_ws;
  size_t off = 0;
  auto alloc = [&](size_t bytes) {
    char* p = ws + off;
    off += (bytes + 255) & ~(size_t)255;
    return p;
  };
  unsigned short* xb  = (unsigned short*)alloc((size_t)T_TOK * DIM * 2);       // 16.8 MB
  unsigned short* w1t = (unsigned short*)alloc((size_t)NE * DIM * HID * 2);    // 46.1 MB  [E][H][D]
  unsigned short* w3t = (unsigned short*)alloc((size_t)NE * DIM * HID * 2);    // 46.1 MB  [E][H][D]
  unsigned short* w2t = (unsigned short*)alloc((size_t)NE * DIM * HID * 2);    // 46.1 MB  [E][D][H]
  unsigned short* hb  = (unsigned short*)alloc((size_t)2 * T_TOK * HID * 2);   // 92.3 MB
  int*   cnt   = (int*)alloc(NE * sizeof(int));
  int*   idx   = (int*)alloc((size_t)NE * T_TOK * sizeof(int));
  float* wslot = (float*)alloc((size_t)2 * T_TOK * sizeof(float));
  // part aliases w1t..w3t region: 2*T*D*4 = 67.1 MB <= 92.2 MB
  float* part0 = (float*)w1t;
  float* part1 = part0 + (size_t)T_TOK * DIM;

  hipMemsetAsync(cnt, 0, NE * sizeof(int), stream);

  front_kernel<<<RTB + 3 * TPM, 256, 0, stream>>>(x, gw, w1, w3, w2, xb,
                                                  w1t, w3t, w2t, cnt, idx, wslot);
  gemm1_kernel<<<72 * NT1, 512, 0, stream>>>(xb, w1t, w3t, cnt, idx, hb);
  gemm2_kernel<<<72 * NT2, 512, 0, stream>>>(hb, w2t, cnt, idx, wslot, part0, part1);
  combine_kernel<<<(T_TOK * DIM) / (4 * 256), 256, 0, stream>>>(part0, part1, out);
}